// Round 18
// baseline (245.040 us; speedup 1.0000x reference)
//
#include <hip/hip_runtime.h>
#include <hip/hip_bf16.h>
#include <math.h>

#define DIV_UP(a,b) (((a)+(b)-1)/(b))
#define FSQRT(x) __builtin_amdgcn_sqrtf(x)

typedef __attribute__((ext_vector_type(8))) short short8;
typedef __attribute__((ext_vector_type(4))) float f32x4;

// async global->LDS, 16B per lane; gptr per-lane, lptr wave-uniform
#define GL16(g, l) __builtin_amdgcn_global_load_lds( \
    (const __attribute__((address_space(1))) void*)(g), \
    (__attribute__((address_space(3))) void*)(l), 16, 0, 0)

// ---------------- W1 prep (+stats/counter zero folded in) ----------------
__global__ __launch_bounds__(256) void w1split_kernel(
    const float* __restrict__ w, ushort* __restrict__ Wh, ushort* __restrict__ Wl,
    double* __restrict__ stats) {
    if (blockIdx.x == 0 && threadIdx.x < 78) stats[threadIdx.x] = 0.0;  // includes counters
    int e = blockIdx.x*256 + threadIdx.x;
    if (e >= 112*96) return;
    int o = e / 96, kk = e - o*96, c = kk >> 5, k = kk & 31;
    float v = (o < 100 && k < 25) ? w[o*75 + c*25 + k] : 0.f;
    __hip_bfloat16 hb = __float2bfloat16(v);
    float hf = __bfloat162float(hb);
    __hip_bfloat16 lb = __float2bfloat16(v - hf);
    Wh[e] = *(ushort*)&hb;
    Wl[e] = *(ushort*)&lb;
}

__global__ __launch_bounds__(64) void w1norm_kernel(
    const ushort* __restrict__ Wh, const ushort* __restrict__ Wl, float* __restrict__ wn1) {
    int j = blockIdx.x*64 + threadIdx.x;
    if (j >= 336) return;
    int o = j / 3, c = j - o*3;
    const ushort* h = Wh + o*96 + c*32;
    const ushort* l = Wl + o*96 + c*32;
    float s = 0.f;
#pragma unroll
    for (int k = 0; k < 25; ++k) {
        ushort hu = h[k], lu = l[k];
        float v = __bfloat162float(*(__hip_bfloat16*)&hu) + __bfloat162float(*(__hip_bfloat16*)&lu);
        s += v*v;
    }
    wn1[j] = s;
}

// ---------------- layer 1 MFMA (R15 version: 4 images, 7-wave phase C) ----------------
__global__ __launch_bounds__(512, 2) void rbf1_mfma(
    const float* __restrict__ x, const ushort* __restrict__ Wh, const ushort* __restrict__ Wl,
    const float* __restrict__ wn1, float* __restrict__ dist1,
    float* __restrict__ pixstat) {
    __shared__ ushort Ah[3*144*32];
    __shared__ ushort Al[3*144*32];
    __shared__ float pnl[432];
    __shared__ float rstat[7*144*2];   // [wave][row][sum,sq] — every slot written, no init
    int tid = threadIdx.x;
    int b4 = blockIdx.x;

    if (tid < 432) {
        int row = tid / 3, c = tid - row*3;
        int img = row / 36, p = row - img*36;
        int ph = p / 6, pw = p - ph*6;
        const float* xp = x + (size_t)b4*9408 + img*2352 + c*784 + (ph*28 + pw)*4;
        float arr[25];
#pragma unroll
        for (int ki = 0; ki < 5; ++ki) {
            float4 v4 = *(const float4*)(xp + ki*28);
            arr[ki*5+0] = v4.x; arr[ki*5+1] = v4.y;
            arr[ki*5+2] = v4.z; arr[ki*5+3] = v4.w;
            arr[ki*5+4] = xp[ki*28 + 4];
        }
        float pnc = 0.f;
        int tilebase = c*9216 + row*64;
        int r3 = (row >> 1) & 3;
#pragma unroll
        for (int kb = 0; kb < 4; ++kb) {
            uint4 hq, lq;
            uint* hqa = (uint*)&hq;
            uint* lqa = (uint*)&lq;
#pragma unroll
            for (int j = 0; j < 4; ++j) {
                int k0 = kb*8 + 2*j;
                float v0 = (k0 < 25) ? arr[k0] : 0.f;
                float v1 = (k0+1 < 25) ? arr[k0+1] : 0.f;
                __hip_bfloat16 h0 = __float2bfloat16(v0);
                float hf0 = __bfloat162float(h0);
                __hip_bfloat16 l0 = __float2bfloat16(v0 - hf0);
                float r0 = hf0 + __bfloat162float(l0);
                __hip_bfloat16 h1 = __float2bfloat16(v1);
                float hf1 = __bfloat162float(h1);
                __hip_bfloat16 l1 = __float2bfloat16(v1 - hf1);
                float r1 = hf1 + __bfloat162float(l1);
                pnc += r0*r0 + r1*r1;
                hqa[j] = (uint)(*(ushort*)&h0) | ((uint)(*(ushort*)&h1) << 16);
                lqa[j] = (uint)(*(ushort*)&l0) | ((uint)(*(ushort*)&l1) << 16);
            }
            int kbs = kb ^ r3;
            *(uint4*)((char*)Ah + tilebase + kbs*16) = hq;
            *(uint4*)((char*)Al + tilebase + kbs*16) = lq;
        }
        pnl[tid] = pnc;
    }
    __syncthreads();

    int lane = tid & 63, wave = tid >> 6;
    if (wave < 7) {
        int nf = wave;
        int rl = lane & 15, kh = lane >> 4;
        int o = nf*16 + rl;
        const ushort* bhp = Wh + o*96 + kh*8;
        const ushort* blp = Wl + o*96 + kh*8;
        short8 bh0 = *(const short8*)(bhp);
        short8 bh1 = *(const short8*)(bhp + 32);
        short8 bh2 = *(const short8*)(bhp + 64);
        short8 bl0 = *(const short8*)(blp);
        short8 bl1 = *(const short8*)(blp + 32);
        short8 bl2 = *(const short8*)(blp + 64);
        float w0 = wn1[o*3], w1v = wn1[o*3+1], w2v = wn1[o*3+2];
        int swz = (rl >> 1) & 3;
        int kx = (kh ^ swz) * 16;
        bool valid = (o < 100);
        float* mystat = rstat + wave*288;
#pragma unroll
        for (int mf = 0; mf < 9; ++mf) {
            int rbase = (mf*16 + rl)*64;
            short8 ah0 = *(const short8*)((const char*)Ah + rbase + kx);
            short8 al0 = *(const short8*)((const char*)Al + rbase + kx);
            short8 ah1 = *(const short8*)((const char*)Ah + 9216 + rbase + kx);
            short8 al1 = *(const short8*)((const char*)Al + 9216 + rbase + kx);
            short8 ah2 = *(const short8*)((const char*)Ah + 18432 + rbase + kx);
            short8 al2 = *(const short8*)((const char*)Al + 18432 + rbase + kx);
            f32x4 a0 = {0.f,0.f,0.f,0.f}, a1 = {0.f,0.f,0.f,0.f}, a2 = {0.f,0.f,0.f,0.f};
            a0 = __builtin_amdgcn_mfma_f32_16x16x32_bf16(ah0, bh0, a0, 0, 0, 0);
            a1 = __builtin_amdgcn_mfma_f32_16x16x32_bf16(ah1, bh1, a1, 0, 0, 0);
            a2 = __builtin_amdgcn_mfma_f32_16x16x32_bf16(ah2, bh2, a2, 0, 0, 0);
            a0 = __builtin_amdgcn_mfma_f32_16x16x32_bf16(ah0, bl0, a0, 0, 0, 0);
            a1 = __builtin_amdgcn_mfma_f32_16x16x32_bf16(ah1, bl1, a1, 0, 0, 0);
            a2 = __builtin_amdgcn_mfma_f32_16x16x32_bf16(ah2, bl2, a2, 0, 0, 0);
            a0 = __builtin_amdgcn_mfma_f32_16x16x32_bf16(al0, bh0, a0, 0, 0, 0);
            a1 = __builtin_amdgcn_mfma_f32_16x16x32_bf16(al1, bh1, a1, 0, 0, 0);
            a2 = __builtin_amdgcn_mfma_f32_16x16x32_bf16(al2, bh2, a2, 0, 0, 0);
            float dsum[4], dsq[4];
            size_t base = (size_t)(b4*144 + mf*16 + kh*4)*100 + o;
#pragma unroll
            for (int r = 0; r < 4; ++r) {
                int row = mf*16 + kh*4 + r;
                float d = FSQRT(fmaxf(pnl[row*3+0] + w0  - 2.f*a0[r], 1e-12f))
                        + FSQRT(fmaxf(pnl[row*3+1] + w1v - 2.f*a1[r], 1e-12f))
                        + FSQRT(fmaxf(pnl[row*3+2] + w2v - 2.f*a2[r], 1e-12f));
                float dv = valid ? d : 0.f;
                if (valid) dist1[base + (size_t)r*100] = d;
                dsum[r] = dv; dsq[r] = dv*dv;
            }
#pragma unroll
            for (int m = 1; m <= 8; m <<= 1) {
#pragma unroll
                for (int r = 0; r < 4; ++r) {
                    dsum[r] += __shfl_xor(dsum[r], m, 64);
                    dsq[r]  += __shfl_xor(dsq[r],  m, 64);
                }
            }
            if (rl == 0) {
#pragma unroll
                for (int r = 0; r < 4; ++r) {
                    int row = mf*16 + kh*4 + r;
                    mystat[row*2]     = dsum[r];   // private region, plain store
                    mystat[row*2 + 1] = dsq[r];
                }
            }
        }
    }
    __syncthreads();
    if (tid < 72) {
        int p = tid >> 1, w = tid & 1;
        float s = 0.f;
#pragma unroll
        for (int wv = 0; wv < 7; ++wv)
#pragma unroll
            for (int g = 0; g < 4; ++g)
                s += rstat[wv*288 + (p + 36*g)*2 + w];
        pixstat[(size_t)b4*72 + 2*p + w] = s;
    }
}

// reduce per-block pixel partials -> scale[p], p = blockIdx.x (36 blocks, 1024 partials)
__global__ __launch_bounds__(256) void finalize36_kernel(
    const float* __restrict__ pixstat, float* __restrict__ scale) {
    __shared__ double ss[256], qq[256];
    int p = blockIdx.x, tid = threadIdx.x;
    double s = 0.0, q = 0.0;
    for (int b = tid; b < 1024; b += 256) {
        s += (double)pixstat[(size_t)b*72 + 2*p];
        q += (double)pixstat[(size_t)b*72 + 2*p + 1];
    }
    ss[tid] = s; qq[tid] = q; __syncthreads();
    for (int st = 128; st > 0; st >>= 1) {
        if (tid < st) { ss[tid] += ss[tid+st]; qq[tid] += qq[tid+st]; }
        __syncthreads();
    }
    if (tid == 0) {
        const double N = 409600.0;
        double m = ss[0] / N;
        double var = (qq[0] - N*m*m) / (N - 1.0);
        scale[p] = (float)(0.5 / var);
    }
}

// fused exp+crelu+SFM1+split+norm: dist1 -> Y2 planes [36864][128] + norms (roomy path)
__global__ __launch_bounds__(256) void sfm1s_kernel(
    const float* __restrict__ dist1, const float* __restrict__ scale,
    ushort* __restrict__ H, ushort* __restrict__ L, float* __restrict__ norm) {
    int wave = threadIdx.x >> 6, lane = threadIdx.x & 63;
    int n = blockIdx.x*4 + wave;
    int b = n / 9, ij = n % 9, i = ij / 3, j = ij % 3;
    const float alpha[2][2] = {{0.729f, 0.81f},{0.9f, 1.0f}};
    float s = 0.f;
#pragma unroll
    for (int q = 0; q < 2; ++q) {
        int k = lane + q*64;
        float y = 0.f;
        if (k < 100) {
            float acc = 0.f;
#pragma unroll
            for (int fh = 0; fh < 2; ++fh)
#pragma unroll
                for (int fw = 0; fw < 2; ++fw) {
                    int p = (2*i+fh)*6 + (2*j+fw);
                    float d = dist1[(size_t)b*3600 + p*100 + k];
                    float v = __expf(-d*d*scale[p]);
                    v = (v >= 0.4f) ? v : 0.f;
                    acc += alpha[fh][fw]*v;
                }
            y = 0.25f * acc;
        }
        __hip_bfloat16 hb = __float2bfloat16(y);
        float hf = __bfloat162float(hb);
        __hip_bfloat16 lb = __float2bfloat16(y - hf);
        H[(size_t)n*128 + k] = *(ushort*)&hb;
        L[(size_t)n*128 + k] = *(ushort*)&lb;
        float r = hf + __bfloat162float(lb);
        s += r*r;
    }
    for (int off = 32; off > 0; off >>= 1) s += __shfl_down(s, off, 64);
    if (lane == 0) norm[n] = s;
}

// sfm1 fallback (non-roomy): dist1 -> y2 fp32
__global__ __launch_bounds__(256) void sfm1_kernel(
    const float* __restrict__ dist1, const float* __restrict__ scale,
    float* __restrict__ y2) {
    int gid = blockIdx.x*256 + threadIdx.x;
    if (gid >= 36864*100) return;
    int c = gid % 100, n = gid / 100;
    int b = n / 9, ij = n % 9, i = ij / 3, j = ij % 3;
    const float alpha[2][2] = {{0.729f, 0.81f},{0.9f, 1.0f}};
    float acc = 0.f;
#pragma unroll
    for (int fh = 0; fh < 2; ++fh)
#pragma unroll
        for (int fw = 0; fw < 2; ++fw) {
            int p = (2*i+fh)*6 + (2*j+fw);
            float d = dist1[(size_t)b*3600 + p*100 + c];
            float v = __expf(-d*d*scale[p]);
            v = (v >= 0.4f) ? v : 0.f;
            acc += alpha[fh][fw]*v;
        }
    y2[gid] = 0.25f * acc;
}

// fused split+pad+rownorm: one wave per row
__global__ __launch_bounds__(256) void splitnorm_kernel(
    const float* __restrict__ src, ushort* __restrict__ H, ushort* __restrict__ L,
    float* __restrict__ norm, int R, int K, int Kp) {
    int wave = threadIdx.x >> 6, lane = threadIdx.x & 63;
    int row = blockIdx.x*4 + wave;
    float s = 0.f;
    if (row < R) {
        for (int k = lane; k < Kp; k += 64) {
            float v = (k < K) ? src[(size_t)row*K + k] : 0.f;
            __hip_bfloat16 hb = __float2bfloat16(v);
            float hf = __bfloat162float(hb);
            __hip_bfloat16 lb = __float2bfloat16(v - hf);
            H[(size_t)row*Kp + k] = *(ushort*)&hb;
            L[(size_t)row*Kp + k] = *(ushort*)&lb;
            float r = hf + __bfloat162float(lb);
            s += r*r;
        }
    } else {
        for (int k = lane; k < Kp; k += 64) {
            H[(size_t)row*Kp + k] = 0;
            L[(size_t)row*Kp + k] = 0;
        }
    }
    for (int off = 32; off > 0; off >>= 1) s += __shfl_down(s, off, 64);
    if (lane == 0) norm[row] = s;
}

// fused exp+crelu+SFM2+split+norm
__global__ __launch_bounds__(256) void sfm2s_kernel(
    const float* __restrict__ dist2, const float* __restrict__ scale,
    ushort* __restrict__ H, ushort* __restrict__ L, float* __restrict__ norm) {
    int wave = threadIdx.x >> 6, lane = threadIdx.x & 63;
    int n2 = blockIdx.x*4 + wave;
    int b = n2 / 3, i = n2 % 3;
    float s2 = scale[0];
    const float alphaJ[3] = {0.81f, 0.9f, 1.0f};
    float s = 0.f;
#pragma unroll
    for (int q = 0; q < 4; ++q) {
        int k = lane + q*64;
        float y = 0.f;
        if (k < 225) {
            float acc = 0.f;
#pragma unroll
            for (int j = 0; j < 3; ++j) {
                float d = dist2[((size_t)(b*9 + i*3 + j))*225 + k];
                float v = __expf(-d*d*s2);
                v = (v >= 0.1f) ? v : 0.f;
                acc += alphaJ[j]*v;
            }
            y = acc * (1.f/3.f);
        }
        __hip_bfloat16 hb = __float2bfloat16(y);
        float hf = __bfloat162float(hb);
        __hip_bfloat16 lb = __float2bfloat16(y - hf);
        H[(size_t)n2*256 + k] = *(ushort*)&hb;
        L[(size_t)n2*256 + k] = *(ushort*)&lb;
        float r = hf + __bfloat162float(lb);
        s += r*r;
    }
    for (int off = 32; off > 0; off >>= 1) s += __shfl_down(s, off, 64);
    if (lane == 0) norm[n2] = s;
}

// fused exp+crelu+SFM3+split+norm
__global__ __launch_bounds__(256) void sfm3s_kernel(
    const float* __restrict__ dist3, const float* __restrict__ scale,
    ushort* __restrict__ H, ushort* __restrict__ L, float* __restrict__ norm) {
    int wave = threadIdx.x >> 6, lane = threadIdx.x & 63;
    int b = blockIdx.x*4 + wave;
    float s3 = scale[0];
    const float alphaI[3] = {0.81f, 0.9f, 1.0f};
    float s = 0.f;
#pragma unroll
    for (int q = 0; q < 10; ++q) {
        int k = lane + q*64;
        float y = 0.f;
        if (k < 625) {
            float acc = 0.f;
#pragma unroll
            for (int i = 0; i < 3; ++i) {
                float d = dist3[((size_t)(b*3 + i))*625 + k];
                float v = __expf(-d*d*s3);
                v = (v >= 0.01f) ? v : 0.f;
                acc += alphaI[i]*v;
            }
            y = acc * (1.f/3.f);
        }
        __hip_bfloat16 hb = __float2bfloat16(y);
        float hf = __bfloat162float(hb);
        __hip_bfloat16 lb = __float2bfloat16(y - hf);
        H[(size_t)b*640 + k] = *(ushort*)&hb;
        L[(size_t)b*640 + k] = *(ushort*)&lb;
        float r = hf + __bfloat162float(lb);
        s += r*r;
    }
    for (int off = 32; off > 0; off >>= 1) s += __shfl_down(s, off, 64);
    if (lane == 0) norm[b] = s;
}

// ---------------- unified dist GEMM: 128x128, 8 waves, gl_lds, LAST-BLOCK finalize ----------------
__global__ __launch_bounds__(512, 4) void distg_mfma(
    const ushort* __restrict__ Yh, const ushort* __restrict__ Yl,   // [N][Kp]
    const ushort* __restrict__ Wh, const ushort* __restrict__ Wl,   // [Opad][Kp]
    const float* __restrict__ pn, const float* __restrict__ wn,
    float* __restrict__ D, int N, int O, int Kp,
    double* __restrict__ part, int nb, float* __restrict__ scaleDst,
    double Nstat, uint* __restrict__ counter) {
    __shared__ ushort Ahs[4096], Als[4096], Bhs[4096], Bls[4096];
    __shared__ double wred[8][2];
    __shared__ int lastFlag;
    int tid = threadIdx.x, lane = tid & 63, wave = tid >> 6;
    int bn = blockIdx.x * 128, bo = blockIdx.y * 128;
    int wm = wave >> 2, wq = wave & 3;

    int rL = lane >> 2, cL = lane & 3;
    int cs = cL ^ ((rL >> 1) & 3);
    int row16 = wave*16 + rL;
    size_t aoff = (size_t)(bn + row16) * Kp + cs*8;
    size_t boff = (size_t)(bo + row16) * Kp + cs*8;
    ushort* lAh = Ahs + wave*512;
    ushort* lAl = Als + wave*512;
    ushort* lBh = Bhs + wave*512;
    ushort* lBl = Bls + wave*512;

    int rl = lane & 15, kh = lane >> 4;
    int kbs_r = kh ^ ((rl >> 1) & 3);
    int raoff[4], rboff[2];
#pragma unroll
    for (int mf = 0; mf < 4; ++mf) raoff[mf] = (wm*64 + mf*16 + rl)*64 + kbs_r*16;
#pragma unroll
    for (int nf = 0; nf < 2; ++nf) rboff[nf] = (wq*32 + nf*16 + rl)*64 + kbs_r*16;

    f32x4 acc[4][2];
#pragma unroll
    for (int mf = 0; mf < 4; ++mf)
#pragma unroll
        for (int nf = 0; nf < 2; ++nf) acc[mf][nf] = (f32x4){0.f,0.f,0.f,0.f};

    int NT = Kp >> 5;
    for (int t = 0; t < NT; ++t) {
        int k0 = t*32;
        GL16(Yh + aoff + k0, lAh);
        GL16(Yl + aoff + k0, lAl);
        GL16(Wh + boff + k0, lBh);
        GL16(Wl + boff + k0, lBl);
        __syncthreads();
        short8 a_h[4], a_l[4];
#pragma unroll
        for (int mf = 0; mf < 4; ++mf) {
            a_h[mf] = *(const short8*)((const char*)Ahs + raoff[mf]);
            a_l[mf] = *(const short8*)((const char*)Als + raoff[mf]);
        }
#pragma unroll
        for (int nf = 0; nf < 2; ++nf) {
            short8 b_h = *(const short8*)((const char*)Bhs + rboff[nf]);
            short8 b_l = *(const short8*)((const char*)Bls + rboff[nf]);
#pragma unroll
            for (int mf = 0; mf < 4; ++mf) {
                acc[mf][nf] = __builtin_amdgcn_mfma_f32_16x16x32_bf16(a_h[mf], b_h, acc[mf][nf], 0, 0, 0);
                acc[mf][nf] = __builtin_amdgcn_mfma_f32_16x16x32_bf16(a_h[mf], b_l, acc[mf][nf], 0, 0, 0);
                acc[mf][nf] = __builtin_amdgcn_mfma_f32_16x16x32_bf16(a_l[mf], b_h, acc[mf][nf], 0, 0, 0);
            }
        }
        __syncthreads();
    }

    double lsum = 0.0, lsq = 0.0;
#pragma unroll
    for (int mf = 0; mf < 4; ++mf) {
#pragma unroll
        for (int r = 0; r < 4; ++r) {
            int n = bn + wm*64 + mf*16 + kh*4 + r;
            float pv = pn[n];
#pragma unroll
            for (int nf = 0; nf < 2; ++nf) {
                int o = bo + wq*32 + nf*16 + rl;
                if (o < O) {
                    float d2 = pv + wn[o] - 2.f*acc[mf][nf][r];
                    float dd = FSQRT(fmaxf(d2, 1e-12f));
                    D[(size_t)n*O + o] = dd;
                    lsum += dd; lsq += (double)dd*dd;
                }
            }
        }
    }
    for (int off = 32; off > 0; off >>= 1) {
        lsum += __shfl_down(lsum, off, 64);
        lsq  += __shfl_down(lsq,  off, 64);
    }
    if (lane == 0) { wred[wave][0] = lsum; wred[wave][1] = lsq; }
    __syncthreads();
    if (tid == 0) {
        double s = 0.0, q = 0.0;
#pragma unroll
        for (int w = 0; w < 8; ++w) { s += wred[w][0]; q += wred[w][1]; }
        int bid = blockIdx.y * gridDim.x + blockIdx.x;
        part[2*bid]   = s;
        part[2*bid+1] = q;
        __threadfence();                       // publish partial (device scope)
        uint old = atomicAdd(counter, 1u);
        lastFlag = (old == (uint)(nb - 1));
    }
    __syncthreads();
    if (lastFlag) {
        __threadfence();                       // acquire all partials
        double* ss = (double*)Ahs;             // reuse tile LDS as reduce scratch
        double* qq = (double*)Bhs;
        double s = 0.0, q = 0.0;
        for (int i = tid; i < nb; i += 512) { s += part[2*i]; q += part[2*i+1]; }
        ss[tid] = s; qq[tid] = q;
        __syncthreads();
        for (int st = 256; st > 0; st >>= 1) {
            if (tid < st) { ss[tid] += ss[tid+st]; qq[tid] += qq[tid+st]; }
            __syncthreads();
        }
        if (tid == 0) {
            double m = ss[0] / Nstat;
            double var = (qq[0] - Nstat*m*m) / (Nstat - 1.0);
            scaleDst[0] = (float)(0.5 / var);
            *counter = 0;                      // deterministic across graph replays
        }
    }
}

// exp+crelu(0.01)+FC: dist4 [4096,1225] -> out [4096,10]
__global__ __launch_bounds__(256) void fc_kernel(
    const float* __restrict__ dist4, const float* __restrict__ scale,
    const float* __restrict__ fcw, const float* __restrict__ fcb,
    float* __restrict__ out) {
    int b = blockIdx.x;
    int tid = threadIdx.x;
    float s4 = scale[0];
    float acc[10] = {};
    for (int o = tid; o < 1225; o += 256) {
        float d = dist4[(size_t)b*1225 + o];
        float v = __expf(-d*d*s4);
        v = (v >= 0.01f) ? v : 0.f;
#pragma unroll
        for (int k = 0; k < 10; ++k) acc[k] += v * fcw[k*1225 + o];
    }
    __shared__ float red[10*256];
#pragma unroll
    for (int k = 0; k < 10; ++k) red[k*256 + tid] = acc[k];
    __syncthreads();
    for (int st = 128; st > 0; st >>= 1) {
        if (tid < st) {
#pragma unroll
            for (int k = 0; k < 10; ++k) red[k*256 + tid] += red[k*256 + tid + st];
        }
        __syncthreads();
    }
    if (tid < 10) out[b*10 + tid] = red[tid*256] + fcb[tid];
}

extern "C" void kernel_launch(void* const* d_in, const int* in_sizes, int n_in,
                              void* d_out, int out_size, void* d_ws, size_t ws_size,
                              hipStream_t stream) {
    const float* x     = (const float*)d_in[0];
    const float* rgb_w = (const float*)d_in[1];
    const float* w2    = (const float*)d_in[2];
    const float* w3    = (const float*)d_in[3];
    const float* w4    = (const float*)d_in[4];
    const float* fc_w  = (const float*)d_in[5];
    const float* fc_b  = (const float*)d_in[6];
    float* out = (float*)d_out;

    float* wsf   = (float*)d_ws;
    float* dist  = wsf;                    // 14,745,600 floats
    float* ybuf  = wsf + 14745600;         // 3,686,400 floats
    float* pnb   = ybuf + 3686400;         // 36,864 floats
    float* wnb   = pnb + 36864;            // 1,280
    float* scale = wnb + 1280;             // 64
    double* stats = (double*)(scale + 64); // 78 doubles (zeroed each launch)
    double* pblk  = stats + 78;            // 1152 doubles
    float* wsend  = (float*)(pblk + 1152);

    uint* ctr = (uint*)(stats + 72);       // 3 counters inside zeroed stats region

    ushort* W1h = (ushort*)pnb;
    ushort* W1l = W1h + 10752;
    float*  wn1 = (float*)(W1l + 10752);

    float* pixstat = ybuf;                 // 1024*72 floats

    size_t base_floats = (size_t)(wsend - wsf);
    size_t y2_floats   = 2u * 36864u * 128u / 2u;
    bool roomy = ws_size >= (base_floats + y2_floats + 1024) * sizeof(float);

    ushort* Y2h = roomy ? (ushort*)wsend : (ushort*)(dist + 8388608);
    ushort* Y2l = Y2h + 36864*128;
    ushort* W2h = (ushort*)(dist + 8388608) + 2*36864*128;
    ushort* W2l = W2h + 256*128;
    ushort* Y3h = (ushort*)ybuf;
    ushort* Y3l = Y3h + 12288*256;
    ushort* W3h = Y3l + 12288*256;
    ushort* W3l = W3h + 640*256;
    ushort* Y4h = (ushort*)ybuf;
    ushort* Y4l = Y4h + 4096*640;
    ushort* W4h = Y4l + 4096*640;
    ushort* W4l = W4h + 1280*640;

    // ---- layer 1 ----
    w1split_kernel<<<DIV_UP(112*96,256), 256, 0, stream>>>(rgb_w, W1h, W1l, stats);
    w1norm_kernel<<<DIV_UP(336,64), 64, 0, stream>>>(W1h, W1l, wn1);
    rbf1_mfma<<<1024, 512, 0, stream>>>(x, W1h, W1l, wn1, dist, pixstat);
    finalize36_kernel<<<36, 256, 0, stream>>>(pixstat, scale);

    // ---- layer 1 -> 2 transition ----
    if (roomy) {
        sfm1s_kernel<<<36864/4, 256, 0, stream>>>(dist, scale, Y2h, Y2l, pnb);
    } else {
        sfm1_kernel<<<DIV_UP(36864*100,256), 256, 0, stream>>>(dist, scale, ybuf);
        splitnorm_kernel<<<36864/4, 256, 0, stream>>>(ybuf, Y2h, Y2l, pnb, 36864, 100, 128);
    }
    splitnorm_kernel<<<256/4, 256, 0, stream>>>(w2, W2h, W2l, wnb, 225, 100, 128);

    // ---- layer 2 (scale computed by last distg block) ----
    distg_mfma<<<dim3(288,2), 512, 0, stream>>>(Y2h, Y2l, W2h, W2l, pnb, wnb, dist,
                                                36864, 225, 128, pblk, 576, scale + 36,
                                                8294400.0, ctr + 0);
    sfm2s_kernel<<<12288/4, 256, 0, stream>>>(dist, scale + 36, Y3h, Y3l, pnb);

    // ---- layer 3 ----
    splitnorm_kernel<<<640/4, 256, 0, stream>>>(w3, W3h, W3l, wnb, 625, 225, 256);
    distg_mfma<<<dim3(96,5), 512, 0, stream>>>(Y3h, Y3l, W3h, W3l, pnb, wnb, dist,
                                               12288, 625, 256, pblk, 480, scale + 37,
                                               7680000.0, ctr + 1);
    sfm3s_kernel<<<4096/4, 256, 0, stream>>>(dist, scale + 37, Y4h, Y4l, pnb);

    // ---- layer 4 ----
    splitnorm_kernel<<<1280/4, 256, 0, stream>>>(w4, W4h, W4l, wnb, 1225, 625, 640);
    distg_mfma<<<dim3(32,10), 512, 0, stream>>>(Y4h, Y4l, W4h, W4l, pnb, wnb, dist,
                                                4096, 1225, 640, pblk, 320, scale + 38,
                                                5017600.0, ctr + 2);

    // ---- FC ----
    fc_kernel<<<4096, 256, 0, stream>>>(dist, scale + 38, fc_w, fc_b, out);
}

// Round 19
// 205.659 us; speedup vs baseline: 1.1915x; 1.1915x over previous
//
#include <hip/hip_runtime.h>
#include <hip/hip_bf16.h>
#include <math.h>

#define DIV_UP(a,b) (((a)+(b)-1)/(b))
#define FSQRT(x) __builtin_amdgcn_sqrtf(x)

typedef __attribute__((ext_vector_type(8))) short short8;
typedef __attribute__((ext_vector_type(4))) float f32x4;

// async global->LDS, 16B per lane; gptr per-lane, lptr wave-uniform
#define GL16(g, l) __builtin_amdgcn_global_load_lds( \
    (const __attribute__((address_space(1))) void*)(g), \
    (__attribute__((address_space(3))) void*)(l), 16, 0, 0)

// ---------------- W1 prep (+stats zero folded in) ----------------
__global__ __launch_bounds__(256) void w1split_kernel(
    const float* __restrict__ w, ushort* __restrict__ Wh, ushort* __restrict__ Wl,
    double* __restrict__ stats) {
    if (blockIdx.x == 0 && threadIdx.x < 78) stats[threadIdx.x] = 0.0;
    int e = blockIdx.x*256 + threadIdx.x;
    if (e >= 112*96) return;
    int o = e / 96, kk = e - o*96, c = kk >> 5, k = kk & 31;
    float v = (o < 100 && k < 25) ? w[o*75 + c*25 + k] : 0.f;
    __hip_bfloat16 hb = __float2bfloat16(v);
    float hf = __bfloat162float(hb);
    __hip_bfloat16 lb = __float2bfloat16(v - hf);
    Wh[e] = *(ushort*)&hb;
    Wl[e] = *(ushort*)&lb;
}

__global__ __launch_bounds__(64) void w1norm_kernel(
    const ushort* __restrict__ Wh, const ushort* __restrict__ Wl, float* __restrict__ wn1) {
    int j = blockIdx.x*64 + threadIdx.x;
    if (j >= 336) return;
    int o = j / 3, c = j - o*3;
    const ushort* h = Wh + o*96 + c*32;
    const ushort* l = Wl + o*96 + c*32;
    float s = 0.f;
#pragma unroll
    for (int k = 0; k < 25; ++k) {
        ushort hu = h[k], lu = l[k];
        float v = __bfloat162float(*(__hip_bfloat16*)&hu) + __bfloat162float(*(__hip_bfloat16*)&lu);
        s += v*v;
    }
    wn1[j] = s;
}

// ---------------- layer 1 MFMA (+fused stats, per-wave private LDS, no atomics) ----------------
__global__ __launch_bounds__(512, 2) void rbf1_mfma(
    const float* __restrict__ x, const ushort* __restrict__ Wh, const ushort* __restrict__ Wl,
    const float* __restrict__ wn1, float* __restrict__ dist1,
    float* __restrict__ pixstat) {
    __shared__ ushort Ah[3*144*32];
    __shared__ ushort Al[3*144*32];
    __shared__ float pnl[432];
    __shared__ float rstat[7*144*2];   // [wave][row][sum,sq] — every slot written, no init
    int tid = threadIdx.x;
    int b4 = blockIdx.x;

    if (tid < 432) {
        int row = tid / 3, c = tid - row*3;
        int img = row / 36, p = row - img*36;
        int ph = p / 6, pw = p - ph*6;
        const float* xp = x + (size_t)b4*9408 + img*2352 + c*784 + (ph*28 + pw)*4;
        float arr[25];
#pragma unroll
        for (int ki = 0; ki < 5; ++ki) {
            float4 v4 = *(const float4*)(xp + ki*28);
            arr[ki*5+0] = v4.x; arr[ki*5+1] = v4.y;
            arr[ki*5+2] = v4.z; arr[ki*5+3] = v4.w;
            arr[ki*5+4] = xp[ki*28 + 4];
        }
        float pnc = 0.f;
        int tilebase = c*9216 + row*64;
        int r3 = (row >> 1) & 3;
#pragma unroll
        for (int kb = 0; kb < 4; ++kb) {
            uint4 hq, lq;
            uint* hqa = (uint*)&hq;
            uint* lqa = (uint*)&lq;
#pragma unroll
            for (int j = 0; j < 4; ++j) {
                int k0 = kb*8 + 2*j;
                float v0 = (k0 < 25) ? arr[k0] : 0.f;
                float v1 = (k0+1 < 25) ? arr[k0+1] : 0.f;
                __hip_bfloat16 h0 = __float2bfloat16(v0);
                float hf0 = __bfloat162float(h0);
                __hip_bfloat16 l0 = __float2bfloat16(v0 - hf0);
                float r0 = hf0 + __bfloat162float(l0);
                __hip_bfloat16 h1 = __float2bfloat16(v1);
                float hf1 = __bfloat162float(h1);
                __hip_bfloat16 l1 = __float2bfloat16(v1 - hf1);
                float r1 = hf1 + __bfloat162float(l1);
                pnc += r0*r0 + r1*r1;
                hqa[j] = (uint)(*(ushort*)&h0) | ((uint)(*(ushort*)&h1) << 16);
                lqa[j] = (uint)(*(ushort*)&l0) | ((uint)(*(ushort*)&l1) << 16);
            }
            int kbs = kb ^ r3;
            *(uint4*)((char*)Ah + tilebase + kbs*16) = hq;
            *(uint4*)((char*)Al + tilebase + kbs*16) = lq;
        }
        pnl[tid] = pnc;
    }
    __syncthreads();

    int lane = tid & 63, wave = tid >> 6;
    if (wave < 7) {
        int nf = wave;
        int rl = lane & 15, kh = lane >> 4;
        int o = nf*16 + rl;
        const ushort* bhp = Wh + o*96 + kh*8;
        const ushort* blp = Wl + o*96 + kh*8;
        short8 bh0 = *(const short8*)(bhp);
        short8 bh1 = *(const short8*)(bhp + 32);
        short8 bh2 = *(const short8*)(bhp + 64);
        short8 bl0 = *(const short8*)(blp);
        short8 bl1 = *(const short8*)(blp + 32);
        short8 bl2 = *(const short8*)(blp + 64);
        float w0 = wn1[o*3], w1v = wn1[o*3+1], w2v = wn1[o*3+2];
        int swz = (rl >> 1) & 3;
        int kx = (kh ^ swz) * 16;
        bool valid = (o < 100);
        float* mystat = rstat + wave*288;
#pragma unroll
        for (int mf = 0; mf < 9; ++mf) {
            int rbase = (mf*16 + rl)*64;
            short8 ah0 = *(const short8*)((const char*)Ah + rbase + kx);
            short8 al0 = *(const short8*)((const char*)Al + rbase + kx);
            short8 ah1 = *(const short8*)((const char*)Ah + 9216 + rbase + kx);
            short8 al1 = *(const short8*)((const char*)Al + 9216 + rbase + kx);
            short8 ah2 = *(const short8*)((const char*)Ah + 18432 + rbase + kx);
            short8 al2 = *(const short8*)((const char*)Al + 18432 + rbase + kx);
            f32x4 a0 = {0.f,0.f,0.f,0.f}, a1 = {0.f,0.f,0.f,0.f}, a2 = {0.f,0.f,0.f,0.f};
            a0 = __builtin_amdgcn_mfma_f32_16x16x32_bf16(ah0, bh0, a0, 0, 0, 0);
            a1 = __builtin_amdgcn_mfma_f32_16x16x32_bf16(ah1, bh1, a1, 0, 0, 0);
            a2 = __builtin_amdgcn_mfma_f32_16x16x32_bf16(ah2, bh2, a2, 0, 0, 0);
            a0 = __builtin_amdgcn_mfma_f32_16x16x32_bf16(ah0, bl0, a0, 0, 0, 0);
            a1 = __builtin_amdgcn_mfma_f32_16x16x32_bf16(ah1, bl1, a1, 0, 0, 0);
            a2 = __builtin_amdgcn_mfma_f32_16x16x32_bf16(ah2, bl2, a2, 0, 0, 0);
            a0 = __builtin_amdgcn_mfma_f32_16x16x32_bf16(al0, bh0, a0, 0, 0, 0);
            a1 = __builtin_amdgcn_mfma_f32_16x16x32_bf16(al1, bh1, a1, 0, 0, 0);
            a2 = __builtin_amdgcn_mfma_f32_16x16x32_bf16(al2, bh2, a2, 0, 0, 0);
            float dsum[4], dsq[4];
            size_t base = (size_t)(b4*144 + mf*16 + kh*4)*100 + o;
#pragma unroll
            for (int r = 0; r < 4; ++r) {
                int row = mf*16 + kh*4 + r;
                float d = FSQRT(fmaxf(pnl[row*3+0] + w0  - 2.f*a0[r], 1e-12f))
                        + FSQRT(fmaxf(pnl[row*3+1] + w1v - 2.f*a1[r], 1e-12f))
                        + FSQRT(fmaxf(pnl[row*3+2] + w2v - 2.f*a2[r], 1e-12f));
                float dv = valid ? d : 0.f;
                if (valid) dist1[base + (size_t)r*100] = d;
                dsum[r] = dv; dsq[r] = dv*dv;
            }
            // full 16-lane reduce within rl group; rl==0 lane holds row sums
#pragma unroll
            for (int m = 1; m <= 8; m <<= 1) {
#pragma unroll
                for (int r = 0; r < 4; ++r) {
                    dsum[r] += __shfl_xor(dsum[r], m, 64);
                    dsq[r]  += __shfl_xor(dsq[r],  m, 64);
                }
            }
            if (rl == 0) {
#pragma unroll
                for (int r = 0; r < 4; ++r) {
                    int row = mf*16 + kh*4 + r;
                    mystat[row*2]     = dsum[r];   // plain stores: private region
                    mystat[row*2 + 1] = dsq[r];
                }
            }
        }
    }
    __syncthreads();
    // pixel p partial = sum over 7 waves x 4 images (row = p + 36*g)
    if (tid < 72) {
        int p = tid >> 1, w = tid & 1;
        float s = 0.f;
#pragma unroll
        for (int wv = 0; wv < 7; ++wv)
#pragma unroll
            for (int g = 0; g < 4; ++g)
                s += rstat[wv*288 + (p + 36*g)*2 + w];
        pixstat[(size_t)b4*72 + 2*p + w] = s;
    }
}

// reduce per-block pixel partials -> scale[p], p = blockIdx.x (36 blocks)
__global__ __launch_bounds__(256) void finalize36_kernel(
    const float* __restrict__ pixstat, float* __restrict__ scale) {
    __shared__ double ss[256], qq[256];
    int p = blockIdx.x, tid = threadIdx.x;
    double s = 0.0, q = 0.0;
    for (int b = tid; b < 1024; b += 256) {
        s += (double)pixstat[(size_t)b*72 + 2*p];
        q += (double)pixstat[(size_t)b*72 + 2*p + 1];
    }
    ss[tid] = s; qq[tid] = q; __syncthreads();
    for (int st = 128; st > 0; st >>= 1) {
        if (tid < st) { ss[tid] += ss[tid+st]; qq[tid] += qq[tid+st]; }
        __syncthreads();
    }
    if (tid == 0) {
        const double N = 409600.0;
        double m = ss[0] / N;
        double var = (qq[0] - N*m*m) / (N - 1.0);
        scale[p] = (float)(0.5 / var);
    }
}

// reduce per-block partials (no atomics) and compute scale
__global__ __launch_bounds__(256) void finalize_part_kernel(
    const double* __restrict__ part, int nb,
    float* __restrict__ scale, int scaleOff, double N) {
    __shared__ double ss[256], qq[256];
    int tid = threadIdx.x;
    double s = 0.0, q = 0.0;
    for (int i = tid; i < nb; i += 256) { s += part[2*i]; q += part[2*i+1]; }
    ss[tid] = s; qq[tid] = q; __syncthreads();
    for (int st = 128; st > 0; st >>= 1) {
        if (tid < st) { ss[tid] += ss[tid+st]; qq[tid] += qq[tid+st]; }
        __syncthreads();
    }
    if (tid == 0) {
        double m = ss[0] / N;
        double var = (qq[0] - N*m*m) / (N - 1.0);
        scale[scaleOff] = (float)(0.5 / var);
    }
}

// exp+crelu(0.4)+SFM1: dist1 -> y2 [36864,100] (fallback path)
__global__ __launch_bounds__(256) void sfm1_kernel(
    const float* __restrict__ dist1, const float* __restrict__ scale,
    float* __restrict__ y2) {
    int gid = blockIdx.x*256 + threadIdx.x;
    if (gid >= 36864*100) return;
    int c = gid % 100, n = gid / 100;
    int b = n / 9, ij = n % 9, i = ij / 3, j = ij % 3;
    const float alpha[2][2] = {{0.729f, 0.81f},{0.9f, 1.0f}};
    float acc = 0.f;
#pragma unroll
    for (int fh = 0; fh < 2; ++fh)
#pragma unroll
        for (int fw = 0; fw < 2; ++fw) {
            int p = (2*i+fh)*6 + (2*j+fw);
            float d = dist1[(size_t)b*3600 + p*100 + c];
            float v = __expf(-d*d*scale[p]);
            v = (v >= 0.4f) ? v : 0.f;
            acc += alpha[fh][fw]*v;
        }
    y2[gid] = 0.25f * acc;
}

// fused exp+crelu+SFM1+split+norm: dist1 -> Y2 planes [36864][128] + norms (roomy path)
__global__ __launch_bounds__(256) void sfm1s_kernel(
    const float* __restrict__ dist1, const float* __restrict__ scale,
    ushort* __restrict__ H, ushort* __restrict__ L, float* __restrict__ norm) {
    int wave = threadIdx.x >> 6, lane = threadIdx.x & 63;
    int n = blockIdx.x*4 + wave;       // 0..36863
    int b = n / 9, ij = n % 9, i = ij / 3, j = ij % 3;
    const float alpha[2][2] = {{0.729f, 0.81f},{0.9f, 1.0f}};
    float s = 0.f;
#pragma unroll
    for (int q = 0; q < 2; ++q) {
        int k = lane + q*64;
        float y = 0.f;
        if (k < 100) {
            float acc = 0.f;
#pragma unroll
            for (int fh = 0; fh < 2; ++fh)
#pragma unroll
                for (int fw = 0; fw < 2; ++fw) {
                    int p = (2*i+fh)*6 + (2*j+fw);
                    float d = dist1[(size_t)b*3600 + p*100 + k];
                    float v = __expf(-d*d*scale[p]);
                    v = (v >= 0.4f) ? v : 0.f;
                    acc += alpha[fh][fw]*v;
                }
            y = 0.25f * acc;
        }
        __hip_bfloat16 hb = __float2bfloat16(y);
        float hf = __bfloat162float(hb);
        __hip_bfloat16 lb = __float2bfloat16(y - hf);
        H[(size_t)n*128 + k] = *(ushort*)&hb;
        L[(size_t)n*128 + k] = *(ushort*)&lb;
        float r = hf + __bfloat162float(lb);
        s += r*r;
    }
    for (int off = 32; off > 0; off >>= 1) s += __shfl_down(s, off, 64);
    if (lane == 0) norm[n] = s;
}

// fused split+pad+rownorm: one wave per row
__global__ __launch_bounds__(256) void splitnorm_kernel(
    const float* __restrict__ src, ushort* __restrict__ H, ushort* __restrict__ L,
    float* __restrict__ norm, int R, int K, int Kp) {
    int wave = threadIdx.x >> 6, lane = threadIdx.x & 63;
    int row = blockIdx.x*4 + wave;
    float s = 0.f;
    if (row < R) {
        for (int k = lane; k < Kp; k += 64) {
            float v = (k < K) ? src[(size_t)row*K + k] : 0.f;
            __hip_bfloat16 hb = __float2bfloat16(v);
            float hf = __bfloat162float(hb);
            __hip_bfloat16 lb = __float2bfloat16(v - hf);
            H[(size_t)row*Kp + k] = *(ushort*)&hb;
            L[(size_t)row*Kp + k] = *(ushort*)&lb;
            float r = hf + __bfloat162float(lb);
            s += r*r;
        }
    } else {
        for (int k = lane; k < Kp; k += 64) {
            H[(size_t)row*Kp + k] = 0;
            L[(size_t)row*Kp + k] = 0;
        }
    }
    for (int off = 32; off > 0; off >>= 1) s += __shfl_down(s, off, 64);
    if (lane == 0) norm[row] = s;
}

// fused exp+crelu+SFM2+split+norm
__global__ __launch_bounds__(256) void sfm2s_kernel(
    const float* __restrict__ dist2, const float* __restrict__ scale,
    ushort* __restrict__ H, ushort* __restrict__ L, float* __restrict__ norm) {
    int wave = threadIdx.x >> 6, lane = threadIdx.x & 63;
    int n2 = blockIdx.x*4 + wave;
    int b = n2 / 3, i = n2 % 3;
    float s2 = scale[0];
    const float alphaJ[3] = {0.81f, 0.9f, 1.0f};
    float s = 0.f;
#pragma unroll
    for (int q = 0; q < 4; ++q) {
        int k = lane + q*64;
        float y = 0.f;
        if (k < 225) {
            float acc = 0.f;
#pragma unroll
            for (int j = 0; j < 3; ++j) {
                float d = dist2[((size_t)(b*9 + i*3 + j))*225 + k];
                float v = __expf(-d*d*s2);
                v = (v >= 0.1f) ? v : 0.f;
                acc += alphaJ[j]*v;
            }
            y = acc * (1.f/3.f);
        }
        __hip_bfloat16 hb = __float2bfloat16(y);
        float hf = __bfloat162float(hb);
        __hip_bfloat16 lb = __float2bfloat16(y - hf);
        H[(size_t)n2*256 + k] = *(ushort*)&hb;
        L[(size_t)n2*256 + k] = *(ushort*)&lb;
        float r = hf + __bfloat162float(lb);
        s += r*r;
    }
    for (int off = 32; off > 0; off >>= 1) s += __shfl_down(s, off, 64);
    if (lane == 0) norm[n2] = s;
}

// fused exp+crelu+SFM3+split+norm
__global__ __launch_bounds__(256) void sfm3s_kernel(
    const float* __restrict__ dist3, const float* __restrict__ scale,
    ushort* __restrict__ H, ushort* __restrict__ L, float* __restrict__ norm) {
    int wave = threadIdx.x >> 6, lane = threadIdx.x & 63;
    int b = blockIdx.x*4 + wave;
    float s3 = scale[0];
    const float alphaI[3] = {0.81f, 0.9f, 1.0f};
    float s = 0.f;
#pragma unroll
    for (int q = 0; q < 10; ++q) {
        int k = lane + q*64;
        float y = 0.f;
        if (k < 625) {
            float acc = 0.f;
#pragma unroll
            for (int i = 0; i < 3; ++i) {
                float d = dist3[((size_t)(b*3 + i))*625 + k];
                float v = __expf(-d*d*s3);
                v = (v >= 0.01f) ? v : 0.f;
                acc += alphaI[i]*v;
            }
            y = acc * (1.f/3.f);
        }
        __hip_bfloat16 hb = __float2bfloat16(y);
        float hf = __bfloat162float(hb);
        __hip_bfloat16 lb = __float2bfloat16(y - hf);
        H[(size_t)b*640 + k] = *(ushort*)&hb;
        L[(size_t)b*640 + k] = *(ushort*)&lb;
        float r = hf + __bfloat162float(lb);
        s += r*r;
    }
    for (int off = 32; off > 0; off >>= 1) s += __shfl_down(s, off, 64);
    if (lane == 0) norm[b] = s;
}

// ---------------- unified dist GEMM: 128x128, 8 WAVES, gl_lds single-buffer ----------------
__global__ __launch_bounds__(512, 4) void distg_mfma(
    const ushort* __restrict__ Yh, const ushort* __restrict__ Yl,   // [N][Kp]
    const ushort* __restrict__ Wh, const ushort* __restrict__ Wl,   // [Opad][Kp]
    const float* __restrict__ pn, const float* __restrict__ wn,
    float* __restrict__ D, int N, int O, int Kp,
    double* __restrict__ part) {
    __shared__ ushort Ahs[4096], Als[4096], Bhs[4096], Bls[4096];
    __shared__ double wred[8][2];
    int tid = threadIdx.x, lane = tid & 63, wave = tid >> 6;
    int bn = blockIdx.x * 128, bo = blockIdx.y * 128;
    int wm = wave >> 2, wq = wave & 3;

    int rL = lane >> 2, cL = lane & 3;
    int cs = cL ^ ((rL >> 1) & 3);
    int row16 = wave*16 + rL;
    size_t aoff = (size_t)(bn + row16) * Kp + cs*8;
    size_t boff = (size_t)(bo + row16) * Kp + cs*8;
    ushort* lAh = Ahs + wave*512;
    ushort* lAl = Als + wave*512;
    ushort* lBh = Bhs + wave*512;
    ushort* lBl = Bls + wave*512;

    int rl = lane & 15, kh = lane >> 4;
    int kbs_r = kh ^ ((rl >> 1) & 3);
    int raoff[4], rboff[2];
#pragma unroll
    for (int mf = 0; mf < 4; ++mf) raoff[mf] = (wm*64 + mf*16 + rl)*64 + kbs_r*16;
#pragma unroll
    for (int nf = 0; nf < 2; ++nf) rboff[nf] = (wq*32 + nf*16 + rl)*64 + kbs_r*16;

    f32x4 acc[4][2];
#pragma unroll
    for (int mf = 0; mf < 4; ++mf)
#pragma unroll
        for (int nf = 0; nf < 2; ++nf) acc[mf][nf] = (f32x4){0.f,0.f,0.f,0.f};

    int NT = Kp >> 5;
    for (int t = 0; t < NT; ++t) {
        int k0 = t*32;
        GL16(Yh + aoff + k0, lAh);
        GL16(Yl + aoff + k0, lAl);
        GL16(Wh + boff + k0, lBh);
        GL16(Wl + boff + k0, lBl);
        __syncthreads();
        short8 a_h[4], a_l[4];
#pragma unroll
        for (int mf = 0; mf < 4; ++mf) {
            a_h[mf] = *(const short8*)((const char*)Ahs + raoff[mf]);
            a_l[mf] = *(const short8*)((const char*)Als + raoff[mf]);
        }
#pragma unroll
        for (int nf = 0; nf < 2; ++nf) {
            short8 b_h = *(const short8*)((const char*)Bhs + rboff[nf]);
            short8 b_l = *(const short8*)((const char*)Bls + rboff[nf]);
#pragma unroll
            for (int mf = 0; mf < 4; ++mf) {
                acc[mf][nf] = __builtin_amdgcn_mfma_f32_16x16x32_bf16(a_h[mf], b_h, acc[mf][nf], 0, 0, 0);
                acc[mf][nf] = __builtin_amdgcn_mfma_f32_16x16x32_bf16(a_h[mf], b_l, acc[mf][nf], 0, 0, 0);
                acc[mf][nf] = __builtin_amdgcn_mfma_f32_16x16x32_bf16(a_l[mf], b_h, acc[mf][nf], 0, 0, 0);
            }
        }
        __syncthreads();
    }

    double lsum = 0.0, lsq = 0.0;
#pragma unroll
    for (int mf = 0; mf < 4; ++mf) {
#pragma unroll
        for (int r = 0; r < 4; ++r) {
            int n = bn + wm*64 + mf*16 + kh*4 + r;
            float pv = pn[n];
#pragma unroll
            for (int nf = 0; nf < 2; ++nf) {
                int o = bo + wq*32 + nf*16 + rl;
                if (o < O) {
                    float d2 = pv + wn[o] - 2.f*acc[mf][nf][r];
                    float dd = FSQRT(fmaxf(d2, 1e-12f));
                    D[(size_t)n*O + o] = dd;
                    lsum += dd; lsq += (double)dd*dd;
                }
            }
        }
    }
    for (int off = 32; off > 0; off >>= 1) {
        lsum += __shfl_down(lsum, off, 64);
        lsq  += __shfl_down(lsq,  off, 64);
    }
    if (lane == 0) { wred[wave][0] = lsum; wred[wave][1] = lsq; }
    __syncthreads();
    if (tid == 0) {
        double s = 0.0, q = 0.0;
#pragma unroll
        for (int w = 0; w < 8; ++w) { s += wred[w][0]; q += wred[w][1]; }
        int bid = blockIdx.y * gridDim.x + blockIdx.x;
        part[2*bid]   = s;
        part[2*bid+1] = q;
    }
}

// exp+crelu(0.01)+FC: dist4 [4096,1225] -> out [4096,10]
__global__ __launch_bounds__(256) void fc_kernel(
    const float* __restrict__ dist4, const float* __restrict__ scale,
    const float* __restrict__ fcw, const float* __restrict__ fcb,
    float* __restrict__ out) {
    int b = blockIdx.x;
    int tid = threadIdx.x;
    float s4 = scale[0];
    float acc[10] = {};
    for (int o = tid; o < 1225; o += 256) {
        float d = dist4[(size_t)b*1225 + o];
        float v = __expf(-d*d*s4);
        v = (v >= 0.01f) ? v : 0.f;
#pragma unroll
        for (int k = 0; k < 10; ++k) acc[k] += v * fcw[k*1225 + o];
    }
    __shared__ float red[10*256];
#pragma unroll
    for (int k = 0; k < 10; ++k) red[k*256 + tid] = acc[k];
    __syncthreads();
    for (int st = 128; st > 0; st >>= 1) {
        if (tid < st) {
#pragma unroll
            for (int k = 0; k < 10; ++k) red[k*256 + tid] += red[k*256 + tid + st];
        }
        __syncthreads();
    }
    if (tid < 10) out[b*10 + tid] = red[tid*256] + fcb[tid];
}

extern "C" void kernel_launch(void* const* d_in, const int* in_sizes, int n_in,
                              void* d_out, int out_size, void* d_ws, size_t ws_size,
                              hipStream_t stream) {
    const float* x     = (const float*)d_in[0];
    const float* rgb_w = (const float*)d_in[1];
    const float* w2    = (const float*)d_in[2];
    const float* w3    = (const float*)d_in[3];
    const float* w4    = (const float*)d_in[4];
    const float* fc_w  = (const float*)d_in[5];
    const float* fc_b  = (const float*)d_in[6];
    float* out = (float*)d_out;

    float* wsf   = (float*)d_ws;
    float* dist  = wsf;                    // 14,745,600 floats
    float* ybuf  = wsf + 14745600;         // 3,686,400 floats
    float* pnb   = ybuf + 3686400;         // 36,864 floats
    float* wnb   = pnb + 36864;            // 1,280
    float* scale = wnb + 1280;             // 64
    double* stats = (double*)(scale + 64); // 78 doubles
    double* pblk  = stats + 78;            // 1152 doubles
    float* wsend  = (float*)(pblk + 1152);

    ushort* W1h = (ushort*)pnb;
    ushort* W1l = W1h + 10752;
    float*  wn1 = (float*)(W1l + 10752);

    float* pixstat = ybuf;

    size_t base_floats = (size_t)(wsend - wsf);
    size_t y2_floats   = 2u * 36864u * 128u / 2u;
    bool roomy = ws_size >= (base_floats + y2_floats + 1024) * sizeof(float);

    ushort* Y2h = roomy ? (ushort*)wsend : (ushort*)(dist + 8388608);
    ushort* Y2l = Y2h + 36864*128;
    ushort* W2h = (ushort*)(dist + 8388608) + 2*36864*128;
    ushort* W2l = W2h + 256*128;
    ushort* Y3h = (ushort*)ybuf;
    ushort* Y3l = Y3h + 12288*256;
    ushort* W3h = Y3l + 12288*256;
    ushort* W3l = W3h + 640*256;
    ushort* Y4h = (ushort*)ybuf;
    ushort* Y4l = Y4h + 4096*640;
    ushort* W4h = Y4l + 4096*640;
    ushort* W4l = W4h + 1280*640;

    // ---- layer 1 ----
    w1split_kernel<<<DIV_UP(112*96,256), 256, 0, stream>>>(rgb_w, W1h, W1l, stats);
    w1norm_kernel<<<DIV_UP(336,64), 64, 0, stream>>>(W1h, W1l, wn1);
    rbf1_mfma<<<1024, 512, 0, stream>>>(x, W1h, W1l, wn1, dist, pixstat);
    finalize36_kernel<<<36, 256, 0, stream>>>(pixstat, scale);

    // ---- layer 1 -> 2 transition ----
    if (roomy) {
        sfm1s_kernel<<<36864/4, 256, 0, stream>>>(dist, scale, Y2h, Y2l, pnb);
    } else {
        sfm1_kernel<<<DIV_UP(36864*100,256), 256, 0, stream>>>(dist, scale, ybuf);
        splitnorm_kernel<<<36864/4, 256, 0, stream>>>(ybuf, Y2h, Y2l, pnb, 36864, 100, 128);
    }
    splitnorm_kernel<<<256/4, 256, 0, stream>>>(w2, W2h, W2l, wnb, 225, 100, 128);

    // ---- layer 2 ----
    distg_mfma<<<dim3(288,2), 512, 0, stream>>>(Y2h, Y2l, W2h, W2l, pnb, wnb, dist, 36864, 225, 128, pblk);
    finalize_part_kernel<<<1, 256, 0, stream>>>(pblk, 576, scale, 36, 8294400.0);
    sfm2s_kernel<<<12288/4, 256, 0, stream>>>(dist, scale + 36, Y3h, Y3l, pnb);

    // ---- layer 3 ----
    splitnorm_kernel<<<640/4, 256, 0, stream>>>(w3, W3h, W3l, wnb, 625, 225, 256);
    distg_mfma<<<dim3(96,5), 512, 0, stream>>>(Y3h, Y3l, W3h, W3l, pnb, wnb, dist, 12288, 625, 256, pblk);
    finalize_part_kernel<<<1, 256, 0, stream>>>(pblk, 480, scale, 37, 7680000.0);
    sfm3s_kernel<<<4096/4, 256, 0, stream>>>(dist, scale + 37, Y4h, Y4l, pnb);

    // ---- layer 4 ----
    splitnorm_kernel<<<1280/4, 256, 0, stream>>>(w4, W4h, W4l, wnb, 1225, 625, 640);
    distg_mfma<<<dim3(32,10), 512, 0, stream>>>(Y4h, Y4l, W4h, W4l, pnb, wnb, dist, 4096, 1225, 640, pblk);
    finalize_part_kernel<<<1, 256, 0, stream>>>(pblk, 320, scale, 38, 5017600.0);

    // ---- FC ----
    fc_kernel<<<4096, 256, 0, stream>>>(dist, scale + 38, fc_w, fc_b, out);
}

// Round 20
// 203.693 us; speedup vs baseline: 1.2030x; 1.0097x over previous
//
#include <hip/hip_runtime.h>
#include <hip/hip_bf16.h>
#include <math.h>

#define DIV_UP(a,b) (((a)+(b)-1)/(b))
#define FSQRT(x) __builtin_amdgcn_sqrtf(x)

typedef __attribute__((ext_vector_type(8))) short short8;
typedef __attribute__((ext_vector_type(4))) float f32x4;

// async global->LDS, 16B per lane; gptr per-lane, lptr wave-uniform
#define GL16(g, l) __builtin_amdgcn_global_load_lds( \
    (const __attribute__((address_space(1))) void*)(g), \
    (__attribute__((address_space(3))) void*)(l), 16, 0, 0)

// ---------------- W1 prep (+stats zero folded in) ----------------
__global__ __launch_bounds__(256) void w1split_kernel(
    const float* __restrict__ w, ushort* __restrict__ Wh, ushort* __restrict__ Wl,
    double* __restrict__ stats) {
    if (blockIdx.x == 0 && threadIdx.x < 78) stats[threadIdx.x] = 0.0;
    int e = blockIdx.x*256 + threadIdx.x;
    if (e >= 112*96) return;
    int o = e / 96, kk = e - o*96, c = kk >> 5, k = kk & 31;
    float v = (o < 100 && k < 25) ? w[o*75 + c*25 + k] : 0.f;
    __hip_bfloat16 hb = __float2bfloat16(v);
    float hf = __bfloat162float(hb);
    __hip_bfloat16 lb = __float2bfloat16(v - hf);
    Wh[e] = *(ushort*)&hb;
    Wl[e] = *(ushort*)&lb;
}

__global__ __launch_bounds__(64) void w1norm_kernel(
    const ushort* __restrict__ Wh, const ushort* __restrict__ Wl, float* __restrict__ wn1) {
    int j = blockIdx.x*64 + threadIdx.x;
    if (j >= 336) return;
    int o = j / 3, c = j - o*3;
    const ushort* h = Wh + o*96 + c*32;
    const ushort* l = Wl + o*96 + c*32;
    float s = 0.f;
#pragma unroll
    for (int k = 0; k < 25; ++k) {
        ushort hu = h[k], lu = l[k];
        float v = __bfloat162float(*(__hip_bfloat16*)&hu) + __bfloat162float(*(__hip_bfloat16*)&lu);
        s += v*v;
    }
    wn1[j] = s;
}

// ---------------- layer 1 MFMA (+fused stats, per-wave private LDS, no atomics) ----------------
__global__ __launch_bounds__(512, 2) void rbf1_mfma(
    const float* __restrict__ x, const ushort* __restrict__ Wh, const ushort* __restrict__ Wl,
    const float* __restrict__ wn1, float* __restrict__ dist1,
    float* __restrict__ pixstat) {
    __shared__ ushort Ah[3*144*32];
    __shared__ ushort Al[3*144*32];
    __shared__ float pnl[432];
    __shared__ float rstat[7*144*2];   // [wave][row][sum,sq] — every slot written, no init
    int tid = threadIdx.x;
    int b4 = blockIdx.x;

    if (tid < 432) {
        int row = tid / 3, c = tid - row*3;
        int img = row / 36, p = row - img*36;
        int ph = p / 6, pw = p - ph*6;
        const float* xp = x + (size_t)b4*9408 + img*2352 + c*784 + (ph*28 + pw)*4;
        float arr[25];
#pragma unroll
        for (int ki = 0; ki < 5; ++ki) {
            float4 v4 = *(const float4*)(xp + ki*28);
            arr[ki*5+0] = v4.x; arr[ki*5+1] = v4.y;
            arr[ki*5+2] = v4.z; arr[ki*5+3] = v4.w;
            arr[ki*5+4] = xp[ki*28 + 4];
        }
        float pnc = 0.f;
        int tilebase = c*9216 + row*64;
        int r3 = (row >> 1) & 3;
#pragma unroll
        for (int kb = 0; kb < 4; ++kb) {
            uint4 hq, lq;
            uint* hqa = (uint*)&hq;
            uint* lqa = (uint*)&lq;
#pragma unroll
            for (int j = 0; j < 4; ++j) {
                int k0 = kb*8 + 2*j;
                float v0 = (k0 < 25) ? arr[k0] : 0.f;
                float v1 = (k0+1 < 25) ? arr[k0+1] : 0.f;
                __hip_bfloat16 h0 = __float2bfloat16(v0);
                float hf0 = __bfloat162float(h0);
                __hip_bfloat16 l0 = __float2bfloat16(v0 - hf0);
                float r0 = hf0 + __bfloat162float(l0);
                __hip_bfloat16 h1 = __float2bfloat16(v1);
                float hf1 = __bfloat162float(h1);
                __hip_bfloat16 l1 = __float2bfloat16(v1 - hf1);
                float r1 = hf1 + __bfloat162float(l1);
                pnc += r0*r0 + r1*r1;
                hqa[j] = (uint)(*(ushort*)&h0) | ((uint)(*(ushort*)&h1) << 16);
                lqa[j] = (uint)(*(ushort*)&l0) | ((uint)(*(ushort*)&l1) << 16);
            }
            int kbs = kb ^ r3;
            *(uint4*)((char*)Ah + tilebase + kbs*16) = hq;
            *(uint4*)((char*)Al + tilebase + kbs*16) = lq;
        }
        pnl[tid] = pnc;
    }
    __syncthreads();

    int lane = tid & 63, wave = tid >> 6;
    if (wave < 7) {
        int nf = wave;
        int rl = lane & 15, kh = lane >> 4;
        int o = nf*16 + rl;
        const ushort* bhp = Wh + o*96 + kh*8;
        const ushort* blp = Wl + o*96 + kh*8;
        short8 bh0 = *(const short8*)(bhp);
        short8 bh1 = *(const short8*)(bhp + 32);
        short8 bh2 = *(const short8*)(bhp + 64);
        short8 bl0 = *(const short8*)(blp);
        short8 bl1 = *(const short8*)(blp + 32);
        short8 bl2 = *(const short8*)(blp + 64);
        float w0 = wn1[o*3], w1v = wn1[o*3+1], w2v = wn1[o*3+2];
        int swz = (rl >> 1) & 3;
        int kx = (kh ^ swz) * 16;
        bool valid = (o < 100);
        float* mystat = rstat + wave*288;
#pragma unroll
        for (int mf = 0; mf < 9; ++mf) {
            int rbase = (mf*16 + rl)*64;
            short8 ah0 = *(const short8*)((const char*)Ah + rbase + kx);
            short8 al0 = *(const short8*)((const char*)Al + rbase + kx);
            short8 ah1 = *(const short8*)((const char*)Ah + 9216 + rbase + kx);
            short8 al1 = *(const short8*)((const char*)Al + 9216 + rbase + kx);
            short8 ah2 = *(const short8*)((const char*)Ah + 18432 + rbase + kx);
            short8 al2 = *(const short8*)((const char*)Al + 18432 + rbase + kx);
            f32x4 a0 = {0.f,0.f,0.f,0.f}, a1 = {0.f,0.f,0.f,0.f}, a2 = {0.f,0.f,0.f,0.f};
            a0 = __builtin_amdgcn_mfma_f32_16x16x32_bf16(ah0, bh0, a0, 0, 0, 0);
            a1 = __builtin_amdgcn_mfma_f32_16x16x32_bf16(ah1, bh1, a1, 0, 0, 0);
            a2 = __builtin_amdgcn_mfma_f32_16x16x32_bf16(ah2, bh2, a2, 0, 0, 0);
            a0 = __builtin_amdgcn_mfma_f32_16x16x32_bf16(ah0, bl0, a0, 0, 0, 0);
            a1 = __builtin_amdgcn_mfma_f32_16x16x32_bf16(ah1, bl1, a1, 0, 0, 0);
            a2 = __builtin_amdgcn_mfma_f32_16x16x32_bf16(ah2, bl2, a2, 0, 0, 0);
            a0 = __builtin_amdgcn_mfma_f32_16x16x32_bf16(al0, bh0, a0, 0, 0, 0);
            a1 = __builtin_amdgcn_mfma_f32_16x16x32_bf16(al1, bh1, a1, 0, 0, 0);
            a2 = __builtin_amdgcn_mfma_f32_16x16x32_bf16(al2, bh2, a2, 0, 0, 0);
            float dsum[4], dsq[4];
            size_t base = (size_t)(b4*144 + mf*16 + kh*4)*100 + o;
#pragma unroll
            for (int r = 0; r < 4; ++r) {
                int row = mf*16 + kh*4 + r;
                float d = FSQRT(fmaxf(pnl[row*3+0] + w0  - 2.f*a0[r], 1e-12f))
                        + FSQRT(fmaxf(pnl[row*3+1] + w1v - 2.f*a1[r], 1e-12f))
                        + FSQRT(fmaxf(pnl[row*3+2] + w2v - 2.f*a2[r], 1e-12f));
                float dv = valid ? d : 0.f;
                if (valid) dist1[base + (size_t)r*100] = d;
                dsum[r] = dv; dsq[r] = dv*dv;
            }
#pragma unroll
            for (int m = 1; m <= 8; m <<= 1) {
#pragma unroll
                for (int r = 0; r < 4; ++r) {
                    dsum[r] += __shfl_xor(dsum[r], m, 64);
                    dsq[r]  += __shfl_xor(dsq[r],  m, 64);
                }
            }
            if (rl == 0) {
#pragma unroll
                for (int r = 0; r < 4; ++r) {
                    int row = mf*16 + kh*4 + r;
                    mystat[row*2]     = dsum[r];
                    mystat[row*2 + 1] = dsq[r];
                }
            }
        }
    }
    __syncthreads();
    if (tid < 72) {
        int p = tid >> 1, w = tid & 1;
        float s = 0.f;
#pragma unroll
        for (int wv = 0; wv < 7; ++wv)
#pragma unroll
            for (int g = 0; g < 4; ++g)
                s += rstat[wv*288 + (p + 36*g)*2 + w];
        pixstat[(size_t)b4*72 + 2*p + w] = s;
    }
}

// reduce per-block pixel partials -> scale[p], p = blockIdx.x (36 blocks)
__global__ __launch_bounds__(256) void finalize36_kernel(
    const float* __restrict__ pixstat, float* __restrict__ scale) {
    __shared__ double ss[256], qq[256];
    int p = blockIdx.x, tid = threadIdx.x;
    double s = 0.0, q = 0.0;
    for (int b = tid; b < 1024; b += 256) {
        s += (double)pixstat[(size_t)b*72 + 2*p];
        q += (double)pixstat[(size_t)b*72 + 2*p + 1];
    }
    ss[tid] = s; qq[tid] = q; __syncthreads();
    for (int st = 128; st > 0; st >>= 1) {
        if (tid < st) { ss[tid] += ss[tid+st]; qq[tid] += qq[tid+st]; }
        __syncthreads();
    }
    if (tid == 0) {
        const double N = 409600.0;
        double m = ss[0] / N;
        double var = (qq[0] - N*m*m) / (N - 1.0);
        scale[p] = (float)(0.5 / var);
    }
}

// reduce per-block partials (no atomics) and compute scale
__global__ __launch_bounds__(256) void finalize_part_kernel(
    const double* __restrict__ part, int nb,
    float* __restrict__ scale, int scaleOff, double N) {
    __shared__ double ss[256], qq[256];
    int tid = threadIdx.x;
    double s = 0.0, q = 0.0;
    for (int i = tid; i < nb; i += 256) { s += part[2*i]; q += part[2*i+1]; }
    ss[tid] = s; qq[tid] = q; __syncthreads();
    for (int st = 128; st > 0; st >>= 1) {
        if (tid < st) { ss[tid] += ss[tid+st]; qq[tid] += qq[tid+st]; }
        __syncthreads();
    }
    if (tid == 0) {
        double m = ss[0] / N;
        double var = (qq[0] - N*m*m) / (N - 1.0);
        scale[scaleOff] = (float)(0.5 / var);
    }
}

// exp+crelu(0.4)+SFM1: dist1 -> y2 [36864,100] (fallback path)
__global__ __launch_bounds__(256) void sfm1_kernel(
    const float* __restrict__ dist1, const float* __restrict__ scale,
    float* __restrict__ y2) {
    int gid = blockIdx.x*256 + threadIdx.x;
    if (gid >= 36864*100) return;
    int c = gid % 100, n = gid / 100;
    int b = n / 9, ij = n % 9, i = ij / 3, j = ij % 3;
    const float alpha[2][2] = {{0.729f, 0.81f},{0.9f, 1.0f}};
    float acc = 0.f;
#pragma unroll
    for (int fh = 0; fh < 2; ++fh)
#pragma unroll
        for (int fw = 0; fw < 2; ++fw) {
            int p = (2*i+fh)*6 + (2*j+fw);
            float d = dist1[(size_t)b*3600 + p*100 + c];
            float v = __expf(-d*d*scale[p]);
            v = (v >= 0.4f) ? v : 0.f;
            acc += alpha[fh][fw]*v;
        }
    y2[gid] = 0.25f * acc;
}

// fused exp+crelu+SFM1+split+norm: dist1 -> Y2 planes [36864][128] + norms (roomy path)
__global__ __launch_bounds__(256) void sfm1s_kernel(
    const float* __restrict__ dist1, const float* __restrict__ scale,
    ushort* __restrict__ H, ushort* __restrict__ L, float* __restrict__ norm) {
    int wave = threadIdx.x >> 6, lane = threadIdx.x & 63;
    int n = blockIdx.x*4 + wave;
    int b = n / 9, ij = n % 9, i = ij / 3, j = ij % 3;
    const float alpha[2][2] = {{0.729f, 0.81f},{0.9f, 1.0f}};
    float s = 0.f;
#pragma unroll
    for (int q = 0; q < 2; ++q) {
        int k = lane + q*64;
        float y = 0.f;
        if (k < 100) {
            float acc = 0.f;
#pragma unroll
            for (int fh = 0; fh < 2; ++fh)
#pragma unroll
                for (int fw = 0; fw < 2; ++fw) {
                    int p = (2*i+fh)*6 + (2*j+fw);
                    float d = dist1[(size_t)b*3600 + p*100 + k];
                    float v = __expf(-d*d*scale[p]);
                    v = (v >= 0.4f) ? v : 0.f;
                    acc += alpha[fh][fw]*v;
                }
            y = 0.25f * acc;
        }
        __hip_bfloat16 hb = __float2bfloat16(y);
        float hf = __bfloat162float(hb);
        __hip_bfloat16 lb = __float2bfloat16(y - hf);
        H[(size_t)n*128 + k] = *(ushort*)&hb;
        L[(size_t)n*128 + k] = *(ushort*)&lb;
        float r = hf + __bfloat162float(lb);
        s += r*r;
    }
    for (int off = 32; off > 0; off >>= 1) s += __shfl_down(s, off, 64);
    if (lane == 0) norm[n] = s;
}

// fused split+pad+rownorm: one wave per row
__global__ __launch_bounds__(256) void splitnorm_kernel(
    const float* __restrict__ src, ushort* __restrict__ H, ushort* __restrict__ L,
    float* __restrict__ norm, int R, int K, int Kp) {
    int wave = threadIdx.x >> 6, lane = threadIdx.x & 63;
    int row = blockIdx.x*4 + wave;
    float s = 0.f;
    if (row < R) {
        for (int k = lane; k < Kp; k += 64) {
            float v = (k < K) ? src[(size_t)row*K + k] : 0.f;
            __hip_bfloat16 hb = __float2bfloat16(v);
            float hf = __bfloat162float(hb);
            __hip_bfloat16 lb = __float2bfloat16(v - hf);
            H[(size_t)row*Kp + k] = *(ushort*)&hb;
            L[(size_t)row*Kp + k] = *(ushort*)&lb;
            float r = hf + __bfloat162float(lb);
            s += r*r;
        }
    } else {
        for (int k = lane; k < Kp; k += 64) {
            H[(size_t)row*Kp + k] = 0;
            L[(size_t)row*Kp + k] = 0;
        }
    }
    for (int off = 32; off > 0; off >>= 1) s += __shfl_down(s, off, 64);
    if (lane == 0) norm[row] = s;
}

// fused exp+crelu+SFM2+split+norm
__global__ __launch_bounds__(256) void sfm2s_kernel(
    const float* __restrict__ dist2, const float* __restrict__ scale,
    ushort* __restrict__ H, ushort* __restrict__ L, float* __restrict__ norm) {
    int wave = threadIdx.x >> 6, lane = threadIdx.x & 63;
    int n2 = blockIdx.x*4 + wave;
    int b = n2 / 3, i = n2 % 3;
    float s2 = scale[0];
    const float alphaJ[3] = {0.81f, 0.9f, 1.0f};
    float s = 0.f;
#pragma unroll
    for (int q = 0; q < 4; ++q) {
        int k = lane + q*64;
        float y = 0.f;
        if (k < 225) {
            float acc = 0.f;
#pragma unroll
            for (int j = 0; j < 3; ++j) {
                float d = dist2[((size_t)(b*9 + i*3 + j))*225 + k];
                float v = __expf(-d*d*s2);
                v = (v >= 0.1f) ? v : 0.f;
                acc += alphaJ[j]*v;
            }
            y = acc * (1.f/3.f);
        }
        __hip_bfloat16 hb = __float2bfloat16(y);
        float hf = __bfloat162float(hb);
        __hip_bfloat16 lb = __float2bfloat16(y - hf);
        H[(size_t)n2*256 + k] = *(ushort*)&hb;
        L[(size_t)n2*256 + k] = *(ushort*)&lb;
        float r = hf + __bfloat162float(lb);
        s += r*r;
    }
    for (int off = 32; off > 0; off >>= 1) s += __shfl_down(s, off, 64);
    if (lane == 0) norm[n2] = s;
}

// fused exp+crelu+SFM3+split+norm
__global__ __launch_bounds__(256) void sfm3s_kernel(
    const float* __restrict__ dist3, const float* __restrict__ scale,
    ushort* __restrict__ H, ushort* __restrict__ L, float* __restrict__ norm) {
    int wave = threadIdx.x >> 6, lane = threadIdx.x & 63;
    int b = blockIdx.x*4 + wave;
    float s3 = scale[0];
    const float alphaI[3] = {0.81f, 0.9f, 1.0f};
    float s = 0.f;
#pragma unroll
    for (int q = 0; q < 10; ++q) {
        int k = lane + q*64;
        float y = 0.f;
        if (k < 625) {
            float acc = 0.f;
#pragma unroll
            for (int i = 0; i < 3; ++i) {
                float d = dist3[((size_t)(b*3 + i))*625 + k];
                float v = __expf(-d*d*s3);
                v = (v >= 0.01f) ? v : 0.f;
                acc += alphaI[i]*v;
            }
            y = acc * (1.f/3.f);
        }
        __hip_bfloat16 hb = __float2bfloat16(y);
        float hf = __bfloat162float(hb);
        __hip_bfloat16 lb = __float2bfloat16(y - hf);
        H[(size_t)b*640 + k] = *(ushort*)&hb;
        L[(size_t)b*640 + k] = *(ushort*)&lb;
        float r = hf + __bfloat162float(lb);
        s += r*r;
    }
    for (int off = 32; off > 0; off >>= 1) s += __shfl_down(s, off, 64);
    if (lane == 0) norm[b] = s;
}

// ---------------- unified dist GEMM: 64x128 tile, 8 waves, 24KB LDS, gl_lds ----------------
// Per-wave output 32x32 (acc[2][2]). Staging per K-step: all waves stage B rows
// [w*16,w*16+16) (2 gl_lds); waves 0-3 stage A-hi chunk w, waves 4-7 A-lo chunk w-4.
__global__ __launch_bounds__(512, 4) void distg_mfma(
    const ushort* __restrict__ Yh, const ushort* __restrict__ Yl,   // [N][Kp]
    const ushort* __restrict__ Wh, const ushort* __restrict__ Wl,   // [Opad][Kp]
    const float* __restrict__ pn, const float* __restrict__ wn,
    float* __restrict__ D, int N, int O, int Kp,
    double* __restrict__ part) {
    __shared__ ushort Ahs[2048], Als[2048], Bhs[4096], Bls[4096];   // 24 KB
    __shared__ double wred[8][2];
    int tid = threadIdx.x, lane = tid & 63, wave = tid >> 6;
    int bn = blockIdx.x * 64, bo = blockIdx.y * 128;
    int wm = wave >> 2, wq = wave & 3;

    int rL = lane >> 2, cL = lane & 3;
    int cs = cL ^ ((rL >> 1) & 3);                 // 16-row-aligned bases keep formula valid
    // B staging: wave stages B rows [wave*16, wave*16+16), both planes
    size_t boff = (size_t)(bo + wave*16 + rL) * Kp + cs*8;
    ushort* lBh = Bhs + wave*512;
    ushort* lBl = Bls + wave*512;
    // A staging: waves 0-3 -> A-hi rows [w*16..), waves 4-7 -> A-lo rows [(w-4)*16..)
    int aw = wave & 3;
    size_t aoff = (size_t)(bn + aw*16 + rL) * Kp + cs*8;
    ushort* lA = ((wave < 4) ? Ahs : Als) + aw*512;
    const ushort* Asrc = (wave < 4) ? Yh : Yl;

    int rl = lane & 15, kh = lane >> 4;
    int kbs_r = kh ^ ((rl >> 1) & 3);
    int raoff[2], rboff[2];
#pragma unroll
    for (int mf = 0; mf < 2; ++mf) raoff[mf] = (wm*32 + mf*16 + rl)*64 + kbs_r*16;
#pragma unroll
    for (int nf = 0; nf < 2; ++nf) rboff[nf] = (wq*32 + nf*16 + rl)*64 + kbs_r*16;

    f32x4 acc[2][2];
#pragma unroll
    for (int mf = 0; mf < 2; ++mf)
#pragma unroll
        for (int nf = 0; nf < 2; ++nf) acc[mf][nf] = (f32x4){0.f,0.f,0.f,0.f};

    int NT = Kp >> 5;
    for (int t = 0; t < NT; ++t) {
        int k0 = t*32;
        GL16(Asrc + aoff + k0, lA);
        GL16(Wh + boff + k0, lBh);
        GL16(Wl + boff + k0, lBl);
        __syncthreads();
        short8 a_h[2], a_l[2];
#pragma unroll
        for (int mf = 0; mf < 2; ++mf) {
            a_h[mf] = *(const short8*)((const char*)Ahs + raoff[mf]);
            a_l[mf] = *(const short8*)((const char*)Als + raoff[mf]);
        }
#pragma unroll
        for (int nf = 0; nf < 2; ++nf) {
            short8 b_h = *(const short8*)((const char*)Bhs + rboff[nf]);
            short8 b_l = *(const short8*)((const char*)Bls + rboff[nf]);
#pragma unroll
            for (int mf = 0; mf < 2; ++mf) {
                acc[mf][nf] = __builtin_amdgcn_mfma_f32_16x16x32_bf16(a_h[mf], b_h, acc[mf][nf], 0, 0, 0);
                acc[mf][nf] = __builtin_amdgcn_mfma_f32_16x16x32_bf16(a_h[mf], b_l, acc[mf][nf], 0, 0, 0);
                acc[mf][nf] = __builtin_amdgcn_mfma_f32_16x16x32_bf16(a_l[mf], b_h, acc[mf][nf], 0, 0, 0);
            }
        }
        __syncthreads();
    }

    double lsum = 0.0, lsq = 0.0;
#pragma unroll
    for (int mf = 0; mf < 2; ++mf) {
#pragma unroll
        for (int r = 0; r < 4; ++r) {
            int n = bn + wm*32 + mf*16 + kh*4 + r;
            float pv = pn[n];
#pragma unroll
            for (int nf = 0; nf < 2; ++nf) {
                int o = bo + wq*32 + nf*16 + rl;
                if (o < O) {
                    float d2 = pv + wn[o] - 2.f*acc[mf][nf][r];
                    float dd = FSQRT(fmaxf(d2, 1e-12f));
                    D[(size_t)n*O + o] = dd;
                    lsum += dd; lsq += (double)dd*dd;
                }
            }
        }
    }
    for (int off = 32; off > 0; off >>= 1) {
        lsum += __shfl_down(lsum, off, 64);
        lsq  += __shfl_down(lsq,  off, 64);
    }
    if (lane == 0) { wred[wave][0] = lsum; wred[wave][1] = lsq; }
    __syncthreads();
    if (tid == 0) {
        double s = 0.0, q = 0.0;
#pragma unroll
        for (int w = 0; w < 8; ++w) { s += wred[w][0]; q += wred[w][1]; }
        int bid = blockIdx.y * gridDim.x + blockIdx.x;
        part[2*bid]   = s;
        part[2*bid+1] = q;
    }
}

// exp+crelu(0.01)+FC: dist4 [4096,1225] -> out [4096,10]
__global__ __launch_bounds__(256) void fc_kernel(
    const float* __restrict__ dist4, const float* __restrict__ scale,
    const float* __restrict__ fcw, const float* __restrict__ fcb,
    float* __restrict__ out) {
    int b = blockIdx.x;
    int tid = threadIdx.x;
    float s4 = scale[0];
    float acc[10] = {};
    for (int o = tid; o < 1225; o += 256) {
        float d = dist4[(size_t)b*1225 + o];
        float v = __expf(-d*d*s4);
        v = (v >= 0.01f) ? v : 0.f;
#pragma unroll
        for (int k = 0; k < 10; ++k) acc[k] += v * fcw[k*1225 + o];
    }
    __shared__ float red[10*256];
#pragma unroll
    for (int k = 0; k < 10; ++k) red[k*256 + tid] = acc[k];
    __syncthreads();
    for (int st = 128; st > 0; st >>= 1) {
        if (tid < st) {
#pragma unroll
            for (int k = 0; k < 10; ++k) red[k*256 + tid] += red[k*256 + tid + st];
        }
        __syncthreads();
    }
    if (tid < 10) out[b*10 + tid] = red[tid*256] + fcb[tid];
}

extern "C" void kernel_launch(void* const* d_in, const int* in_sizes, int n_in,
                              void* d_out, int out_size, void* d_ws, size_t ws_size,
                              hipStream_t stream) {
    const float* x     = (const float*)d_in[0];
    const float* rgb_w = (const float*)d_in[1];
    const float* w2    = (const float*)d_in[2];
    const float* w3    = (const float*)d_in[3];
    const float* w4    = (const float*)d_in[4];
    const float* fc_w  = (const float*)d_in[5];
    const float* fc_b  = (const float*)d_in[6];
    float* out = (float*)d_out;

    float* wsf   = (float*)d_ws;
    float* dist  = wsf;                    // 14,745,600 floats
    float* ybuf  = wsf + 14745600;         // 3,686,400 floats
    float* pnb   = ybuf + 3686400;         // 36,864 floats
    float* wnb   = pnb + 36864;            // 1,280
    float* scale = wnb + 1280;             // 64
    double* stats = (double*)(scale + 64); // 78 doubles
    double* pblk  = stats + 78;            // 2304 doubles (max grid 1152 blocks)
    float* wsend  = (float*)(pblk + 2304);

    ushort* W1h = (ushort*)pnb;
    ushort* W1l = W1h + 10752;
    float*  wn1 = (float*)(W1l + 10752);

    float* pixstat = ybuf;

    size_t base_floats = (size_t)(wsend - wsf);
    size_t y2_floats   = 2u * 36864u * 128u / 2u;
    bool roomy = ws_size >= (base_floats + y2_floats + 1024) * sizeof(float);

    ushort* Y2h = roomy ? (ushort*)wsend : (ushort*)(dist + 8388608);
    ushort* Y2l = Y2h + 36864*128;
    ushort* W2h = (ushort*)(dist + 8388608) + 2*36864*128;
    ushort* W2l = W2h + 256*128;
    ushort* Y3h = (ushort*)ybuf;
    ushort* Y3l = Y3h + 12288*256;
    ushort* W3h = Y3l + 12288*256;
    ushort* W3l = W3h + 640*256;
    ushort* Y4h = (ushort*)ybuf;
    ushort* Y4l = Y4h + 4096*640;
    ushort* W4h = Y4l + 4096*640;
    ushort* W4l = W4h + 1280*640;

    // ---- layer 1 ----
    w1split_kernel<<<DIV_UP(112*96,256), 256, 0, stream>>>(rgb_w, W1h, W1l, stats);
    w1norm_kernel<<<DIV_UP(336,64), 64, 0, stream>>>(W1h, W1l, wn1);
    rbf1_mfma<<<1024, 512, 0, stream>>>(x, W1h, W1l, wn1, dist, pixstat);
    finalize36_kernel<<<36, 256, 0, stream>>>(pixstat, scale);

    // ---- layer 1 -> 2 transition ----
    if (roomy) {
        sfm1s_kernel<<<36864/4, 256, 0, stream>>>(dist, scale, Y2h, Y2l, pnb);
    } else {
        sfm1_kernel<<<DIV_UP(36864*100,256), 256, 0, stream>>>(dist, scale, ybuf);
        splitnorm_kernel<<<36864/4, 256, 0, stream>>>(ybuf, Y2h, Y2l, pnb, 36864, 100, 128);
    }
    splitnorm_kernel<<<256/4, 256, 0, stream>>>(w2, W2h, W2l, wnb, 225, 100, 128);

    // ---- layer 2: 64x128 tiles -> grid (576,2)=1152 blocks ----
    distg_mfma<<<dim3(576,2), 512, 0, stream>>>(Y2h, Y2l, W2h, W2l, pnb, wnb, dist, 36864, 225, 128, pblk);
    finalize_part_kernel<<<1, 256, 0, stream>>>(pblk, 1152, scale, 36, 8294400.0);
    sfm2s_kernel<<<12288/4, 256, 0, stream>>>(dist, scale + 36, Y3h, Y3l, pnb);

    // ---- layer 3: grid (192,5)=960 blocks ----
    splitnorm_kernel<<<640/4, 256, 0, stream>>>(w3, W3h, W3l, wnb, 625, 225, 256);
    distg_mfma<<<dim3(192,5), 512, 0, stream>>>(Y3h, Y3l, W3h, W3l, pnb, wnb, dist, 12288, 625, 256, pblk);
    finalize_part_kernel<<<1, 256, 0, stream>>>(pblk, 960, scale, 37, 7680000.0);
    sfm3s_kernel<<<4096/4, 256, 0, stream>>>(dist, scale + 37, Y4h, Y4l, pnb);

    // ---- layer 4: grid (64,10)=640 blocks ----
    splitnorm_kernel<<<1280/4, 256, 0, stream>>>(w4, W4h, W4l, wnb, 1225, 625, 640);
    distg_mfma<<<dim3(64,10), 512, 0, stream>>>(Y4h, Y4l, W4h, W4l, pnb, wnb, dist, 4096, 1225, 640, pblk);
    finalize_part_kernel<<<1, 256, 0, stream>>>(pblk, 640, scale, 38, 5017600.0);

    // ---- FC ----
    fc_kernel<<<4096, 256, 0, stream>>>(dist, scale + 38, fc_w, fc_b, out);
}

// Round 21
// 202.452 us; speedup vs baseline: 1.2104x; 1.0061x over previous
//
#include <hip/hip_runtime.h>
#include <hip/hip_bf16.h>
#include <math.h>

#define DIV_UP(a,b) (((a)+(b)-1)/(b))
#define FSQRT(x) __builtin_amdgcn_sqrtf(x)

typedef __attribute__((ext_vector_type(8))) short short8;
typedef __attribute__((ext_vector_type(4))) float f32x4;

// async global->LDS, 16B per lane; gptr per-lane, lptr wave-uniform
#define GL16(g, l) __builtin_amdgcn_global_load_lds( \
    (const __attribute__((address_space(1))) void*)(g), \
    (__attribute__((address_space(3))) void*)(l), 16, 0, 0)

// in-block redundant scale derivation from per-block GEMM partials (published at
// the previous kernel boundary — no fences/atomics needed, deterministic)
#define SCALE_FROM_PART(OUTVAR) \
    __shared__ double ss_[256], qq_[256]; \
    __shared__ float ssc_; \
    { int t_ = threadIdx.x; double s_ = 0.0, q_ = 0.0; \
      for (int i_ = t_; i_ < nb; i_ += 256) { s_ += part[2*i_]; q_ += part[2*i_+1]; } \
      ss_[t_] = s_; qq_[t_] = q_; __syncthreads(); \
      for (int st_ = 128; st_ > 0; st_ >>= 1) { \
          if (t_ < st_) { ss_[t_] += ss_[t_+st_]; qq_[t_] += qq_[t_+st_]; } \
          __syncthreads(); } \
      if (t_ == 0) { double m_ = ss_[0] / Nstat; \
          double var_ = (qq_[0] - Nstat*m_*m_) / (Nstat - 1.0); \
          ssc_ = (float)(0.5 / var_); } \
      __syncthreads(); } \
    float OUTVAR = ssc_;

// ---------------- W1 prep: split + per-(o,c) norm in ONE kernel (+stats zero) ----------------
// grid 84 x 256: wave handles one (o,c) group j = blockIdx*4+wave; lanes 0-31 cover k.
__global__ __launch_bounds__(256) void w1prep_kernel(
    const float* __restrict__ w, ushort* __restrict__ Wh, ushort* __restrict__ Wl,
    float* __restrict__ wn1, double* __restrict__ stats) {
    if (blockIdx.x == 0 && threadIdx.x < 78) stats[threadIdx.x] = 0.0;
    int wave = threadIdx.x >> 6, lane = threadIdx.x & 63;
    int j = blockIdx.x*4 + wave;           // 0..335
    if (j >= 336) return;
    int o = j / 3, c = j - o*3;
    float s = 0.f;
    if (lane < 32) {
        int k = lane;
        float v = (o < 100 && k < 25) ? w[o*75 + c*25 + k] : 0.f;
        __hip_bfloat16 hb = __float2bfloat16(v);
        float hf = __bfloat162float(hb);
        __hip_bfloat16 lb = __float2bfloat16(v - hf);
        Wh[o*96 + c*32 + k] = *(ushort*)&hb;
        Wl[o*96 + c*32 + k] = *(ushort*)&lb;
        float r = hf + __bfloat162float(lb);
        s = r*r;
    }
#pragma unroll
    for (int off = 16; off > 0; off >>= 1) s += __shfl_down(s, off, 64);
    if (lane == 0) wn1[j] = s;
}

// ---------------- layer 1 MFMA (+fused stats, per-wave private LDS, no atomics) ----------------
__global__ __launch_bounds__(512, 2) void rbf1_mfma(
    const float* __restrict__ x, const ushort* __restrict__ Wh, const ushort* __restrict__ Wl,
    const float* __restrict__ wn1, float* __restrict__ dist1,
    float* __restrict__ pixstat) {
    __shared__ ushort Ah[3*144*32];
    __shared__ ushort Al[3*144*32];
    __shared__ float pnl[432];
    __shared__ float rstat[7*144*2];   // [wave][row][sum,sq] — every slot written, no init
    int tid = threadIdx.x;
    int b4 = blockIdx.x;

    if (tid < 432) {
        int row = tid / 3, c = tid - row*3;
        int img = row / 36, p = row - img*36;
        int ph = p / 6, pw = p - ph*6;
        const float* xp = x + (size_t)b4*9408 + img*2352 + c*784 + (ph*28 + pw)*4;
        float arr[25];
#pragma unroll
        for (int ki = 0; ki < 5; ++ki) {
            float4 v4 = *(const float4*)(xp + ki*28);
            arr[ki*5+0] = v4.x; arr[ki*5+1] = v4.y;
            arr[ki*5+2] = v4.z; arr[ki*5+3] = v4.w;
            arr[ki*5+4] = xp[ki*28 + 4];
        }
        float pnc = 0.f;
        int tilebase = c*9216 + row*64;
        int r3 = (row >> 1) & 3;
#pragma unroll
        for (int kb = 0; kb < 4; ++kb) {
            uint4 hq, lq;
            uint* hqa = (uint*)&hq;
            uint* lqa = (uint*)&lq;
#pragma unroll
            for (int j = 0; j < 4; ++j) {
                int k0 = kb*8 + 2*j;
                float v0 = (k0 < 25) ? arr[k0] : 0.f;
                float v1 = (k0+1 < 25) ? arr[k0+1] : 0.f;
                __hip_bfloat16 h0 = __float2bfloat16(v0);
                float hf0 = __bfloat162float(h0);
                __hip_bfloat16 l0 = __float2bfloat16(v0 - hf0);
                float r0 = hf0 + __bfloat162float(l0);
                __hip_bfloat16 h1 = __float2bfloat16(v1);
                float hf1 = __bfloat162float(h1);
                __hip_bfloat16 l1 = __float2bfloat16(v1 - hf1);
                float r1 = hf1 + __bfloat162float(l1);
                pnc += r0*r0 + r1*r1;
                hqa[j] = (uint)(*(ushort*)&h0) | ((uint)(*(ushort*)&h1) << 16);
                lqa[j] = (uint)(*(ushort*)&l0) | ((uint)(*(ushort*)&l1) << 16);
            }
            int kbs = kb ^ r3;
            *(uint4*)((char*)Ah + tilebase + kbs*16) = hq;
            *(uint4*)((char*)Al + tilebase + kbs*16) = lq;
        }
        pnl[tid] = pnc;
    }
    __syncthreads();

    int lane = tid & 63, wave = tid >> 6;
    if (wave < 7) {
        int nf = wave;
        int rl = lane & 15, kh = lane >> 4;
        int o = nf*16 + rl;
        const ushort* bhp = Wh + o*96 + kh*8;
        const ushort* blp = Wl + o*96 + kh*8;
        short8 bh0 = *(const short8*)(bhp);
        short8 bh1 = *(const short8*)(bhp + 32);
        short8 bh2 = *(const short8*)(bhp + 64);
        short8 bl0 = *(const short8*)(blp);
        short8 bl1 = *(const short8*)(blp + 32);
        short8 bl2 = *(const short8*)(blp + 64);
        float w0 = wn1[o*3], w1v = wn1[o*3+1], w2v = wn1[o*3+2];
        int swz = (rl >> 1) & 3;
        int kx = (kh ^ swz) * 16;
        bool valid = (o < 100);
        float* mystat = rstat + wave*288;
#pragma unroll
        for (int mf = 0; mf < 9; ++mf) {
            int rbase = (mf*16 + rl)*64;
            short8 ah0 = *(const short8*)((const char*)Ah + rbase + kx);
            short8 al0 = *(const short8*)((const char*)Al + rbase + kx);
            short8 ah1 = *(const short8*)((const char*)Ah + 9216 + rbase + kx);
            short8 al1 = *(const short8*)((const char*)Al + 9216 + rbase + kx);
            short8 ah2 = *(const short8*)((const char*)Ah + 18432 + rbase + kx);
            short8 al2 = *(const short8*)((const char*)Al + 18432 + rbase + kx);
            f32x4 a0 = {0.f,0.f,0.f,0.f}, a1 = {0.f,0.f,0.f,0.f}, a2 = {0.f,0.f,0.f,0.f};
            a0 = __builtin_amdgcn_mfma_f32_16x16x32_bf16(ah0, bh0, a0, 0, 0, 0);
            a1 = __builtin_amdgcn_mfma_f32_16x16x32_bf16(ah1, bh1, a1, 0, 0, 0);
            a2 = __builtin_amdgcn_mfma_f32_16x16x32_bf16(ah2, bh2, a2, 0, 0, 0);
            a0 = __builtin_amdgcn_mfma_f32_16x16x32_bf16(ah0, bl0, a0, 0, 0, 0);
            a1 = __builtin_amdgcn_mfma_f32_16x16x32_bf16(ah1, bl1, a1, 0, 0, 0);
            a2 = __builtin_amdgcn_mfma_f32_16x16x32_bf16(ah2, bl2, a2, 0, 0, 0);
            a0 = __builtin_amdgcn_mfma_f32_16x16x32_bf16(al0, bh0, a0, 0, 0, 0);
            a1 = __builtin_amdgcn_mfma_f32_16x16x32_bf16(al1, bh1, a1, 0, 0, 0);
            a2 = __builtin_amdgcn_mfma_f32_16x16x32_bf16(al2, bh2, a2, 0, 0, 0);
            float dsum[4], dsq[4];
            size_t base = (size_t)(b4*144 + mf*16 + kh*4)*100 + o;
#pragma unroll
            for (int r = 0; r < 4; ++r) {
                int row = mf*16 + kh*4 + r;
                float d = FSQRT(fmaxf(pnl[row*3+0] + w0  - 2.f*a0[r], 1e-12f))
                        + FSQRT(fmaxf(pnl[row*3+1] + w1v - 2.f*a1[r], 1e-12f))
                        + FSQRT(fmaxf(pnl[row*3+2] + w2v - 2.f*a2[r], 1e-12f));
                float dv = valid ? d : 0.f;
                if (valid) dist1[base + (size_t)r*100] = d;
                dsum[r] = dv; dsq[r] = dv*dv;
            }
#pragma unroll
            for (int m = 1; m <= 8; m <<= 1) {
#pragma unroll
                for (int r = 0; r < 4; ++r) {
                    dsum[r] += __shfl_xor(dsum[r], m, 64);
                    dsq[r]  += __shfl_xor(dsq[r],  m, 64);
                }
            }
            if (rl == 0) {
#pragma unroll
                for (int r = 0; r < 4; ++r) {
                    int row = mf*16 + kh*4 + r;
                    mystat[row*2]     = dsum[r];
                    mystat[row*2 + 1] = dsq[r];
                }
            }
        }
    }
    __syncthreads();
    if (tid < 72) {
        int p = tid >> 1, w = tid & 1;
        float s = 0.f;
#pragma unroll
        for (int wv = 0; wv < 7; ++wv)
#pragma unroll
            for (int g = 0; g < 4; ++g)
                s += rstat[wv*288 + (p + 36*g)*2 + w];
        pixstat[(size_t)b4*72 + 2*p + w] = s;
    }
}

// reduce per-block pixel partials -> scale[p], p = blockIdx.x (36 blocks)
__global__ __launch_bounds__(256) void finalize36_kernel(
    const float* __restrict__ pixstat, float* __restrict__ scale) {
    __shared__ double ss[256], qq[256];
    int p = blockIdx.x, tid = threadIdx.x;
    double s = 0.0, q = 0.0;
    for (int b = tid; b < 1024; b += 256) {
        s += (double)pixstat[(size_t)b*72 + 2*p];
        q += (double)pixstat[(size_t)b*72 + 2*p + 1];
    }
    ss[tid] = s; qq[tid] = q; __syncthreads();
    for (int st = 128; st > 0; st >>= 1) {
        if (tid < st) { ss[tid] += ss[tid+st]; qq[tid] += qq[tid+st]; }
        __syncthreads();
    }
    if (tid == 0) {
        const double N = 409600.0;
        double m = ss[0] / N;
        double var = (qq[0] - N*m*m) / (N - 1.0);
        scale[p] = (float)(0.5 / var);
    }
}

// exp+crelu(0.4)+SFM1: dist1 -> y2 [36864,100] (fallback path)
__global__ __launch_bounds__(256) void sfm1_kernel(
    const float* __restrict__ dist1, const float* __restrict__ scale,
    float* __restrict__ y2) {
    int gid = blockIdx.x*256 + threadIdx.x;
    if (gid >= 36864*100) return;
    int c = gid % 100, n = gid / 100;
    int b = n / 9, ij = n % 9, i = ij / 3, j = ij % 3;
    const float alpha[2][2] = {{0.729f, 0.81f},{0.9f, 1.0f}};
    float acc = 0.f;
#pragma unroll
    for (int fh = 0; fh < 2; ++fh)
#pragma unroll
        for (int fw = 0; fw < 2; ++fw) {
            int p = (2*i+fh)*6 + (2*j+fw);
            float d = dist1[(size_t)b*3600 + p*100 + c];
            float v = __expf(-d*d*scale[p]);
            v = (v >= 0.4f) ? v : 0.f;
            acc += alpha[fh][fw]*v;
        }
    y2[gid] = 0.25f * acc;
}

// fused exp+crelu+SFM1+split+norm: dist1 -> Y2 planes [36864][128] + norms (roomy path)
__global__ __launch_bounds__(256) void sfm1s_kernel(
    const float* __restrict__ dist1, const float* __restrict__ scale,
    ushort* __restrict__ H, ushort* __restrict__ L, float* __restrict__ norm) {
    int wave = threadIdx.x >> 6, lane = threadIdx.x & 63;
    int n = blockIdx.x*4 + wave;
    int b = n / 9, ij = n % 9, i = ij / 3, j = ij % 3;
    const float alpha[2][2] = {{0.729f, 0.81f},{0.9f, 1.0f}};
    float s = 0.f;
#pragma unroll
    for (int q = 0; q < 2; ++q) {
        int k = lane + q*64;
        float y = 0.f;
        if (k < 100) {
            float acc = 0.f;
#pragma unroll
            for (int fh = 0; fh < 2; ++fh)
#pragma unroll
                for (int fw = 0; fw < 2; ++fw) {
                    int p = (2*i+fh)*6 + (2*j+fw);
                    float d = dist1[(size_t)b*3600 + p*100 + k];
                    float v = __expf(-d*d*scale[p]);
                    v = (v >= 0.4f) ? v : 0.f;
                    acc += alpha[fh][fw]*v;
                }
            y = 0.25f * acc;
        }
        __hip_bfloat16 hb = __float2bfloat16(y);
        float hf = __bfloat162float(hb);
        __hip_bfloat16 lb = __float2bfloat16(y - hf);
        H[(size_t)n*128 + k] = *(ushort*)&hb;
        L[(size_t)n*128 + k] = *(ushort*)&lb;
        float r = hf + __bfloat162float(lb);
        s += r*r;
    }
    for (int off = 32; off > 0; off >>= 1) s += __shfl_down(s, off, 64);
    if (lane == 0) norm[n] = s;
}

// fused split+pad+rownorm: one wave per row
__global__ __launch_bounds__(256) void splitnorm_kernel(
    const float* __restrict__ src, ushort* __restrict__ H, ushort* __restrict__ L,
    float* __restrict__ norm, int R, int K, int Kp) {
    int wave = threadIdx.x >> 6, lane = threadIdx.x & 63;
    int row = blockIdx.x*4 + wave;
    float s = 0.f;
    if (row < R) {
        for (int k = lane; k < Kp; k += 64) {
            float v = (k < K) ? src[(size_t)row*K + k] : 0.f;
            __hip_bfloat16 hb = __float2bfloat16(v);
            float hf = __bfloat162float(hb);
            __hip_bfloat16 lb = __float2bfloat16(v - hf);
            H[(size_t)row*Kp + k] = *(ushort*)&hb;
            L[(size_t)row*Kp + k] = *(ushort*)&lb;
            float r = hf + __bfloat162float(lb);
            s += r*r;
        }
    } else {
        for (int k = lane; k < Kp; k += 64) {
            H[(size_t)row*Kp + k] = 0;
            L[(size_t)row*Kp + k] = 0;
        }
    }
    for (int off = 32; off > 0; off >>= 1) s += __shfl_down(s, off, 64);
    if (lane == 0) norm[row] = s;
}

// fused exp+crelu+SFM2+split+norm; scale re-derived in-block from GEMM partials
__global__ __launch_bounds__(256) void sfm2s_kernel(
    const float* __restrict__ dist2, const double* __restrict__ part, int nb, double Nstat,
    ushort* __restrict__ H, ushort* __restrict__ L, float* __restrict__ norm) {
    SCALE_FROM_PART(s2);
    int wave = threadIdx.x >> 6, lane = threadIdx.x & 63;
    int n2 = blockIdx.x*4 + wave;
    int b = n2 / 3, i = n2 % 3;
    const float alphaJ[3] = {0.81f, 0.9f, 1.0f};
    float s = 0.f;
#pragma unroll
    for (int q = 0; q < 4; ++q) {
        int k = lane + q*64;
        float y = 0.f;
        if (k < 225) {
            float acc = 0.f;
#pragma unroll
            for (int j = 0; j < 3; ++j) {
                float d = dist2[((size_t)(b*9 + i*3 + j))*225 + k];
                float v = __expf(-d*d*s2);
                v = (v >= 0.1f) ? v : 0.f;
                acc += alphaJ[j]*v;
            }
            y = acc * (1.f/3.f);
        }
        __hip_bfloat16 hb = __float2bfloat16(y);
        float hf = __bfloat162float(hb);
        __hip_bfloat16 lb = __float2bfloat16(y - hf);
        H[(size_t)n2*256 + k] = *(ushort*)&hb;
        L[(size_t)n2*256 + k] = *(ushort*)&lb;
        float r = hf + __bfloat162float(lb);
        s += r*r;
    }
    for (int off = 32; off > 0; off >>= 1) s += __shfl_down(s, off, 64);
    if (lane == 0) norm[n2] = s;
}

// fused exp+crelu+SFM3+split+norm; scale re-derived in-block
__global__ __launch_bounds__(256) void sfm3s_kernel(
    const float* __restrict__ dist3, const double* __restrict__ part, int nb, double Nstat,
    ushort* __restrict__ H, ushort* __restrict__ L, float* __restrict__ norm) {
    SCALE_FROM_PART(s3);
    int wave = threadIdx.x >> 6, lane = threadIdx.x & 63;
    int b = blockIdx.x*4 + wave;
    const float alphaI[3] = {0.81f, 0.9f, 1.0f};
    float s = 0.f;
#pragma unroll
    for (int q = 0; q < 10; ++q) {
        int k = lane + q*64;
        float y = 0.f;
        if (k < 625) {
            float acc = 0.f;
#pragma unroll
            for (int i = 0; i < 3; ++i) {
                float d = dist3[((size_t)(b*3 + i))*625 + k];
                float v = __expf(-d*d*s3);
                v = (v >= 0.01f) ? v : 0.f;
                acc += alphaI[i]*v;
            }
            y = acc * (1.f/3.f);
        }
        __hip_bfloat16 hb = __float2bfloat16(y);
        float hf = __bfloat162float(hb);
        __hip_bfloat16 lb = __float2bfloat16(y - hf);
        H[(size_t)b*640 + k] = *(ushort*)&hb;
        L[(size_t)b*640 + k] = *(ushort*)&lb;
        float r = hf + __bfloat162float(lb);
        s += r*r;
    }
    for (int off = 32; off > 0; off >>= 1) s += __shfl_down(s, off, 64);
    if (lane == 0) norm[b] = s;
}

// ---------------- unified dist GEMM: 64x128 tile, 8 waves, 24KB LDS, gl_lds ----------------
__global__ __launch_bounds__(512, 4) void distg_mfma(
    const ushort* __restrict__ Yh, const ushort* __restrict__ Yl,   // [N][Kp]
    const ushort* __restrict__ Wh, const ushort* __restrict__ Wl,   // [Opad][Kp]
    const float* __restrict__ pn, const float* __restrict__ wn,
    float* __restrict__ D, int N, int O, int Kp,
    double* __restrict__ part) {
    __shared__ ushort Ahs[2048], Als[2048], Bhs[4096], Bls[4096];   // 24 KB
    __shared__ double wred[8][2];
    int tid = threadIdx.x, lane = tid & 63, wave = tid >> 6;
    int bn = blockIdx.x * 64, bo = blockIdx.y * 128;
    int wm = wave >> 2, wq = wave & 3;

    int rL = lane >> 2, cL = lane & 3;
    int cs = cL ^ ((rL >> 1) & 3);
    size_t boff = (size_t)(bo + wave*16 + rL) * Kp + cs*8;
    ushort* lBh = Bhs + wave*512;
    ushort* lBl = Bls + wave*512;
    int aw = wave & 3;
    size_t aoff = (size_t)(bn + aw*16 + rL) * Kp + cs*8;
    ushort* lA = ((wave < 4) ? Ahs : Als) + aw*512;
    const ushort* Asrc = (wave < 4) ? Yh : Yl;

    int rl = lane & 15, kh = lane >> 4;
    int kbs_r = kh ^ ((rl >> 1) & 3);
    int raoff[2], rboff[2];
#pragma unroll
    for (int mf = 0; mf < 2; ++mf) raoff[mf] = (wm*32 + mf*16 + rl)*64 + kbs_r*16;
#pragma unroll
    for (int nf = 0; nf < 2; ++nf) rboff[nf] = (wq*32 + nf*16 + rl)*64 + kbs_r*16;

    f32x4 acc[2][2];
#pragma unroll
    for (int mf = 0; mf < 2; ++mf)
#pragma unroll
        for (int nf = 0; nf < 2; ++nf) acc[mf][nf] = (f32x4){0.f,0.f,0.f,0.f};

    int NT = Kp >> 5;
    for (int t = 0; t < NT; ++t) {
        int k0 = t*32;
        GL16(Asrc + aoff + k0, lA);
        GL16(Wh + boff + k0, lBh);
        GL16(Wl + boff + k0, lBl);
        __syncthreads();
        short8 a_h[2], a_l[2];
#pragma unroll
        for (int mf = 0; mf < 2; ++mf) {
            a_h[mf] = *(const short8*)((const char*)Ahs + raoff[mf]);
            a_l[mf] = *(const short8*)((const char*)Als + raoff[mf]);
        }
#pragma unroll
        for (int nf = 0; nf < 2; ++nf) {
            short8 b_h = *(const short8*)((const char*)Bhs + rboff[nf]);
            short8 b_l = *(const short8*)((const char*)Bls + rboff[nf]);
#pragma unroll
            for (int mf = 0; mf < 2; ++mf) {
                acc[mf][nf] = __builtin_amdgcn_mfma_f32_16x16x32_bf16(a_h[mf], b_h, acc[mf][nf], 0, 0, 0);
                acc[mf][nf] = __builtin_amdgcn_mfma_f32_16x16x32_bf16(a_h[mf], b_l, acc[mf][nf], 0, 0, 0);
                acc[mf][nf] = __builtin_amdgcn_mfma_f32_16x16x32_bf16(a_l[mf], b_h, acc[mf][nf], 0, 0, 0);
            }
        }
        __syncthreads();
    }

    double lsum = 0.0, lsq = 0.0;
#pragma unroll
    for (int mf = 0; mf < 2; ++mf) {
#pragma unroll
        for (int r = 0; r < 4; ++r) {
            int n = bn + wm*32 + mf*16 + kh*4 + r;
            float pv = pn[n];
#pragma unroll
            for (int nf = 0; nf < 2; ++nf) {
                int o = bo + wq*32 + nf*16 + rl;
                if (o < O) {
                    float d2 = pv + wn[o] - 2.f*acc[mf][nf][r];
                    float dd = FSQRT(fmaxf(d2, 1e-12f));
                    D[(size_t)n*O + o] = dd;
                    lsum += dd; lsq += (double)dd*dd;
                }
            }
        }
    }
    for (int off = 32; off > 0; off >>= 1) {
        lsum += __shfl_down(lsum, off, 64);
        lsq  += __shfl_down(lsq,  off, 64);
    }
    if (lane == 0) { wred[wave][0] = lsum; wred[wave][1] = lsq; }
    __syncthreads();
    if (tid == 0) {
        double s = 0.0, q = 0.0;
#pragma unroll
        for (int w = 0; w < 8; ++w) { s += wred[w][0]; q += wred[w][1]; }
        int bid = blockIdx.y * gridDim.x + blockIdx.x;
        part[2*bid]   = s;
        part[2*bid+1] = q;
    }
}

// exp+crelu(0.01)+FC; scale re-derived in-block: dist4 [4096,1225] -> out [4096,10]
__global__ __launch_bounds__(256) void fc_kernel(
    const float* __restrict__ dist4, const double* __restrict__ part, int nb, double Nstat,
    const float* __restrict__ fcw, const float* __restrict__ fcb,
    float* __restrict__ out) {
    SCALE_FROM_PART(s4);
    int b = blockIdx.x;
    int tid = threadIdx.x;
    float acc[10] = {};
    for (int o = tid; o < 1225; o += 256) {
        float d = dist4[(size_t)b*1225 + o];
        float v = __expf(-d*d*s4);
        v = (v >= 0.01f) ? v : 0.f;
#pragma unroll
        for (int k = 0; k < 10; ++k) acc[k] += v * fcw[k*1225 + o];
    }
    __shared__ float red[10*256];
#pragma unroll
    for (int k = 0; k < 10; ++k) red[k*256 + tid] = acc[k];
    __syncthreads();
    for (int st = 128; st > 0; st >>= 1) {
        if (tid < st) {
#pragma unroll
            for (int k = 0; k < 10; ++k) red[k*256 + tid] += red[k*256 + tid + st];
        }
        __syncthreads();
    }
    if (tid < 10) out[b*10 + tid] = red[tid*256] + fcb[tid];
}

extern "C" void kernel_launch(void* const* d_in, const int* in_sizes, int n_in,
                              void* d_out, int out_size, void* d_ws, size_t ws_size,
                              hipStream_t stream) {
    const float* x     = (const float*)d_in[0];
    const float* rgb_w = (const float*)d_in[1];
    const float* w2    = (const float*)d_in[2];
    const float* w3    = (const float*)d_in[3];
    const float* w4    = (const float*)d_in[4];
    const float* fc_w  = (const float*)d_in[5];
    const float* fc_b  = (const float*)d_in[6];
    float* out = (float*)d_out;

    float* wsf   = (float*)d_ws;
    float* dist  = wsf;                    // 14,745,600 floats
    float* ybuf  = wsf + 14745600;         // 3,686,400 floats
    float* pnb   = ybuf + 3686400;         // 36,864 floats
    float* wnb   = pnb + 36864;            // 1,280
    float* scale = wnb + 1280;             // 64
    double* stats = (double*)(scale + 64); // 78 doubles
    double* pblk  = stats + 78;            // 2304 doubles (max grid 1152 blocks)
    float* wsend  = (float*)(pblk + 2304);

    ushort* W1h = (ushort*)pnb;
    ushort* W1l = W1h + 10752;
    float*  wn1 = (float*)(W1l + 10752);

    float* pixstat = ybuf;

    size_t base_floats = (size_t)(wsend - wsf);
    size_t y2_floats   = 2u * 36864u * 128u / 2u;
    bool roomy = ws_size >= (base_floats + y2_floats + 1024) * sizeof(float);

    ushort* Y2h = roomy ? (ushort*)wsend : (ushort*)(dist + 8388608);
    ushort* Y2l = Y2h + 36864*128;
    ushort* W2h = (ushort*)(dist + 8388608) + 2*36864*128;
    ushort* W2l = W2h + 256*128;
    ushort* Y3h = (ushort*)ybuf;
    ushort* Y3l = Y3h + 12288*256;
    ushort* W3h = Y3l + 12288*256;
    ushort* W3l = W3h + 640*256;
    ushort* Y4h = (ushort*)ybuf;
    ushort* Y4l = Y4h + 4096*640;
    ushort* W4h = Y4l + 4096*640;
    ushort* W4l = W4h + 1280*640;

    // ---- layer 1 ----
    w1prep_kernel<<<84, 256, 0, stream>>>(rgb_w, W1h, W1l, wn1, stats);
    rbf1_mfma<<<1024, 512, 0, stream>>>(x, W1h, W1l, wn1, dist, pixstat);
    finalize36_kernel<<<36, 256, 0, stream>>>(pixstat, scale);

    // ---- layer 1 -> 2 transition ----
    if (roomy) {
        sfm1s_kernel<<<36864/4, 256, 0, stream>>>(dist, scale, Y2h, Y2l, pnb);
    } else {
        sfm1_kernel<<<DIV_UP(36864*100,256), 256, 0, stream>>>(dist, scale, ybuf);
        splitnorm_kernel<<<36864/4, 256, 0, stream>>>(ybuf, Y2h, Y2l, pnb, 36864, 100, 128);
    }
    splitnorm_kernel<<<256/4, 256, 0, stream>>>(w2, W2h, W2l, wnb, 225, 100, 128);

    // ---- layer 2: 64x128 tiles -> grid (576,2)=1152 blocks ----
    distg_mfma<<<dim3(576,2), 512, 0, stream>>>(Y2h, Y2l, W2h, W2l, pnb, wnb, dist, 36864, 225, 128, pblk);
    sfm2s_kernel<<<12288/4, 256, 0, stream>>>(dist, pblk, 1152, 8294400.0, Y3h, Y3l, pnb);

    // ---- layer 3: grid (192,5)=960 blocks ----
    splitnorm_kernel<<<640/4, 256, 0, stream>>>(w3, W3h, W3l, wnb, 625, 225, 256);
    distg_mfma<<<dim3(192,5), 512, 0, stream>>>(Y3h, Y3l, W3h, W3l, pnb, wnb, dist, 12288, 625, 256, pblk);
    sfm3s_kernel<<<4096/4, 256, 0, stream>>>(dist, pblk, 960, 7680000.0, Y4h, Y4l, pnb);

    // ---- layer 4: grid (64,10)=640 blocks ----
    splitnorm_kernel<<<1280/4, 256, 0, stream>>>(w4, W4h, W4l, wnb, 1225, 625, 640);
    distg_mfma<<<dim3(64,10), 512, 0, stream>>>(Y4h, Y4l, W4h, W4l, pnb, wnb, dist, 4096, 1225, 640, pblk);

    // ---- FC (scale re-derived in-block) ----
    fc_kernel<<<4096, 256, 0, stream>>>(dist, pblk, 640, 5017600.0, fc_w, fc_b, out);
}

// Round 22
// 191.432 us; speedup vs baseline: 1.2800x; 1.0576x over previous
//
#include <hip/hip_runtime.h>
#include <hip/hip_bf16.h>
#include <math.h>

#define DIV_UP(a,b) (((a)+(b)-1)/(b))
#define FSQRT(x) __builtin_amdgcn_sqrtf(x)

typedef __attribute__((ext_vector_type(8))) short short8;
typedef __attribute__((ext_vector_type(4))) float f32x4;

// async global->LDS, 16B per lane; gptr per-lane, lptr wave-uniform
#define GL16(g, l) __builtin_amdgcn_global_load_lds( \
    (const __attribute__((address_space(1))) void*)(g), \
    (__attribute__((address_space(3))) void*)(l), 16, 0, 0)

// in-block redundant scale derivation from per-block GEMM partials
#define SCALE_FROM_PART(OUTVAR) \
    __shared__ double ss_[256], qq_[256]; \
    __shared__ float ssc_; \
    { int t_ = threadIdx.x; double s_ = 0.0, q_ = 0.0; \
      for (int i_ = t_; i_ < nb; i_ += 256) { s_ += part[2*i_]; q_ += part[2*i_+1]; } \
      ss_[t_] = s_; qq_[t_] = q_; __syncthreads(); \
      for (int st_ = 128; st_ > 0; st_ >>= 1) { \
          if (t_ < st_) { ss_[t_] += ss_[t_+st_]; qq_[t_] += qq_[t_+st_]; } \
          __syncthreads(); } \
      if (t_ == 0) { double m_ = ss_[0] / Nstat; \
          double var_ = (qq_[0] - Nstat*m_*m_) / (Nstat - 1.0); \
          ssc_ = (float)(0.5 / var_); } \
      __syncthreads(); } \
    float OUTVAR = ssc_;

// shared row split+pad+norm body
__device__ __forceinline__ void splitnorm_row(
    const float* __restrict__ src, ushort* __restrict__ H, ushort* __restrict__ L,
    float* __restrict__ norm, int R, int K, int Kp, int row, int lane) {
    float s = 0.f;
    if (row < R) {
        for (int k = lane; k < Kp; k += 64) {
            float v = (k < K) ? src[(size_t)row*K + k] : 0.f;
            __hip_bfloat16 hb = __float2bfloat16(v);
            float hf = __bfloat162float(hb);
            __hip_bfloat16 lb = __float2bfloat16(v - hf);
            H[(size_t)row*Kp + k] = *(ushort*)&hb;
            L[(size_t)row*Kp + k] = *(ushort*)&lb;
            float r = hf + __bfloat162float(lb);
            s += r*r;
        }
    } else {
        for (int k = lane; k < Kp; k += 64) {
            H[(size_t)row*Kp + k] = 0;
            L[(size_t)row*Kp + k] = 0;
        }
    }
    for (int off = 32; off > 0; off >>= 1) s += __shfl_down(s, off, 64);
    if (lane == 0) norm[row] = s;
}

// ---------------- ALL weight prep in ONE kernel (block-range dispatch) ----------------
// blocks [0,84): W1 split + per-(o,c) norm
// blocks [84,148): W2 splitnorm; [148,308): W3; [308,628): W4 (only if frontload)
__global__ __launch_bounds__(256) void prep_all_kernel(
    const float* __restrict__ w1, ushort* __restrict__ W1h, ushort* __restrict__ W1l,
    float* __restrict__ wn1,
    const float* __restrict__ w2, ushort* __restrict__ W2h, ushort* __restrict__ W2l,
    float* __restrict__ wn2,
    const float* __restrict__ w3, ushort* __restrict__ W3h, ushort* __restrict__ W3l,
    float* __restrict__ wn3,
    const float* __restrict__ w4, ushort* __restrict__ W4h, ushort* __restrict__ W4l,
    float* __restrict__ wn4,
    int frontload) {
    int blk = blockIdx.x;
    int wave = threadIdx.x >> 6, lane = threadIdx.x & 63;
    if (blk < 84) {
        int j = blk*4 + wave;           // 0..335
        if (j >= 336) return;
        int o = j / 3, c = j - o*3;
        float s = 0.f;
        if (lane < 32) {
            int k = lane;
            float v = (o < 100 && k < 25) ? w1[o*75 + c*25 + k] : 0.f;
            __hip_bfloat16 hb = __float2bfloat16(v);
            float hf = __bfloat162float(hb);
            __hip_bfloat16 lb = __float2bfloat16(v - hf);
            W1h[o*96 + c*32 + k] = *(ushort*)&hb;
            W1l[o*96 + c*32 + k] = *(ushort*)&lb;
            float r = hf + __bfloat162float(lb);
            s = r*r;
        }
#pragma unroll
        for (int off = 16; off > 0; off >>= 1) s += __shfl_down(s, off, 64);
        if (lane == 0) wn1[j] = s;
    } else if (!frontload) {
        return;
    } else if (blk < 148) {
        int row = (blk - 84)*4 + wave;      // 0..255
        splitnorm_row(w2, W2h, W2l, wn2, 225, 100, 128, row, lane);
    } else if (blk < 308) {
        int row = (blk - 148)*4 + wave;     // 0..639
        splitnorm_row(w3, W3h, W3l, wn3, 625, 225, 256, row, lane);
    } else {
        int row = (blk - 308)*4 + wave;     // 0..1279
        splitnorm_row(w4, W4h, W4l, wn4, 1225, 625, 640, row, lane);
    }
}

// standalone splitnorm (fallback path)
__global__ __launch_bounds__(256) void splitnorm_kernel(
    const float* __restrict__ src, ushort* __restrict__ H, ushort* __restrict__ L,
    float* __restrict__ norm, int R, int K, int Kp) {
    int wave = threadIdx.x >> 6, lane = threadIdx.x & 63;
    int row = blockIdx.x*4 + wave;
    splitnorm_row(src, H, L, norm, R, K, Kp, row, lane);
}

// ---------------- layer 1 MFMA (+fused stats, per-wave private LDS, no atomics) ----------------
__global__ __launch_bounds__(512, 2) void rbf1_mfma(
    const float* __restrict__ x, const ushort* __restrict__ Wh, const ushort* __restrict__ Wl,
    const float* __restrict__ wn1, float* __restrict__ dist1,
    float* __restrict__ pixstat) {
    __shared__ ushort Ah[3*144*32];
    __shared__ ushort Al[3*144*32];
    __shared__ float pnl[432];
    __shared__ float rstat[7*144*2];
    int tid = threadIdx.x;
    int b4 = blockIdx.x;

    if (tid < 432) {
        int row = tid / 3, c = tid - row*3;
        int img = row / 36, p = row - img*36;
        int ph = p / 6, pw = p - ph*6;
        const float* xp = x + (size_t)b4*9408 + img*2352 + c*784 + (ph*28 + pw)*4;
        float arr[25];
#pragma unroll
        for (int ki = 0; ki < 5; ++ki) {
            float4 v4 = *(const float4*)(xp + ki*28);
            arr[ki*5+0] = v4.x; arr[ki*5+1] = v4.y;
            arr[ki*5+2] = v4.z; arr[ki*5+3] = v4.w;
            arr[ki*5+4] = xp[ki*28 + 4];
        }
        float pnc = 0.f;
        int tilebase = c*9216 + row*64;
        int r3 = (row >> 1) & 3;
#pragma unroll
        for (int kb = 0; kb < 4; ++kb) {
            uint4 hq, lq;
            uint* hqa = (uint*)&hq;
            uint* lqa = (uint*)&lq;
#pragma unroll
            for (int j = 0; j < 4; ++j) {
                int k0 = kb*8 + 2*j;
                float v0 = (k0 < 25) ? arr[k0] : 0.f;
                float v1 = (k0+1 < 25) ? arr[k0+1] : 0.f;
                __hip_bfloat16 h0 = __float2bfloat16(v0);
                float hf0 = __bfloat162float(h0);
                __hip_bfloat16 l0 = __float2bfloat16(v0 - hf0);
                float r0 = hf0 + __bfloat162float(l0);
                __hip_bfloat16 h1 = __float2bfloat16(v1);
                float hf1 = __bfloat162float(h1);
                __hip_bfloat16 l1 = __float2bfloat16(v1 - hf1);
                float r1 = hf1 + __bfloat162float(l1);
                pnc += r0*r0 + r1*r1;
                hqa[j] = (uint)(*(ushort*)&h0) | ((uint)(*(ushort*)&h1) << 16);
                lqa[j] = (uint)(*(ushort*)&l0) | ((uint)(*(ushort*)&l1) << 16);
            }
            int kbs = kb ^ r3;
            *(uint4*)((char*)Ah + tilebase + kbs*16) = hq;
            *(uint4*)((char*)Al + tilebase + kbs*16) = lq;
        }
        pnl[tid] = pnc;
    }
    __syncthreads();

    int lane = tid & 63, wave = tid >> 6;
    if (wave < 7) {
        int nf = wave;
        int rl = lane & 15, kh = lane >> 4;
        int o = nf*16 + rl;
        const ushort* bhp = Wh + o*96 + kh*8;
        const ushort* blp = Wl + o*96 + kh*8;
        short8 bh0 = *(const short8*)(bhp);
        short8 bh1 = *(const short8*)(bhp + 32);
        short8 bh2 = *(const short8*)(bhp + 64);
        short8 bl0 = *(const short8*)(blp);
        short8 bl1 = *(const short8*)(blp + 32);
        short8 bl2 = *(const short8*)(blp + 64);
        float w0 = wn1[o*3], w1v = wn1[o*3+1], w2v = wn1[o*3+2];
        int swz = (rl >> 1) & 3;
        int kx = (kh ^ swz) * 16;
        bool valid = (o < 100);
        float* mystat = rstat + wave*288;
#pragma unroll
        for (int mf = 0; mf < 9; ++mf) {
            int rbase = (mf*16 + rl)*64;
            short8 ah0 = *(const short8*)((const char*)Ah + rbase + kx);
            short8 al0 = *(const short8*)((const char*)Al + rbase + kx);
            short8 ah1 = *(const short8*)((const char*)Ah + 9216 + rbase + kx);
            short8 al1 = *(const short8*)((const char*)Al + 9216 + rbase + kx);
            short8 ah2 = *(const short8*)((const char*)Ah + 18432 + rbase + kx);
            short8 al2 = *(const short8*)((const char*)Al + 18432 + rbase + kx);
            f32x4 a0 = {0.f,0.f,0.f,0.f}, a1 = {0.f,0.f,0.f,0.f}, a2 = {0.f,0.f,0.f,0.f};
            a0 = __builtin_amdgcn_mfma_f32_16x16x32_bf16(ah0, bh0, a0, 0, 0, 0);
            a1 = __builtin_amdgcn_mfma_f32_16x16x32_bf16(ah1, bh1, a1, 0, 0, 0);
            a2 = __builtin_amdgcn_mfma_f32_16x16x32_bf16(ah2, bh2, a2, 0, 0, 0);
            a0 = __builtin_amdgcn_mfma_f32_16x16x32_bf16(ah0, bl0, a0, 0, 0, 0);
            a1 = __builtin_amdgcn_mfma_f32_16x16x32_bf16(ah1, bl1, a1, 0, 0, 0);
            a2 = __builtin_amdgcn_mfma_f32_16x16x32_bf16(ah2, bl2, a2, 0, 0, 0);
            a0 = __builtin_amdgcn_mfma_f32_16x16x32_bf16(al0, bh0, a0, 0, 0, 0);
            a1 = __builtin_amdgcn_mfma_f32_16x16x32_bf16(al1, bh1, a1, 0, 0, 0);
            a2 = __builtin_amdgcn_mfma_f32_16x16x32_bf16(al2, bh2, a2, 0, 0, 0);
            float dsum[4], dsq[4];
            size_t base = (size_t)(b4*144 + mf*16 + kh*4)*100 + o;
#pragma unroll
            for (int r = 0; r < 4; ++r) {
                int row = mf*16 + kh*4 + r;
                float d = FSQRT(fmaxf(pnl[row*3+0] + w0  - 2.f*a0[r], 1e-12f))
                        + FSQRT(fmaxf(pnl[row*3+1] + w1v - 2.f*a1[r], 1e-12f))
                        + FSQRT(fmaxf(pnl[row*3+2] + w2v - 2.f*a2[r], 1e-12f));
                float dv = valid ? d : 0.f;
                if (valid) dist1[base + (size_t)r*100] = d;
                dsum[r] = dv; dsq[r] = dv*dv;
            }
#pragma unroll
            for (int m = 1; m <= 8; m <<= 1) {
#pragma unroll
                for (int r = 0; r < 4; ++r) {
                    dsum[r] += __shfl_xor(dsum[r], m, 64);
                    dsq[r]  += __shfl_xor(dsq[r],  m, 64);
                }
            }
            if (rl == 0) {
#pragma unroll
                for (int r = 0; r < 4; ++r) {
                    int row = mf*16 + kh*4 + r;
                    mystat[row*2]     = dsum[r];
                    mystat[row*2 + 1] = dsq[r];
                }
            }
        }
    }
    __syncthreads();
    if (tid < 72) {
        int p = tid >> 1, w = tid & 1;
        float s = 0.f;
#pragma unroll
        for (int wv = 0; wv < 7; ++wv)
#pragma unroll
            for (int g = 0; g < 4; ++g)
                s += rstat[wv*288 + (p + 36*g)*2 + w];
        pixstat[(size_t)b4*72 + 2*p + w] = s;
    }
}

// reduce per-block pixel partials -> scale[p]
__global__ __launch_bounds__(256) void finalize36_kernel(
    const float* __restrict__ pixstat, float* __restrict__ scale) {
    __shared__ double ss[256], qq[256];
    int p = blockIdx.x, tid = threadIdx.x;
    double s = 0.0, q = 0.0;
    for (int b = tid; b < 1024; b += 256) {
        s += (double)pixstat[(size_t)b*72 + 2*p];
        q += (double)pixstat[(size_t)b*72 + 2*p + 1];
    }
    ss[tid] = s; qq[tid] = q; __syncthreads();
    for (int st = 128; st > 0; st >>= 1) {
        if (tid < st) { ss[tid] += ss[tid+st]; qq[tid] += qq[tid+st]; }
        __syncthreads();
    }
    if (tid == 0) {
        const double N = 409600.0;
        double m = ss[0] / N;
        double var = (qq[0] - N*m*m) / (N - 1.0);
        scale[p] = (float)(0.5 / var);
    }
}

// exp+crelu(0.4)+SFM1 fallback: dist1 -> y2 fp32
__global__ __launch_bounds__(256) void sfm1_kernel(
    const float* __restrict__ dist1, const float* __restrict__ scale,
    float* __restrict__ y2) {
    int gid = blockIdx.x*256 + threadIdx.x;
    if (gid >= 36864*100) return;
    int c = gid % 100, n = gid / 100;
    int b = n / 9, ij = n % 9, i = ij / 3, j = ij % 3;
    const float alpha[2][2] = {{0.729f, 0.81f},{0.9f, 1.0f}};
    float acc = 0.f;
#pragma unroll
    for (int fh = 0; fh < 2; ++fh)
#pragma unroll
        for (int fw = 0; fw < 2; ++fw) {
            int p = (2*i+fh)*6 + (2*j+fw);
            float d = dist1[(size_t)b*3600 + p*100 + c];
            float v = __expf(-d*d*scale[p]);
            v = (v >= 0.4f) ? v : 0.f;
            acc += alpha[fh][fw]*v;
        }
    y2[gid] = 0.25f * acc;
}

// fused exp+crelu+SFM1+split+norm (roomy path)
__global__ __launch_bounds__(256) void sfm1s_kernel(
    const float* __restrict__ dist1, const float* __restrict__ scale,
    ushort* __restrict__ H, ushort* __restrict__ L, float* __restrict__ norm) {
    int wave = threadIdx.x >> 6, lane = threadIdx.x & 63;
    int n = blockIdx.x*4 + wave;
    int b = n / 9, ij = n % 9, i = ij / 3, j = ij % 3;
    const float alpha[2][2] = {{0.729f, 0.81f},{0.9f, 1.0f}};
    float s = 0.f;
#pragma unroll
    for (int q = 0; q < 2; ++q) {
        int k = lane + q*64;
        float y = 0.f;
        if (k < 100) {
            float acc = 0.f;
#pragma unroll
            for (int fh = 0; fh < 2; ++fh)
#pragma unroll
                for (int fw = 0; fw < 2; ++fw) {
                    int p = (2*i+fh)*6 + (2*j+fw);
                    float d = dist1[(size_t)b*3600 + p*100 + k];
                    float v = __expf(-d*d*scale[p]);
                    v = (v >= 0.4f) ? v : 0.f;
                    acc += alpha[fh][fw]*v;
                }
            y = 0.25f * acc;
        }
        __hip_bfloat16 hb = __float2bfloat16(y);
        float hf = __bfloat162float(hb);
        __hip_bfloat16 lb = __float2bfloat16(y - hf);
        H[(size_t)n*128 + k] = *(ushort*)&hb;
        L[(size_t)n*128 + k] = *(ushort*)&lb;
        float r = hf + __bfloat162float(lb);
        s += r*r;
    }
    for (int off = 32; off > 0; off >>= 1) s += __shfl_down(s, off, 64);
    if (lane == 0) norm[n] = s;
}

// fused exp+crelu+SFM2+split+norm; scale re-derived in-block
__global__ __launch_bounds__(256) void sfm2s_kernel(
    const float* __restrict__ dist2, const double* __restrict__ part, int nb, double Nstat,
    ushort* __restrict__ H, ushort* __restrict__ L, float* __restrict__ norm) {
    SCALE_FROM_PART(s2);
    int wave = threadIdx.x >> 6, lane = threadIdx.x & 63;
    int n2 = blockIdx.x*4 + wave;
    int b = n2 / 3, i = n2 % 3;
    const float alphaJ[3] = {0.81f, 0.9f, 1.0f};
    float s = 0.f;
#pragma unroll
    for (int q = 0; q < 4; ++q) {
        int k = lane + q*64;
        float y = 0.f;
        if (k < 225) {
            float acc = 0.f;
#pragma unroll
            for (int j = 0; j < 3; ++j) {
                float d = dist2[((size_t)(b*9 + i*3 + j))*225 + k];
                float v = __expf(-d*d*s2);
                v = (v >= 0.1f) ? v : 0.f;
                acc += alphaJ[j]*v;
            }
            y = acc * (1.f/3.f);
        }
        __hip_bfloat16 hb = __float2bfloat16(y);
        float hf = __bfloat162float(hb);
        __hip_bfloat16 lb = __float2bfloat16(y - hf);
        H[(size_t)n2*256 + k] = *(ushort*)&hb;
        L[(size_t)n2*256 + k] = *(ushort*)&lb;
        float r = hf + __bfloat162float(lb);
        s += r*r;
    }
    for (int off = 32; off > 0; off >>= 1) s += __shfl_down(s, off, 64);
    if (lane == 0) norm[n2] = s;
}

// fused exp+crelu+SFM3+split+norm; scale re-derived in-block
__global__ __launch_bounds__(256) void sfm3s_kernel(
    const float* __restrict__ dist3, const double* __restrict__ part, int nb, double Nstat,
    ushort* __restrict__ H, ushort* __restrict__ L, float* __restrict__ norm) {
    SCALE_FROM_PART(s3);
    int wave = threadIdx.x >> 6, lane = threadIdx.x & 63;
    int b = blockIdx.x*4 + wave;
    const float alphaI[3] = {0.81f, 0.9f, 1.0f};
    float s = 0.f;
#pragma unroll
    for (int q = 0; q < 10; ++q) {
        int k = lane + q*64;
        float y = 0.f;
        if (k < 625) {
            float acc = 0.f;
#pragma unroll
            for (int i = 0; i < 3; ++i) {
                float d = dist3[((size_t)(b*3 + i))*625 + k];
                float v = __expf(-d*d*s3);
                v = (v >= 0.01f) ? v : 0.f;
                acc += alphaI[i]*v;
            }
            y = acc * (1.f/3.f);
        }
        __hip_bfloat16 hb = __float2bfloat16(y);
        float hf = __bfloat162float(hb);
        __hip_bfloat16 lb = __float2bfloat16(y - hf);
        H[(size_t)b*640 + k] = *(ushort*)&hb;
        L[(size_t)b*640 + k] = *(ushort*)&lb;
        float r = hf + __bfloat162float(lb);
        s += r*r;
    }
    for (int off = 32; off > 0; off >>= 1) s += __shfl_down(s, off, 64);
    if (lane == 0) norm[b] = s;
}

// ---------------- unified dist GEMM: 64x128 tile, 8 waves, 24KB LDS, gl_lds ----------------
__global__ __launch_bounds__(512, 4) void distg_mfma(
    const ushort* __restrict__ Yh, const ushort* __restrict__ Yl,
    const ushort* __restrict__ Wh, const ushort* __restrict__ Wl,
    const float* __restrict__ pn, const float* __restrict__ wn,
    float* __restrict__ D, int N, int O, int Kp,
    double* __restrict__ part) {
    __shared__ ushort Ahs[2048], Als[2048], Bhs[4096], Bls[4096];
    __shared__ double wred[8][2];
    int tid = threadIdx.x, lane = tid & 63, wave = tid >> 6;
    int bn = blockIdx.x * 64, bo = blockIdx.y * 128;
    int wm = wave >> 2, wq = wave & 3;

    int rL = lane >> 2, cL = lane & 3;
    int cs = cL ^ ((rL >> 1) & 3);
    size_t boff = (size_t)(bo + wave*16 + rL) * Kp + cs*8;
    ushort* lBh = Bhs + wave*512;
    ushort* lBl = Bls + wave*512;
    int aw = wave & 3;
    size_t aoff = (size_t)(bn + aw*16 + rL) * Kp + cs*8;
    ushort* lA = ((wave < 4) ? Ahs : Als) + aw*512;
    const ushort* Asrc = (wave < 4) ? Yh : Yl;

    int rl = lane & 15, kh = lane >> 4;
    int kbs_r = kh ^ ((rl >> 1) & 3);
    int raoff[2], rboff[2];
#pragma unroll
    for (int mf = 0; mf < 2; ++mf) raoff[mf] = (wm*32 + mf*16 + rl)*64 + kbs_r*16;
#pragma unroll
    for (int nf = 0; nf < 2; ++nf) rboff[nf] = (wq*32 + nf*16 + rl)*64 + kbs_r*16;

    f32x4 acc[2][2];
#pragma unroll
    for (int mf = 0; mf < 2; ++mf)
#pragma unroll
        for (int nf = 0; nf < 2; ++nf) acc[mf][nf] = (f32x4){0.f,0.f,0.f,0.f};

    int NT = Kp >> 5;
    for (int t = 0; t < NT; ++t) {
        int k0 = t*32;
        GL16(Asrc + aoff + k0, lA);
        GL16(Wh + boff + k0, lBh);
        GL16(Wl + boff + k0, lBl);
        __syncthreads();
        short8 a_h[2], a_l[2];
#pragma unroll
        for (int mf = 0; mf < 2; ++mf) {
            a_h[mf] = *(const short8*)((const char*)Ahs + raoff[mf]);
            a_l[mf] = *(const short8*)((const char*)Als + raoff[mf]);
        }
#pragma unroll
        for (int nf = 0; nf < 2; ++nf) {
            short8 b_h = *(const short8*)((const char*)Bhs + rboff[nf]);
            short8 b_l = *(const short8*)((const char*)Bls + rboff[nf]);
#pragma unroll
            for (int mf = 0; mf < 2; ++mf) {
                acc[mf][nf] = __builtin_amdgcn_mfma_f32_16x16x32_bf16(a_h[mf], b_h, acc[mf][nf], 0, 0, 0);
                acc[mf][nf] = __builtin_amdgcn_mfma_f32_16x16x32_bf16(a_h[mf], b_l, acc[mf][nf], 0, 0, 0);
                acc[mf][nf] = __builtin_amdgcn_mfma_f32_16x16x32_bf16(a_l[mf], b_h, acc[mf][nf], 0, 0, 0);
            }
        }
        __syncthreads();
    }

    double lsum = 0.0, lsq = 0.0;
#pragma unroll
    for (int mf = 0; mf < 2; ++mf) {
#pragma unroll
        for (int r = 0; r < 4; ++r) {
            int n = bn + wm*32 + mf*16 + kh*4 + r;
            float pv = pn[n];
#pragma unroll
            for (int nf = 0; nf < 2; ++nf) {
                int o = bo + wq*32 + nf*16 + rl;
                if (o < O) {
                    float d2 = pv + wn[o] - 2.f*acc[mf][nf][r];
                    float dd = FSQRT(fmaxf(d2, 1e-12f));
                    D[(size_t)n*O + o] = dd;
                    lsum += dd; lsq += (double)dd*dd;
                }
            }
        }
    }
    for (int off = 32; off > 0; off >>= 1) {
        lsum += __shfl_down(lsum, off, 64);
        lsq  += __shfl_down(lsq,  off, 64);
    }
    if (lane == 0) { wred[wave][0] = lsum; wred[wave][1] = lsq; }
    __syncthreads();
    if (tid == 0) {
        double s = 0.0, q = 0.0;
#pragma unroll
        for (int w = 0; w < 8; ++w) { s += wred[w][0]; q += wred[w][1]; }
        int bid = blockIdx.y * gridDim.x + blockIdx.x;
        part[2*bid]   = s;
        part[2*bid+1] = q;
    }
}

// exp+crelu(0.01)+FC; scale re-derived in-block
__global__ __launch_bounds__(256) void fc_kernel(
    const float* __restrict__ dist4, const double* __restrict__ part, int nb, double Nstat,
    const float* __restrict__ fcw, const float* __restrict__ fcb,
    float* __restrict__ out) {
    SCALE_FROM_PART(s4);
    int b = blockIdx.x;
    int tid = threadIdx.x;
    float acc[10] = {};
    for (int o = tid; o < 1225; o += 256) {
        float d = dist4[(size_t)b*1225 + o];
        float v = __expf(-d*d*s4);
        v = (v >= 0.01f) ? v : 0.f;
#pragma unroll
        for (int k = 0; k < 10; ++k) acc[k] += v * fcw[k*1225 + o];
    }
    __shared__ float red[10*256];
#pragma unroll
    for (int k = 0; k < 10; ++k) red[k*256 + tid] = acc[k];
    __syncthreads();
    for (int st = 128; st > 0; st >>= 1) {
        if (tid < st) {
#pragma unroll
            for (int k = 0; k < 10; ++k) red[k*256 + tid] += red[k*256 + tid + st];
        }
        __syncthreads();
    }
    if (tid < 10) out[b*10 + tid] = red[tid*256] + fcb[tid];
}

extern "C" void kernel_launch(void* const* d_in, const int* in_sizes, int n_in,
                              void* d_out, int out_size, void* d_ws, size_t ws_size,
                              hipStream_t stream) {
    const float* x     = (const float*)d_in[0];
    const float* rgb_w = (const float*)d_in[1];
    const float* w2    = (const float*)d_in[2];
    const float* w3    = (const float*)d_in[3];
    const float* w4    = (const float*)d_in[4];
    const float* fc_w  = (const float*)d_in[5];
    const float* fc_b  = (const float*)d_in[6];
    float* out = (float*)d_out;

    float* wsf   = (float*)d_ws;
    float* dist  = wsf;                    // 14,745,600 floats
    float* ybuf  = wsf + 14745600;         // 3,686,400 floats
    float* pnb   = ybuf + 3686400;         // 36,864 floats
    float* wnb2  = pnb + 36864;            // 256
    float* wnb3  = wnb2 + 256;             // 640
    float* wnb4  = wnb3 + 640;             // 1,280
    float* scale = wnb4 + 1280;            // 64
    double* pblk = (double*)(scale + 64);  // 2304 doubles (8B aligned: offset even)
    float* wsend = (float*)(pblk + 2304);

    ushort* W1h = (ushort*)pnb;
    ushort* W1l = W1h + 10752;
    float*  wn1 = (float*)(W1l + 10752);

    float* pixstat = ybuf;

    size_t base_floats = (size_t)(wsend - wsf);
    size_t y2_floats   = 2u * 36864u * 128u / 2u;       // 4,718,592
    size_t w2_floats   = 2u * 256u * 128u / 2u;         // 32,768
    bool roomy = ws_size >= (base_floats + y2_floats + w2_floats + 1024) * sizeof(float);

    // Y2 planes
    ushort* Y2h = roomy ? (ushort*)wsend : (ushort*)(dist + 8388608);
    ushort* Y2l = Y2h + 36864*128;
    // W2 planes: roomy -> after Y2 planes (safe at t=0); fallback -> dist tail (written late)
    ushort* W2h = roomy ? (Y2l + 36864*128) : ((ushort*)(dist + 8388608) + 2*36864*128);
    ushort* W2l = W2h + 256*128;
    // Y3/Y4 planes in ybuf head
    ushort* Y3h = (ushort*)ybuf;
    ushort* Y3l = Y3h + 12288*256;                      // Y3 ends at float 3,145,728
    ushort* Y4h = (ushort*)ybuf;
    ushort* Y4l = Y4h + 4096*640;                       // Y4 ends at float 2,621,440
    // W4 planes: floats [2,621,440, 3,440,640)
    ushort* W4h = Y4l + 4096*640;
    ushort* W4l = W4h + 1280*640;
    // W3 planes: roomy -> ybuf tail floats [3,522,560, 3,686,400) (disjoint from Y3/W4)
    //            fallback -> old spot after Y3 (written late)
    ushort* W3h = roomy ? (ushort*)(ybuf + 3522560) : (Y3l + 12288*256);
    ushort* W3l = W3h + 640*256;

    // ---- all weight prep (1 launch) ----
    prep_all_kernel<<<628, 256, 0, stream>>>(
        rgb_w, W1h, W1l, wn1,
        w2, W2h, W2l, wnb2,
        w3, W3h, W3l, wnb3,
        w4, W4h, W4l, wnb4,
        roomy ? 1 : 0);

    // ---- layer 1 ----
    rbf1_mfma<<<1024, 512, 0, stream>>>(x, W1h, W1l, wn1, dist, pixstat);
    finalize36_kernel<<<36, 256, 0, stream>>>(pixstat, scale);

    // ---- layer 1 -> 2 transition ----
    if (roomy) {
        sfm1s_kernel<<<36864/4, 256, 0, stream>>>(dist, scale, Y2h, Y2l, pnb);
    } else {
        sfm1_kernel<<<DIV_UP(36864*100,256), 256, 0, stream>>>(dist, scale, ybuf);
        splitnorm_kernel<<<36864/4, 256, 0, stream>>>(ybuf, Y2h, Y2l, pnb, 36864, 100, 128);
        splitnorm_kernel<<<256/4, 256, 0, stream>>>(w2, W2h, W2l, wnb2, 225, 100, 128);
    }

    // ---- layer 2: 64x128 tiles -> grid (576,2)=1152 blocks ----
    distg_mfma<<<dim3(576,2), 512, 0, stream>>>(Y2h, Y2l, W2h, W2l, pnb, wnb2, dist, 36864, 225, 128, pblk);
    sfm2s_kernel<<<12288/4, 256, 0, stream>>>(dist, pblk, 1152, 8294400.0, Y3h, Y3l, pnb);

    // ---- layer 3: grid (192,5)=960 blocks ----
    if (!roomy) splitnorm_kernel<<<640/4, 256, 0, stream>>>(w3, W3h, W3l, wnb3, 625, 225, 256);
    distg_mfma<<<dim3(192,5), 512, 0, stream>>>(Y3h, Y3l, W3h, W3l, pnb, wnb3, dist, 12288, 625, 256, pblk);
    sfm3s_kernel<<<4096/4, 256, 0, stream>>>(dist, pblk, 960, 7680000.0, Y4h, Y4l, pnb);

    // ---- layer 4: grid (64,10)=640 blocks ----
    if (!roomy) splitnorm_kernel<<<1280/4, 256, 0, stream>>>(w4, W4h, W4l, wnb4, 1225, 625, 640);
    distg_mfma<<<dim3(64,10), 512, 0, stream>>>(Y4h, Y4l, W4h, W4l, pnb, wnb4, dist, 4096, 1225, 640, pblk);

    // ---- FC (scale re-derived in-block) ----
    fc_kernel<<<4096, 256, 0, stream>>>(dist, pblk, 640, 5017600.0, fc_w, fc_b, out);
}

// Round 23
// 187.426 us; speedup vs baseline: 1.3074x; 1.0214x over previous
//
#include <hip/hip_runtime.h>
#include <hip/hip_bf16.h>
#include <math.h>

#define DIV_UP(a,b) (((a)+(b)-1)/(b))
#define FSQRT(x) __builtin_amdgcn_sqrtf(x)

typedef __attribute__((ext_vector_type(8))) short short8;
typedef __attribute__((ext_vector_type(4))) float f32x4;

// async global->LDS, 16B per lane; gptr per-lane, lptr wave-uniform
#define GL16(g, l) __builtin_amdgcn_global_load_lds( \
    (const __attribute__((address_space(1))) void*)(g), \
    (__attribute__((address_space(3))) void*)(l), 16, 0, 0)

// in-block redundant scale derivation from per-block GEMM partials
#define SCALE_FROM_PART(OUTVAR) \
    __shared__ double ss_[256], qq_[256]; \
    __shared__ float ssc_; \
    { int t_ = threadIdx.x; double s_ = 0.0, q_ = 0.0; \
      for (int i_ = t_; i_ < nb; i_ += 256) { s_ += part[2*i_]; q_ += part[2*i_+1]; } \
      ss_[t_] = s_; qq_[t_] = q_; __syncthreads(); \
      for (int st_ = 128; st_ > 0; st_ >>= 1) { \
          if (t_ < st_) { ss_[t_] += ss_[t_+st_]; qq_[t_] += qq_[t_+st_]; } \
          __syncthreads(); } \
      if (t_ == 0) { double m_ = ss_[0] / Nstat; \
          double var_ = (qq_[0] - Nstat*m_*m_) / (Nstat - 1.0); \
          ssc_ = (float)(0.5 / var_); } \
      __syncthreads(); } \
    float OUTVAR = ssc_;

// build one channel's B fragment + weight norm from w1 directly (bit-identical to split path)
#define BUILD_B(C, BH, BL, WN) { \
    float s_ = 0.f; short8 hv_, lv_; \
    _Pragma("unroll") \
    for (int j_ = 0; j_ < 8; ++j_) { \
        int k_ = kh*8 + j_; \
        float v_ = (valid && k_ < 25) ? w1g[o*75 + (C)*25 + k_] : 0.f; \
        __hip_bfloat16 hb_ = __float2bfloat16(v_); \
        float hf_ = __bfloat162float(hb_); \
        __hip_bfloat16 lb_ = __float2bfloat16(v_ - hf_); \
        hv_[j_] = *(short*)&hb_; lv_[j_] = *(short*)&lb_; \
        float r_ = hf_ + __bfloat162float(lb_); \
        s_ += r_*r_; } \
    s_ += __shfl_xor(s_, 16, 64); \
    s_ += __shfl_xor(s_, 32, 64); \
    BH = hv_; BL = lv_; WN = s_; }

// shared row split+pad+norm body
__device__ __forceinline__ void splitnorm_row(
    const float* __restrict__ src, ushort* __restrict__ H, ushort* __restrict__ L,
    float* __restrict__ norm, int R, int K, int Kp, int row, int lane) {
    float s = 0.f;
    if (row < R) {
        for (int k = lane; k < Kp; k += 64) {
            float v = (k < K) ? src[(size_t)row*K + k] : 0.f;
            __hip_bfloat16 hb = __float2bfloat16(v);
            float hf = __bfloat162float(hb);
            __hip_bfloat16 lb = __float2bfloat16(v - hf);
            H[(size_t)row*Kp + k] = *(ushort*)&hb;
            L[(size_t)row*Kp + k] = *(ushort*)&lb;
            float r = hf + __bfloat162float(lb);
            s += r*r;
        }
    } else {
        for (int k = lane; k < Kp; k += 64) {
            H[(size_t)row*Kp + k] = 0;
            L[(size_t)row*Kp + k] = 0;
        }
    }
    for (int off = 32; off > 0; off >>= 1) s += __shfl_down(s, off, 64);
    if (lane == 0) norm[row] = s;
}

// standalone splitnorm (fallback path)
__global__ __launch_bounds__(256) void splitnorm_kernel(
    const float* __restrict__ src, ushort* __restrict__ H, ushort* __restrict__ L,
    float* __restrict__ norm, int R, int K, int Kp) {
    int wave = threadIdx.x >> 6, lane = threadIdx.x & 63;
    int row = blockIdx.x*4 + wave;
    splitnorm_row(src, H, L, norm, R, K, Kp, row, lane);
}

// ---------------- layer 1 MFMA (+fused stats; W1 built in-register; prep tail) ----------------
// blocks [0,1024): main rbf1 work; blocks >=1024: W2/W3/W4 splitnorm (8 rows/block)
__global__ __launch_bounds__(512, 2) void rbf1_mfma(
    const float* __restrict__ x, const float* __restrict__ w1g,
    float* __restrict__ dist1, float* __restrict__ pixstat,
    const float* __restrict__ w2, ushort* __restrict__ W2h, ushort* __restrict__ W2l, float* __restrict__ wn2,
    const float* __restrict__ w3, ushort* __restrict__ W3h, ushort* __restrict__ W3l, float* __restrict__ wn3,
    const float* __restrict__ w4, ushort* __restrict__ W4h, ushort* __restrict__ W4l, float* __restrict__ wn4) {
    __shared__ ushort Ah[3*144*32];
    __shared__ ushort Al[3*144*32];
    __shared__ float pnl[432];
    __shared__ float rstat[7*144*2];
    int tid = threadIdx.x;

    if (blockIdx.x >= 1024) {        // weight-prep tail (block-uniform, no barriers)
        int wv = tid >> 6, ln = tid & 63;
        int prow = (blockIdx.x - 1024)*8 + wv;
        if (prow < 256)      splitnorm_row(w2, W2h, W2l, wn2, 225, 100, 128, prow, ln);
        else if (prow < 896) splitnorm_row(w3, W3h, W3l, wn3, 625, 225, 256, prow-256, ln);
        else                 splitnorm_row(w4, W4h, W4l, wn4, 1225, 625, 640, prow-896, ln);
        return;
    }
    int b4 = blockIdx.x;

    if (tid < 432) {
        int row = tid / 3, c = tid - row*3;
        int img = row / 36, p = row - img*36;
        int ph = p / 6, pw = p - ph*6;
        const float* xp = x + (size_t)b4*9408 + img*2352 + c*784 + (ph*28 + pw)*4;
        float arr[25];
#pragma unroll
        for (int ki = 0; ki < 5; ++ki) {
            float4 v4 = *(const float4*)(xp + ki*28);
            arr[ki*5+0] = v4.x; arr[ki*5+1] = v4.y;
            arr[ki*5+2] = v4.z; arr[ki*5+3] = v4.w;
            arr[ki*5+4] = xp[ki*28 + 4];
        }
        float pnc = 0.f;
        int tilebase = c*9216 + row*64;
        int r3 = (row >> 1) & 3;
#pragma unroll
        for (int kb = 0; kb < 4; ++kb) {
            uint4 hq, lq;
            uint* hqa = (uint*)&hq;
            uint* lqa = (uint*)&lq;
#pragma unroll
            for (int j = 0; j < 4; ++j) {
                int k0 = kb*8 + 2*j;
                float v0 = (k0 < 25) ? arr[k0] : 0.f;
                float v1 = (k0+1 < 25) ? arr[k0+1] : 0.f;
                __hip_bfloat16 h0 = __float2bfloat16(v0);
                float hf0 = __bfloat162float(h0);
                __hip_bfloat16 l0 = __float2bfloat16(v0 - hf0);
                float r0 = hf0 + __bfloat162float(l0);
                __hip_bfloat16 h1 = __float2bfloat16(v1);
                float hf1 = __bfloat162float(h1);
                __hip_bfloat16 l1 = __float2bfloat16(v1 - hf1);
                float r1 = hf1 + __bfloat162float(l1);
                pnc += r0*r0 + r1*r1;
                hqa[j] = (uint)(*(ushort*)&h0) | ((uint)(*(ushort*)&h1) << 16);
                lqa[j] = (uint)(*(ushort*)&l0) | ((uint)(*(ushort*)&l1) << 16);
            }
            int kbs = kb ^ r3;
            *(uint4*)((char*)Ah + tilebase + kbs*16) = hq;
            *(uint4*)((char*)Al + tilebase + kbs*16) = lq;
        }
        pnl[tid] = pnc;
    }
    __syncthreads();

    int lane = tid & 63, wave = tid >> 6;
    if (wave < 7) {
        int nf = wave;
        int rl = lane & 15, kh = lane >> 4;
        int o = nf*16 + rl;
        bool valid = (o < 100);
        short8 bh0, bh1, bh2, bl0, bl1, bl2;
        float w0, w1v, w2v;
        BUILD_B(0, bh0, bl0, w0);
        BUILD_B(1, bh1, bl1, w1v);
        BUILD_B(2, bh2, bl2, w2v);
        int swz = (rl >> 1) & 3;
        int kx = (kh ^ swz) * 16;
        float* mystat = rstat + wave*288;
#pragma unroll
        for (int mf = 0; mf < 9; ++mf) {
            int rbase = (mf*16 + rl)*64;
            short8 ah0 = *(const short8*)((const char*)Ah + rbase + kx);
            short8 al0 = *(const short8*)((const char*)Al + rbase + kx);
            short8 ah1 = *(const short8*)((const char*)Ah + 9216 + rbase + kx);
            short8 al1 = *(const short8*)((const char*)Al + 9216 + rbase + kx);
            short8 ah2 = *(const short8*)((const char*)Ah + 18432 + rbase + kx);
            short8 al2 = *(const short8*)((const char*)Al + 18432 + rbase + kx);
            f32x4 a0 = {0.f,0.f,0.f,0.f}, a1 = {0.f,0.f,0.f,0.f}, a2 = {0.f,0.f,0.f,0.f};
            a0 = __builtin_amdgcn_mfma_f32_16x16x32_bf16(ah0, bh0, a0, 0, 0, 0);
            a1 = __builtin_amdgcn_mfma_f32_16x16x32_bf16(ah1, bh1, a1, 0, 0, 0);
            a2 = __builtin_amdgcn_mfma_f32_16x16x32_bf16(ah2, bh2, a2, 0, 0, 0);
            a0 = __builtin_amdgcn_mfma_f32_16x16x32_bf16(ah0, bl0, a0, 0, 0, 0);
            a1 = __builtin_amdgcn_mfma_f32_16x16x32_bf16(ah1, bl1, a1, 0, 0, 0);
            a2 = __builtin_amdgcn_mfma_f32_16x16x32_bf16(ah2, bl2, a2, 0, 0, 0);
            a0 = __builtin_amdgcn_mfma_f32_16x16x32_bf16(al0, bh0, a0, 0, 0, 0);
            a1 = __builtin_amdgcn_mfma_f32_16x16x32_bf16(al1, bh1, a1, 0, 0, 0);
            a2 = __builtin_amdgcn_mfma_f32_16x16x32_bf16(al2, bh2, a2, 0, 0, 0);
            float dsum[4], dsq[4];
            size_t base = (size_t)(b4*144 + mf*16 + kh*4)*100 + o;
#pragma unroll
            for (int r = 0; r < 4; ++r) {
                int row = mf*16 + kh*4 + r;
                float d = FSQRT(fmaxf(pnl[row*3+0] + w0  - 2.f*a0[r], 1e-12f))
                        + FSQRT(fmaxf(pnl[row*3+1] + w1v - 2.f*a1[r], 1e-12f))
                        + FSQRT(fmaxf(pnl[row*3+2] + w2v - 2.f*a2[r], 1e-12f));
                float dv = valid ? d : 0.f;
                if (valid) dist1[base + (size_t)r*100] = d;
                dsum[r] = dv; dsq[r] = dv*dv;
            }
#pragma unroll
            for (int m = 1; m <= 8; m <<= 1) {
#pragma unroll
                for (int r = 0; r < 4; ++r) {
                    dsum[r] += __shfl_xor(dsum[r], m, 64);
                    dsq[r]  += __shfl_xor(dsq[r],  m, 64);
                }
            }
            if (rl == 0) {
#pragma unroll
                for (int r = 0; r < 4; ++r) {
                    int row = mf*16 + kh*4 + r;
                    mystat[row*2]     = dsum[r];
                    mystat[row*2 + 1] = dsq[r];
                }
            }
        }
    }
    __syncthreads();
    if (tid < 72) {
        int p = tid >> 1, w = tid & 1;
        float s = 0.f;
#pragma unroll
        for (int wv = 0; wv < 7; ++wv)
#pragma unroll
            for (int g = 0; g < 4; ++g)
                s += rstat[wv*288 + (p + 36*g)*2 + w];
        pixstat[(size_t)b4*72 + 2*p + w] = s;
    }
}

// reduce per-block pixel partials -> scale[p]
__global__ __launch_bounds__(256) void finalize36_kernel(
    const float* __restrict__ pixstat, float* __restrict__ scale) {
    __shared__ double ss[256], qq[256];
    int p = blockIdx.x, tid = threadIdx.x;
    double s = 0.0, q = 0.0;
    for (int b = tid; b < 1024; b += 256) {
        s += (double)pixstat[(size_t)b*72 + 2*p];
        q += (double)pixstat[(size_t)b*72 + 2*p + 1];
    }
    ss[tid] = s; qq[tid] = q; __syncthreads();
    for (int st = 128; st > 0; st >>= 1) {
        if (tid < st) { ss[tid] += ss[tid+st]; qq[tid] += qq[tid+st]; }
        __syncthreads();
    }
    if (tid == 0) {
        const double N = 409600.0;
        double m = ss[0] / N;
        double var = (qq[0] - N*m*m) / (N - 1.0);
        scale[p] = (float)(0.5 / var);
    }
}

// exp+crelu(0.4)+SFM1 fallback: dist1 -> y2 fp32
__global__ __launch_bounds__(256) void sfm1_kernel(
    const float* __restrict__ dist1, const float* __restrict__ scale,
    float* __restrict__ y2) {
    int gid = blockIdx.x*256 + threadIdx.x;
    if (gid >= 36864*100) return;
    int c = gid % 100, n = gid / 100;
    int b = n / 9, ij = n % 9, i = ij / 3, j = ij % 3;
    const float alpha[2][2] = {{0.729f, 0.81f},{0.9f, 1.0f}};
    float acc = 0.f;
#pragma unroll
    for (int fh = 0; fh < 2; ++fh)
#pragma unroll
        for (int fw = 0; fw < 2; ++fw) {
            int p = (2*i+fh)*6 + (2*j+fw);
            float d = dist1[(size_t)b*3600 + p*100 + c];
            float v = __expf(-d*d*scale[p]);
            v = (v >= 0.4f) ? v : 0.f;
            acc += alpha[fh][fw]*v;
        }
    y2[gid] = 0.25f * acc;
}

// fused exp+crelu+SFM1+split+norm (roomy path)
__global__ __launch_bounds__(256) void sfm1s_kernel(
    const float* __restrict__ dist1, const float* __restrict__ scale,
    ushort* __restrict__ H, ushort* __restrict__ L, float* __restrict__ norm) {
    int wave = threadIdx.x >> 6, lane = threadIdx.x & 63;
    int n = blockIdx.x*4 + wave;
    int b = n / 9, ij = n % 9, i = ij / 3, j = ij % 3;
    const float alpha[2][2] = {{0.729f, 0.81f},{0.9f, 1.0f}};
    float s = 0.f;
#pragma unroll
    for (int q = 0; q < 2; ++q) {
        int k = lane + q*64;
        float y = 0.f;
        if (k < 100) {
            float acc = 0.f;
#pragma unroll
            for (int fh = 0; fh < 2; ++fh)
#pragma unroll
                for (int fw = 0; fw < 2; ++fw) {
                    int p = (2*i+fh)*6 + (2*j+fw);
                    float d = dist1[(size_t)b*3600 + p*100 + k];
                    float v = __expf(-d*d*scale[p]);
                    v = (v >= 0.4f) ? v : 0.f;
                    acc += alpha[fh][fw]*v;
                }
            y = 0.25f * acc;
        }
        __hip_bfloat16 hb = __float2bfloat16(y);
        float hf = __bfloat162float(hb);
        __hip_bfloat16 lb = __float2bfloat16(y - hf);
        H[(size_t)n*128 + k] = *(ushort*)&hb;
        L[(size_t)n*128 + k] = *(ushort*)&lb;
        float r = hf + __bfloat162float(lb);
        s += r*r;
    }
    for (int off = 32; off > 0; off >>= 1) s += __shfl_down(s, off, 64);
    if (lane == 0) norm[n] = s;
}

// fused exp+crelu+SFM2+split+norm; scale re-derived in-block
__global__ __launch_bounds__(256) void sfm2s_kernel(
    const float* __restrict__ dist2, const double* __restrict__ part, int nb, double Nstat,
    ushort* __restrict__ H, ushort* __restrict__ L, float* __restrict__ norm) {
    SCALE_FROM_PART(s2);
    int wave = threadIdx.x >> 6, lane = threadIdx.x & 63;
    int n2 = blockIdx.x*4 + wave;
    int b = n2 / 3, i = n2 % 3;
    const float alphaJ[3] = {0.81f, 0.9f, 1.0f};
    float s = 0.f;
#pragma unroll
    for (int q = 0; q < 4; ++q) {
        int k = lane + q*64;
        float y = 0.f;
        if (k < 225) {
            float acc = 0.f;
#pragma unroll
            for (int j = 0; j < 3; ++j) {
                float d = dist2[((size_t)(b*9 + i*3 + j))*225 + k];
                float v = __expf(-d*d*s2);
                v = (v >= 0.1f) ? v : 0.f;
                acc += alphaJ[j]*v;
            }
            y = acc * (1.f/3.f);
        }
        __hip_bfloat16 hb = __float2bfloat16(y);
        float hf = __bfloat162float(hb);
        __hip_bfloat16 lb = __float2bfloat16(y - hf);
        H[(size_t)n2*256 + k] = *(ushort*)&hb;
        L[(size_t)n2*256 + k] = *(ushort*)&lb;
        float r = hf + __bfloat162float(lb);
        s += r*r;
    }
    for (int off = 32; off > 0; off >>= 1) s += __shfl_down(s, off, 64);
    if (lane == 0) norm[n2] = s;
}

// fused exp+crelu+SFM3+split+norm; scale re-derived in-block
__global__ __launch_bounds__(256) void sfm3s_kernel(
    const float* __restrict__ dist3, const double* __restrict__ part, int nb, double Nstat,
    ushort* __restrict__ H, ushort* __restrict__ L, float* __restrict__ norm) {
    SCALE_FROM_PART(s3);
    int wave = threadIdx.x >> 6, lane = threadIdx.x & 63;
    int b = blockIdx.x*4 + wave;
    const float alphaI[3] = {0.81f, 0.9f, 1.0f};
    float s = 0.f;
#pragma unroll
    for (int q = 0; q < 10; ++q) {
        int k = lane + q*64;
        float y = 0.f;
        if (k < 625) {
            float acc = 0.f;
#pragma unroll
            for (int i = 0; i < 3; ++i) {
                float d = dist3[((size_t)(b*3 + i))*625 + k];
                float v = __expf(-d*d*s3);
                v = (v >= 0.01f) ? v : 0.f;
                acc += alphaI[i]*v;
            }
            y = acc * (1.f/3.f);
        }
        __hip_bfloat16 hb = __float2bfloat16(y);
        float hf = __bfloat162float(hb);
        __hip_bfloat16 lb = __float2bfloat16(y - hf);
        H[(size_t)b*640 + k] = *(ushort*)&hb;
        L[(size_t)b*640 + k] = *(ushort*)&lb;
        float r = hf + __bfloat162float(lb);
        s += r*r;
    }
    for (int off = 32; off > 0; off >>= 1) s += __shfl_down(s, off, 64);
    if (lane == 0) norm[b] = s;
}

// ---------------- unified dist GEMM: 64x128 tile, 8 waves, 24KB LDS, gl_lds ----------------
__global__ __launch_bounds__(512, 4) void distg_mfma(
    const ushort* __restrict__ Yh, const ushort* __restrict__ Yl,
    const ushort* __restrict__ Wh, const ushort* __restrict__ Wl,
    const float* __restrict__ pn, const float* __restrict__ wn,
    float* __restrict__ D, int N, int O, int Kp,
    double* __restrict__ part) {
    __shared__ ushort Ahs[2048], Als[2048], Bhs[4096], Bls[4096];
    __shared__ double wred[8][2];
    int tid = threadIdx.x, lane = tid & 63, wave = tid >> 6;
    int bn = blockIdx.x * 64, bo = blockIdx.y * 128;
    int wm = wave >> 2, wq = wave & 3;

    int rL = lane >> 2, cL = lane & 3;
    int cs = cL ^ ((rL >> 1) & 3);
    size_t boff = (size_t)(bo + wave*16 + rL) * Kp + cs*8;
    ushort* lBh = Bhs + wave*512;
    ushort* lBl = Bls + wave*512;
    int aw = wave & 3;
    size_t aoff = (size_t)(bn + aw*16 + rL) * Kp + cs*8;
    ushort* lA = ((wave < 4) ? Ahs : Als) + aw*512;
    const ushort* Asrc = (wave < 4) ? Yh : Yl;

    int rl = lane & 15, kh = lane >> 4;
    int kbs_r = kh ^ ((rl >> 1) & 3);
    int raoff[2], rboff[2];
#pragma unroll
    for (int mf = 0; mf < 2; ++mf) raoff[mf] = (wm*32 + mf*16 + rl)*64 + kbs_r*16;
#pragma unroll
    for (int nf = 0; nf < 2; ++nf) rboff[nf] = (wq*32 + nf*16 + rl)*64 + kbs_r*16;

    f32x4 acc[2][2];
#pragma unroll
    for (int mf = 0; mf < 2; ++mf)
#pragma unroll
        for (int nf = 0; nf < 2; ++nf) acc[mf][nf] = (f32x4){0.f,0.f,0.f,0.f};

    int NT = Kp >> 5;
    for (int t = 0; t < NT; ++t) {
        int k0 = t*32;
        GL16(Asrc + aoff + k0, lA);
        GL16(Wh + boff + k0, lBh);
        GL16(Wl + boff + k0, lBl);
        __syncthreads();
        short8 a_h[2], a_l[2];
#pragma unroll
        for (int mf = 0; mf < 2; ++mf) {
            a_h[mf] = *(const short8*)((const char*)Ahs + raoff[mf]);
            a_l[mf] = *(const short8*)((const char*)Als + raoff[mf]);
        }
#pragma unroll
        for (int nf = 0; nf < 2; ++nf) {
            short8 b_h = *(const short8*)((const char*)Bhs + rboff[nf]);
            short8 b_l = *(const short8*)((const char*)Bls + rboff[nf]);
#pragma unroll
            for (int mf = 0; mf < 2; ++mf) {
                acc[mf][nf] = __builtin_amdgcn_mfma_f32_16x16x32_bf16(a_h[mf], b_h, acc[mf][nf], 0, 0, 0);
                acc[mf][nf] = __builtin_amdgcn_mfma_f32_16x16x32_bf16(a_h[mf], b_l, acc[mf][nf], 0, 0, 0);
                acc[mf][nf] = __builtin_amdgcn_mfma_f32_16x16x32_bf16(a_l[mf], b_h, acc[mf][nf], 0, 0, 0);
            }
        }
        __syncthreads();
    }

    double lsum = 0.0, lsq = 0.0;
#pragma unroll
    for (int mf = 0; mf < 2; ++mf) {
#pragma unroll
        for (int r = 0; r < 4; ++r) {
            int n = bn + wm*32 + mf*16 + kh*4 + r;
            float pv = pn[n];
#pragma unroll
            for (int nf = 0; nf < 2; ++nf) {
                int o = bo + wq*32 + nf*16 + rl;
                if (o < O) {
                    float d2 = pv + wn[o] - 2.f*acc[mf][nf][r];
                    float dd = FSQRT(fmaxf(d2, 1e-12f));
                    D[(size_t)n*O + o] = dd;
                    lsum += dd; lsq += (double)dd*dd;
                }
            }
        }
    }
    for (int off = 32; off > 0; off >>= 1) {
        lsum += __shfl_down(lsum, off, 64);
        lsq  += __shfl_down(lsq,  off, 64);
    }
    if (lane == 0) { wred[wave][0] = lsum; wred[wave][1] = lsq; }
    __syncthreads();
    if (tid == 0) {
        double s = 0.0, q = 0.0;
#pragma unroll
        for (int w = 0; w < 8; ++w) { s += wred[w][0]; q += wred[w][1]; }
        int bid = blockIdx.y * gridDim.x + blockIdx.x;
        part[2*bid]   = s;
        part[2*bid+1] = q;
    }
}

// exp+crelu(0.01)+FC; scale re-derived in-block
__global__ __launch_bounds__(256) void fc_kernel(
    const float* __restrict__ dist4, const double* __restrict__ part, int nb, double Nstat,
    const float* __restrict__ fcw, const float* __restrict__ fcb,
    float* __restrict__ out) {
    SCALE_FROM_PART(s4);
    int b = blockIdx.x;
    int tid = threadIdx.x;
    float acc[10] = {};
    for (int o = tid; o < 1225; o += 256) {
        float d = dist4[(size_t)b*1225 + o];
        float v = __expf(-d*d*s4);
        v = (v >= 0.01f) ? v : 0.f;
#pragma unroll
        for (int k = 0; k < 10; ++k) acc[k] += v * fcw[k*1225 + o];
    }
    __shared__ float red[10*256];
#pragma unroll
    for (int k = 0; k < 10; ++k) red[k*256 + tid] = acc[k];
    __syncthreads();
    for (int st = 128; st > 0; st >>= 1) {
        if (tid < st) {
#pragma unroll
            for (int k = 0; k < 10; ++k) red[k*256 + tid] += red[k*256 + tid + st];
        }
        __syncthreads();
    }
    if (tid < 10) out[b*10 + tid] = red[tid*256] + fcb[tid];
}

extern "C" void kernel_launch(void* const* d_in, const int* in_sizes, int n_in,
                              void* d_out, int out_size, void* d_ws, size_t ws_size,
                              hipStream_t stream) {
    const float* x     = (const float*)d_in[0];
    const float* rgb_w = (const float*)d_in[1];
    const float* w2    = (const float*)d_in[2];
    const float* w3    = (const float*)d_in[3];
    const float* w4    = (const float*)d_in[4];
    const float* fc_w  = (const float*)d_in[5];
    const float* fc_b  = (const float*)d_in[6];
    float* out = (float*)d_out;

    float* wsf   = (float*)d_ws;
    float* dist  = wsf;                    // 14,745,600 floats
    float* ybuf  = wsf + 14745600;         // 3,686,400 floats
    float* pnb   = ybuf + 3686400;         // 36,864 floats
    float* wnb2  = pnb + 36864;            // 256
    float* wnb3  = wnb2 + 256;             // 640
    float* wnb4  = wnb3 + 640;             // 1,280
    float* scale = wnb4 + 1280;            // 64
    double* pblk = (double*)(scale + 64);  // 2304 doubles
    float* wsend = (float*)(pblk + 2304);

    float* pixstat = ybuf;

    size_t base_floats = (size_t)(wsend - wsf);
    size_t y2_floats   = 2u * 36864u * 128u / 2u;       // 4,718,592
    size_t w2_floats   = 2u * 256u * 128u / 2u;         // 32,768
    bool roomy = ws_size >= (base_floats + y2_floats + w2_floats + 1024) * sizeof(float);

    // Y2 planes
    ushort* Y2h = roomy ? (ushort*)wsend : (ushort*)(dist + 8388608);
    ushort* Y2l = Y2h + 36864*128;
    // W2 planes
    ushort* W2h = roomy ? (Y2l + 36864*128) : ((ushort*)(dist + 8388608) + 2*36864*128);
    ushort* W2l = W2h + 256*128;
    // Y3/Y4 planes in ybuf head
    ushort* Y3h = (ushort*)ybuf;
    ushort* Y3l = Y3h + 12288*256;
    ushort* Y4h = (ushort*)ybuf;
    ushort* Y4l = Y4h + 4096*640;
    // W4 planes: floats [2,621,440, 3,440,640)
    ushort* W4h = Y4l + 4096*640;
    ushort* W4l = W4h + 1280*640;
    // W3 planes: roomy -> ybuf tail; fallback -> after Y3
    ushort* W3h = roomy ? (ushort*)(ybuf + 3522560) : (Y3l + 12288*256);
    ushort* W3l = W3h + 640*256;

    // ---- layer 1 (+inline W1 prep; W2/3/4 prep in grid tail when roomy) ----
    rbf1_mfma<<<roomy ? 1296 : 1024, 512, 0, stream>>>(
        x, rgb_w, dist, pixstat,
        w2, W2h, W2l, wnb2,
        w3, W3h, W3l, wnb3,
        w4, W4h, W4l, wnb4);
    finalize36_kernel<<<36, 256, 0, stream>>>(pixstat, scale);

    // ---- layer 1 -> 2 transition ----
    if (roomy) {
        sfm1s_kernel<<<36864/4, 256, 0, stream>>>(dist, scale, Y2h, Y2l, pnb);
    } else {
        sfm1_kernel<<<DIV_UP(36864*100,256), 256, 0, stream>>>(dist, scale, ybuf);
        splitnorm_kernel<<<36864/4, 256, 0, stream>>>(ybuf, Y2h, Y2l, pnb, 36864, 100, 128);
        splitnorm_kernel<<<256/4, 256, 0, stream>>>(w2, W2h, W2l, wnb2, 225, 100, 128);
    }

    // ---- layer 2: 64x128 tiles -> grid (576,2)=1152 blocks ----
    distg_mfma<<<dim3(576,2), 512, 0, stream>>>(Y2h, Y2l, W2h, W2l, pnb, wnb2, dist, 36864, 225, 128, pblk);
    sfm2s_kernel<<<12288/4, 256, 0, stream>>>(dist, pblk, 1152, 8294400.0, Y3h, Y3l, pnb);

    // ---- layer 3: grid (192,5)=960 blocks ----
    if (!roomy) splitnorm_kernel<<<640/4, 256, 0, stream>>>(w3, W3h, W3l, wnb3, 625, 225, 256);
    distg_mfma<<<dim3(192,5), 512, 0, stream>>>(Y3h, Y3l, W3h, W3l, pnb, wnb3, dist, 12288, 625, 256, pblk);
    sfm3s_kernel<<<4096/4, 256, 0, stream>>>(dist, pblk, 960, 7680000.0, Y4h, Y4l, pnb);

    // ---- layer 4: grid (64,10)=640 blocks ----
    if (!roomy) splitnorm_kernel<<<1280/4, 256, 0, stream>>>(w4, W4h, W4l, wnb4, 1225, 625, 640);
    distg_mfma<<<dim3(64,10), 512, 0, stream>>>(Y4h, Y4l, W4h, W4l, pnb, wnb4, dist, 4096, 1225, 640, pblk);

    // ---- FC (scale re-derived in-block) ----
    fc_kernel<<<4096, 256, 0, stream>>>(dist, pblk, 640, 5017600.0, fc_w, fc_b, out);
}

// Round 24
// 187.382 us; speedup vs baseline: 1.3077x; 1.0002x over previous
//
#include <hip/hip_runtime.h>
#include <hip/hip_bf16.h>
#include <math.h>

#define DIV_UP(a,b) (((a)+(b)-1)/(b))
#define FSQRT(x) __builtin_amdgcn_sqrtf(x)

typedef __attribute__((ext_vector_type(8))) short short8;
typedef __attribute__((ext_vector_type(4))) float f32x4;

// async global->LDS, 16B per lane; gptr per-lane, lptr wave-uniform
#define GL16(g, l) __builtin_amdgcn_global_load_lds( \
    (const __attribute__((address_space(1))) void*)(g), \
    (__attribute__((address_space(3))) void*)(l), 16, 0, 0)

// in-block redundant scale derivation from per-block GEMM partials
#define SCALE_FROM_PART(OUTVAR) \
    __shared__ double ss_[256], qq_[256]; \
    __shared__ float ssc_; \
    { int t_ = threadIdx.x; double s_ = 0.0, q_ = 0.0; \
      for (int i_ = t_; i_ < nb; i_ += 256) { s_ += part[2*i_]; q_ += part[2*i_+1]; } \
      ss_[t_] = s_; qq_[t_] = q_; __syncthreads(); \
      for (int st_ = 128; st_ > 0; st_ >>= 1) { \
          if (t_ < st_) { ss_[t_] += ss_[t_+st_]; qq_[t_] += qq_[t_+st_]; } \
          __syncthreads(); } \
      if (t_ == 0) { double m_ = ss_[0] / Nstat; \
          double var_ = (qq_[0] - Nstat*m_*m_) / (Nstat - 1.0); \
          ssc_ = (float)(0.5 / var_); } \
      __syncthreads(); } \
    float OUTVAR = ssc_;

// build one channel's B fragment + weight norm from w1 directly (bit-identical to split path)
#define BUILD_B(C, BH, BL, WN) { \
    float s_ = 0.f; short8 hv_, lv_; \
    _Pragma("unroll") \
    for (int j_ = 0; j_ < 8; ++j_) { \
        int k_ = kh*8 + j_; \
        float v_ = (valid && k_ < 25) ? w1g[o*75 + (C)*25 + k_] : 0.f; \
        __hip_bfloat16 hb_ = __float2bfloat16(v_); \
        float hf_ = __bfloat162float(hb_); \
        __hip_bfloat16 lb_ = __float2bfloat16(v_ - hf_); \
        hv_[j_] = *(short*)&hb_; lv_[j_] = *(short*)&lb_; \
        float r_ = hf_ + __bfloat162float(lb_); \
        s_ += r_*r_; } \
    s_ += __shfl_xor(s_, 16, 64); \
    s_ += __shfl_xor(s_, 32, 64); \
    BH = hv_; BL = lv_; WN = s_; }

// shared row split+pad+norm body
__device__ __forceinline__ void splitnorm_row(
    const float* __restrict__ src, ushort* __restrict__ H, ushort* __restrict__ L,
    float* __restrict__ norm, int R, int K, int Kp, int row, int lane) {
    float s = 0.f;
    if (row < R) {
        for (int k = lane; k < Kp; k += 64) {
            float v = (k < K) ? src[(size_t)row*K + k] : 0.f;
            __hip_bfloat16 hb = __float2bfloat16(v);
            float hf = __bfloat162float(hb);
            __hip_bfloat16 lb = __float2bfloat16(v - hf);
            H[(size_t)row*Kp + k] = *(ushort*)&hb;
            L[(size_t)row*Kp + k] = *(ushort*)&lb;
            float r = hf + __bfloat162float(lb);
            s += r*r;
        }
    } else {
        for (int k = lane; k < Kp; k += 64) {
            H[(size_t)row*Kp + k] = 0;
            L[(size_t)row*Kp + k] = 0;
        }
    }
    for (int off = 32; off > 0; off >>= 1) s += __shfl_down(s, off, 64);
    if (lane == 0) norm[row] = s;
}

// standalone splitnorm (fallback path)
__global__ __launch_bounds__(256) void splitnorm_kernel(
    const float* __restrict__ src, ushort* __restrict__ H, ushort* __restrict__ L,
    float* __restrict__ norm, int R, int K, int Kp) {
    int wave = threadIdx.x >> 6, lane = threadIdx.x & 63;
    int row = blockIdx.x*4 + wave;
    splitnorm_row(src, H, L, norm, R, K, Kp, row, lane);
}

// ---------------- layer 1 MFMA (+fused stats; W1 built in-register; prep tail) ----------------
__global__ __launch_bounds__(512, 2) void rbf1_mfma(
    const float* __restrict__ x, const float* __restrict__ w1g,
    float* __restrict__ dist1, float* __restrict__ pixstat,
    const float* __restrict__ w2, ushort* __restrict__ W2h, ushort* __restrict__ W2l, float* __restrict__ wn2,
    const float* __restrict__ w3, ushort* __restrict__ W3h, ushort* __restrict__ W3l, float* __restrict__ wn3,
    const float* __restrict__ w4, ushort* __restrict__ W4h, ushort* __restrict__ W4l, float* __restrict__ wn4) {
    __shared__ ushort Ah[3*144*32];
    __shared__ ushort Al[3*144*32];
    __shared__ float pnl[432];
    __shared__ float rstat[7*144*2];
    int tid = threadIdx.x;

    if (blockIdx.x >= 1024) {        // weight-prep tail (block-uniform, no barriers)
        int wv = tid >> 6, ln = tid & 63;
        int prow = (blockIdx.x - 1024)*8 + wv;
        if (prow < 256)      splitnorm_row(w2, W2h, W2l, wn2, 225, 100, 128, prow, ln);
        else if (prow < 896) splitnorm_row(w3, W3h, W3l, wn3, 625, 225, 256, prow-256, ln);
        else                 splitnorm_row(w4, W4h, W4l, wn4, 1225, 625, 640, prow-896, ln);
        return;
    }
    int b4 = blockIdx.x;

    if (tid < 432) {
        int row = tid / 3, c = tid - row*3;
        int img = row / 36, p = row - img*36;
        int ph = p / 6, pw = p - ph*6;
        const float* xp = x + (size_t)b4*9408 + img*2352 + c*784 + (ph*28 + pw)*4;
        float arr[25];
#pragma unroll
        for (int ki = 0; ki < 5; ++ki) {
            float4 v4 = *(const float4*)(xp + ki*28);
            arr[ki*5+0] = v4.x; arr[ki*5+1] = v4.y;
            arr[ki*5+2] = v4.z; arr[ki*5+3] = v4.w;
            arr[ki*5+4] = xp[ki*28 + 4];
        }
        float pnc = 0.f;
        int tilebase = c*9216 + row*64;
        int r3 = (row >> 1) & 3;
#pragma unroll
        for (int kb = 0; kb < 4; ++kb) {
            uint4 hq, lq;
            uint* hqa = (uint*)&hq;
            uint* lqa = (uint*)&lq;
#pragma unroll
            for (int j = 0; j < 4; ++j) {
                int k0 = kb*8 + 2*j;
                float v0 = (k0 < 25) ? arr[k0] : 0.f;
                float v1 = (k0+1 < 25) ? arr[k0+1] : 0.f;
                __hip_bfloat16 h0 = __float2bfloat16(v0);
                float hf0 = __bfloat162float(h0);
                __hip_bfloat16 l0 = __float2bfloat16(v0 - hf0);
                float r0 = hf0 + __bfloat162float(l0);
                __hip_bfloat16 h1 = __float2bfloat16(v1);
                float hf1 = __bfloat162float(h1);
                __hip_bfloat16 l1 = __float2bfloat16(v1 - hf1);
                float r1 = hf1 + __bfloat162float(l1);
                pnc += r0*r0 + r1*r1;
                hqa[j] = (uint)(*(ushort*)&h0) | ((uint)(*(ushort*)&h1) << 16);
                lqa[j] = (uint)(*(ushort*)&l0) | ((uint)(*(ushort*)&l1) << 16);
            }
            int kbs = kb ^ r3;
            *(uint4*)((char*)Ah + tilebase + kbs*16) = hq;
            *(uint4*)((char*)Al + tilebase + kbs*16) = lq;
        }
        pnl[tid] = pnc;
    }
    __syncthreads();

    int lane = tid & 63, wave = tid >> 6;
    if (wave < 7) {
        int nf = wave;
        int rl = lane & 15, kh = lane >> 4;
        int o = nf*16 + rl;
        bool valid = (o < 100);
        short8 bh0, bh1, bh2, bl0, bl1, bl2;
        float w0, w1v, w2v;
        BUILD_B(0, bh0, bl0, w0);
        BUILD_B(1, bh1, bl1, w1v);
        BUILD_B(2, bh2, bl2, w2v);
        int swz = (rl >> 1) & 3;
        int kx = (kh ^ swz) * 16;
        float* mystat = rstat + wave*288;
#pragma unroll
        for (int mf = 0; mf < 9; ++mf) {
            int rbase = (mf*16 + rl)*64;
            short8 ah0 = *(const short8*)((const char*)Ah + rbase + kx);
            short8 al0 = *(const short8*)((const char*)Al + rbase + kx);
            short8 ah1 = *(const short8*)((const char*)Ah + 9216 + rbase + kx);
            short8 al1 = *(const short8*)((const char*)Al + 9216 + rbase + kx);
            short8 ah2 = *(const short8*)((const char*)Ah + 18432 + rbase + kx);
            short8 al2 = *(const short8*)((const char*)Al + 18432 + rbase + kx);
            f32x4 a0 = {0.f,0.f,0.f,0.f}, a1 = {0.f,0.f,0.f,0.f}, a2 = {0.f,0.f,0.f,0.f};
            a0 = __builtin_amdgcn_mfma_f32_16x16x32_bf16(ah0, bh0, a0, 0, 0, 0);
            a1 = __builtin_amdgcn_mfma_f32_16x16x32_bf16(ah1, bh1, a1, 0, 0, 0);
            a2 = __builtin_amdgcn_mfma_f32_16x16x32_bf16(ah2, bh2, a2, 0, 0, 0);
            a0 = __builtin_amdgcn_mfma_f32_16x16x32_bf16(ah0, bl0, a0, 0, 0, 0);
            a1 = __builtin_amdgcn_mfma_f32_16x16x32_bf16(ah1, bl1, a1, 0, 0, 0);
            a2 = __builtin_amdgcn_mfma_f32_16x16x32_bf16(ah2, bl2, a2, 0, 0, 0);
            a0 = __builtin_amdgcn_mfma_f32_16x16x32_bf16(al0, bh0, a0, 0, 0, 0);
            a1 = __builtin_amdgcn_mfma_f32_16x16x32_bf16(al1, bh1, a1, 0, 0, 0);
            a2 = __builtin_amdgcn_mfma_f32_16x16x32_bf16(al2, bh2, a2, 0, 0, 0);
            float dsum[4], dsq[4];
            size_t base = (size_t)(b4*144 + mf*16 + kh*4)*100 + o;
#pragma unroll
            for (int r = 0; r < 4; ++r) {
                int row = mf*16 + kh*4 + r;
                float d = FSQRT(fmaxf(pnl[row*3+0] + w0  - 2.f*a0[r], 1e-12f))
                        + FSQRT(fmaxf(pnl[row*3+1] + w1v - 2.f*a1[r], 1e-12f))
                        + FSQRT(fmaxf(pnl[row*3+2] + w2v - 2.f*a2[r], 1e-12f));
                float dv = valid ? d : 0.f;
                if (valid) dist1[base + (size_t)r*100] = d;
                dsum[r] = dv; dsq[r] = dv*dv;
            }
#pragma unroll
            for (int m = 1; m <= 8; m <<= 1) {
#pragma unroll
                for (int r = 0; r < 4; ++r) {
                    dsum[r] += __shfl_xor(dsum[r], m, 64);
                    dsq[r]  += __shfl_xor(dsq[r],  m, 64);
                }
            }
            if (rl == 0) {
#pragma unroll
                for (int r = 0; r < 4; ++r) {
                    int row = mf*16 + kh*4 + r;
                    mystat[row*2]     = dsum[r];
                    mystat[row*2 + 1] = dsq[r];
                }
            }
        }
    }
    __syncthreads();
    if (tid < 72) {
        int p = tid >> 1, w = tid & 1;
        float s = 0.f;
#pragma unroll
        for (int wv = 0; wv < 7; ++wv)
#pragma unroll
            for (int g = 0; g < 4; ++g)
                s += rstat[wv*288 + (p + 36*g)*2 + w];
        pixstat[(size_t)b4*72 + 2*p + w] = s;
    }
}

// reduce per-block pixel partials -> scale[p]
__global__ __launch_bounds__(256) void finalize36_kernel(
    const float* __restrict__ pixstat, float* __restrict__ scale) {
    __shared__ double ss[256], qq[256];
    int p = blockIdx.x, tid = threadIdx.x;
    double s = 0.0, q = 0.0;
    for (int b = tid; b < 1024; b += 256) {
        s += (double)pixstat[(size_t)b*72 + 2*p];
        q += (double)pixstat[(size_t)b*72 + 2*p + 1];
    }
    ss[tid] = s; qq[tid] = q; __syncthreads();
    for (int st = 128; st > 0; st >>= 1) {
        if (tid < st) { ss[tid] += ss[tid+st]; qq[tid] += qq[tid+st]; }
        __syncthreads();
    }
    if (tid == 0) {
        const double N = 409600.0;
        double m = ss[0] / N;
        double var = (qq[0] - N*m*m) / (N - 1.0);
        scale[p] = (float)(0.5 / var);
    }
}

// exp+crelu(0.4)+SFM1 fallback: dist1 -> y2 fp32
__global__ __launch_bounds__(256) void sfm1_kernel(
    const float* __restrict__ dist1, const float* __restrict__ scale,
    float* __restrict__ y2) {
    int gid = blockIdx.x*256 + threadIdx.x;
    if (gid >= 36864*100) return;
    int c = gid % 100, n = gid / 100;
    int b = n / 9, ij = n % 9, i = ij / 3, j = ij % 3;
    const float alpha[2][2] = {{0.729f, 0.81f},{0.9f, 1.0f}};
    float acc = 0.f;
#pragma unroll
    for (int fh = 0; fh < 2; ++fh)
#pragma unroll
        for (int fw = 0; fw < 2; ++fw) {
            int p = (2*i+fh)*6 + (2*j+fw);
            float d = dist1[(size_t)b*3600 + p*100 + c];
            float v = __expf(-d*d*scale[p]);
            v = (v >= 0.4f) ? v : 0.f;
            acc += alpha[fh][fw]*v;
        }
    y2[gid] = 0.25f * acc;
}

// fused exp+crelu+SFM1+split+norm (roomy path)
__global__ __launch_bounds__(256) void sfm1s_kernel(
    const float* __restrict__ dist1, const float* __restrict__ scale,
    ushort* __restrict__ H, ushort* __restrict__ L, float* __restrict__ norm) {
    int wave = threadIdx.x >> 6, lane = threadIdx.x & 63;
    int n = blockIdx.x*4 + wave;
    int b = n / 9, ij = n % 9, i = ij / 3, j = ij % 3;
    const float alpha[2][2] = {{0.729f, 0.81f},{0.9f, 1.0f}};
    float s = 0.f;
#pragma unroll
    for (int q = 0; q < 2; ++q) {
        int k = lane + q*64;
        float y = 0.f;
        if (k < 100) {
            float acc = 0.f;
#pragma unroll
            for (int fh = 0; fh < 2; ++fh)
#pragma unroll
                for (int fw = 0; fw < 2; ++fw) {
                    int p = (2*i+fh)*6 + (2*j+fw);
                    float d = dist1[(size_t)b*3600 + p*100 + k];
                    float v = __expf(-d*d*scale[p]);
                    v = (v >= 0.4f) ? v : 0.f;
                    acc += alpha[fh][fw]*v;
                }
            y = 0.25f * acc;
        }
        __hip_bfloat16 hb = __float2bfloat16(y);
        float hf = __bfloat162float(hb);
        __hip_bfloat16 lb = __float2bfloat16(y - hf);
        H[(size_t)n*128 + k] = *(ushort*)&hb;
        L[(size_t)n*128 + k] = *(ushort*)&lb;
        float r = hf + __bfloat162float(lb);
        s += r*r;
    }
    for (int off = 32; off > 0; off >>= 1) s += __shfl_down(s, off, 64);
    if (lane == 0) norm[n] = s;
}

// fused exp+crelu+SFM2+split+norm; scale re-derived in-block
__global__ __launch_bounds__(256) void sfm2s_kernel(
    const float* __restrict__ dist2, const double* __restrict__ part, int nb, double Nstat,
    ushort* __restrict__ H, ushort* __restrict__ L, float* __restrict__ norm) {
    SCALE_FROM_PART(s2);
    int wave = threadIdx.x >> 6, lane = threadIdx.x & 63;
    int n2 = blockIdx.x*4 + wave;
    int b = n2 / 3, i = n2 % 3;
    const float alphaJ[3] = {0.81f, 0.9f, 1.0f};
    float s = 0.f;
#pragma unroll
    for (int q = 0; q < 4; ++q) {
        int k = lane + q*64;
        float y = 0.f;
        if (k < 225) {
            float acc = 0.f;
#pragma unroll
            for (int j = 0; j < 3; ++j) {
                float d = dist2[((size_t)(b*9 + i*3 + j))*225 + k];
                float v = __expf(-d*d*s2);
                v = (v >= 0.1f) ? v : 0.f;
                acc += alphaJ[j]*v;
            }
            y = acc * (1.f/3.f);
        }
        __hip_bfloat16 hb = __float2bfloat16(y);
        float hf = __bfloat162float(hb);
        __hip_bfloat16 lb = __float2bfloat16(y - hf);
        H[(size_t)n2*256 + k] = *(ushort*)&hb;
        L[(size_t)n2*256 + k] = *(ushort*)&lb;
        float r = hf + __bfloat162float(lb);
        s += r*r;
    }
    for (int off = 32; off > 0; off >>= 1) s += __shfl_down(s, off, 64);
    if (lane == 0) norm[n2] = s;
}

// fused exp+crelu+SFM3+split+norm; scale re-derived in-block
__global__ __launch_bounds__(256) void sfm3s_kernel(
    const float* __restrict__ dist3, const double* __restrict__ part, int nb, double Nstat,
    ushort* __restrict__ H, ushort* __restrict__ L, float* __restrict__ norm) {
    SCALE_FROM_PART(s3);
    int wave = threadIdx.x >> 6, lane = threadIdx.x & 63;
    int b = blockIdx.x*4 + wave;
    const float alphaI[3] = {0.81f, 0.9f, 1.0f};
    float s = 0.f;
#pragma unroll
    for (int q = 0; q < 10; ++q) {
        int k = lane + q*64;
        float y = 0.f;
        if (k < 625) {
            float acc = 0.f;
#pragma unroll
            for (int i = 0; i < 3; ++i) {
                float d = dist3[((size_t)(b*3 + i))*625 + k];
                float v = __expf(-d*d*s3);
                v = (v >= 0.01f) ? v : 0.f;
                acc += alphaI[i]*v;
            }
            y = acc * (1.f/3.f);
        }
        __hip_bfloat16 hb = __float2bfloat16(y);
        float hf = __bfloat162float(hb);
        __hip_bfloat16 lb = __float2bfloat16(y - hf);
        H[(size_t)b*640 + k] = *(ushort*)&hb;
        L[(size_t)b*640 + k] = *(ushort*)&lb;
        float r = hf + __bfloat162float(lb);
        s += r*r;
    }
    for (int off = 32; off > 0; off >>= 1) s += __shfl_down(s, off, 64);
    if (lane == 0) norm[b] = s;
}

// ---------------- unified dist GEMM: 64x128 tile, 8 waves, 24KB LDS, gl_lds ----------------
// 1-D grid, XCD-grouped bijective swizzle: xcd = id&7 owns bn-slots [xcd*bn8, (xcd+1)*bn8)
// for ALL bo values -> A panel stays resident in that XCD's L2 across bo sweeps.
__global__ __launch_bounds__(512, 4) void distg_mfma(
    const ushort* __restrict__ Yh, const ushort* __restrict__ Yl,
    const ushort* __restrict__ Wh, const ushort* __restrict__ Wl,
    const float* __restrict__ pn, const float* __restrict__ wn,
    float* __restrict__ D, int N, int O, int Kp, int bn8,
    double* __restrict__ part) {
    __shared__ ushort Ahs[2048], Als[2048], Bhs[4096], Bls[4096];
    __shared__ double wred[8][2];
    int tid = threadIdx.x, lane = tid & 63, wave = tid >> 6;
    int id = blockIdx.x;
    int xcd = id & 7, g = id >> 3;
    int bn = (xcd * bn8 + (g % bn8)) * 64;
    int bo = (g / bn8) * 128;
    int wm = wave >> 2, wq = wave & 3;

    int rL = lane >> 2, cL = lane & 3;
    int cs = cL ^ ((rL >> 1) & 3);
    size_t boff = (size_t)(bo + wave*16 + rL) * Kp + cs*8;
    ushort* lBh = Bhs + wave*512;
    ushort* lBl = Bls + wave*512;
    int aw = wave & 3;
    size_t aoff = (size_t)(bn + aw*16 + rL) * Kp + cs*8;
    ushort* lA = ((wave < 4) ? Ahs : Als) + aw*512;
    const ushort* Asrc = (wave < 4) ? Yh : Yl;

    int rl = lane & 15, kh = lane >> 4;
    int kbs_r = kh ^ ((rl >> 1) & 3);
    int raoff[2], rboff[2];
#pragma unroll
    for (int mf = 0; mf < 2; ++mf) raoff[mf] = (wm*32 + mf*16 + rl)*64 + kbs_r*16;
#pragma unroll
    for (int nf = 0; nf < 2; ++nf) rboff[nf] = (wq*32 + nf*16 + rl)*64 + kbs_r*16;

    f32x4 acc[2][2];
#pragma unroll
    for (int mf = 0; mf < 2; ++mf)
#pragma unroll
        for (int nf = 0; nf < 2; ++nf) acc[mf][nf] = (f32x4){0.f,0.f,0.f,0.f};

    int NT = Kp >> 5;
    for (int t = 0; t < NT; ++t) {
        int k0 = t*32;
        GL16(Asrc + aoff + k0, lA);
        GL16(Wh + boff + k0, lBh);
        GL16(Wl + boff + k0, lBl);
        __syncthreads();
        short8 a_h[2], a_l[2];
#pragma unroll
        for (int mf = 0; mf < 2; ++mf) {
            a_h[mf] = *(const short8*)((const char*)Ahs + raoff[mf]);
            a_l[mf] = *(const short8*)((const char*)Als + raoff[mf]);
        }
#pragma unroll
        for (int nf = 0; nf < 2; ++nf) {
            short8 b_h = *(const short8*)((const char*)Bhs + rboff[nf]);
            short8 b_l = *(const short8*)((const char*)Bls + rboff[nf]);
#pragma unroll
            for (int mf = 0; mf < 2; ++mf) {
                acc[mf][nf] = __builtin_amdgcn_mfma_f32_16x16x32_bf16(a_h[mf], b_h, acc[mf][nf], 0, 0, 0);
                acc[mf][nf] = __builtin_amdgcn_mfma_f32_16x16x32_bf16(a_h[mf], b_l, acc[mf][nf], 0, 0, 0);
                acc[mf][nf] = __builtin_amdgcn_mfma_f32_16x16x32_bf16(a_l[mf], b_h, acc[mf][nf], 0, 0, 0);
            }
        }
        __syncthreads();
    }

    double lsum = 0.0, lsq = 0.0;
#pragma unroll
    for (int mf = 0; mf < 2; ++mf) {
#pragma unroll
        for (int r = 0; r < 4; ++r) {
            int n = bn + wm*32 + mf*16 + kh*4 + r;
            float pv = pn[n];
#pragma unroll
            for (int nf = 0; nf < 2; ++nf) {
                int o = bo + wq*32 + nf*16 + rl;
                if (o < O) {
                    float d2 = pv + wn[o] - 2.f*acc[mf][nf][r];
                    float dd = FSQRT(fmaxf(d2, 1e-12f));
                    D[(size_t)n*O + o] = dd;
                    lsum += dd; lsq += (double)dd*dd;
                }
            }
        }
    }
    for (int off = 32; off > 0; off >>= 1) {
        lsum += __shfl_down(lsum, off, 64);
        lsq  += __shfl_down(lsq,  off, 64);
    }
    if (lane == 0) { wred[wave][0] = lsum; wred[wave][1] = lsq; }
    __syncthreads();
    if (tid == 0) {
        double s = 0.0, q = 0.0;
#pragma unroll
        for (int w = 0; w < 8; ++w) { s += wred[w][0]; q += wred[w][1]; }
        part[2*id]   = s;
        part[2*id+1] = q;
    }
}

// exp+crelu(0.01)+FC; scale re-derived in-block
__global__ __launch_bounds__(256) void fc_kernel(
    const float* __restrict__ dist4, const double* __restrict__ part, int nb, double Nstat,
    const float* __restrict__ fcw, const float* __restrict__ fcb,
    float* __restrict__ out) {
    SCALE_FROM_PART(s4);
    int b = blockIdx.x;
    int tid = threadIdx.x;
    float acc[10] = {};
    for (int o = tid; o < 1225; o += 256) {
        float d = dist4[(size_t)b*1225 + o];
        float v = __expf(-d*d*s4);
        v = (v >= 0.01f) ? v : 0.f;
#pragma unroll
        for (int k = 0; k < 10; ++k) acc[k] += v * fcw[k*1225 + o];
    }
    __shared__ float red[10*256];
#pragma unroll
    for (int k = 0; k < 10; ++k) red[k*256 + tid] = acc[k];
    __syncthreads();
    for (int st = 128; st > 0; st >>= 1) {
        if (tid < st) {
#pragma unroll
            for (int k = 0; k < 10; ++k) red[k*256 + tid] += red[k*256 + tid + st];
        }
        __syncthreads();
    }
    if (tid < 10) out[b*10 + tid] = red[tid*256] + fcb[tid];
}

extern "C" void kernel_launch(void* const* d_in, const int* in_sizes, int n_in,
                              void* d_out, int out_size, void* d_ws, size_t ws_size,
                              hipStream_t stream) {
    const float* x     = (const float*)d_in[0];
    const float* rgb_w = (const float*)d_in[1];
    const float* w2    = (const float*)d_in[2];
    const float* w3    = (const float*)d_in[3];
    const float* w4    = (const float*)d_in[4];
    const float* fc_w  = (const float*)d_in[5];
    const float* fc_b  = (const float*)d_in[6];
    float* out = (float*)d_out;

    float* wsf   = (float*)d_ws;
    float* dist  = wsf;                    // 14,745,600 floats
    float* ybuf  = wsf + 14745600;         // 3,686,400 floats
    float* pnb   = ybuf + 3686400;         // 36,864 floats
    float* wnb2  = pnb + 36864;            // 256
    float* wnb3  = wnb2 + 256;             // 640
    float* wnb4  = wnb3 + 640;             // 1,280
    float* scale = wnb4 + 1280;            // 64
    double* pblk = (double*)(scale + 64);  // 2304 doubles
    float* wsend = (float*)(pblk + 2304);

    float* pixstat = ybuf;

    size_t base_floats = (size_t)(wsend - wsf);
    size_t y2_floats   = 2u * 36864u * 128u / 2u;       // 4,718,592
    size_t w2_floats   = 2u * 256u * 128u / 2u;         // 32,768
    bool roomy = ws_size >= (base_floats + y2_floats + w2_floats + 1024) * sizeof(float);

    // Y2 planes
    ushort* Y2h = roomy ? (ushort*)wsend : (ushort*)(dist + 8388608);
    ushort* Y2l = Y2h + 36864*128;
    // W2 planes
    ushort* W2h = roomy ? (Y2l + 36864*128) : ((ushort*)(dist + 8388608) + 2*36864*128);
    ushort* W2l = W2h + 256*128;
    // Y3/Y4 planes in ybuf head
    ushort* Y3h = (ushort*)ybuf;
    ushort* Y3l = Y3h + 12288*256;
    ushort* Y4h = (ushort*)ybuf;
    ushort* Y4l = Y4h + 4096*640;
    // W4 planes: floats [2,621,440, 3,440,640)
    ushort* W4h = Y4l + 4096*640;
    ushort* W4l = W4h + 1280*640;
    // W3 planes: roomy -> ybuf tail; fallback -> after Y3
    ushort* W3h = roomy ? (ushort*)(ybuf + 3522560) : (Y3l + 12288*256);
    ushort* W3l = W3h + 640*256;

    // ---- layer 1 (+inline W1 prep; W2/3/4 prep in grid tail when roomy) ----
    rbf1_mfma<<<roomy ? 1296 : 1024, 512, 0, stream>>>(
        x, rgb_w, dist, pixstat,
        w2, W2h, W2l, wnb2,
        w3, W3h, W3l, wnb3,
        w4, W4h, W4l, wnb4);
    finalize36_kernel<<<36, 256, 0, stream>>>(pixstat, scale);

    // ---- layer 1 -> 2 transition ----
    if (roomy) {
        sfm1s_kernel<<<36864/4, 256, 0, stream>>>(dist, scale, Y2h, Y2l, pnb);
    } else {
        sfm1_kernel<<<DIV_UP(36864*100,256), 256, 0, stream>>>(dist, scale, ybuf);
        splitnorm_kernel<<<36864/4, 256, 0, stream>>>(ybuf, Y2h, Y2l, pnb, 36864, 100, 128);
        splitnorm_kernel<<<256/4, 256, 0, stream>>>(w2, W2h, W2l, wnb2, 225, 100, 128);
    }

    // ---- layer 2: 1152 blocks (bn 576, bo 2), bn8 = 72 ----
    distg_mfma<<<1152, 512, 0, stream>>>(Y2h, Y2l, W2h, W2l, pnb, wnb2, dist, 36864, 225, 128, 72, pblk);
    sfm2s_kernel<<<12288/4, 256, 0, stream>>>(dist, pblk, 1152, 8294400.0, Y3h, Y3l, pnb);

    // ---- layer 3: 960 blocks (bn 192, bo 5), bn8 = 24 ----
    if (!roomy) splitnorm_kernel<<<640/4, 256, 0, stream>>>(w3, W3h, W3l, wnb3, 625, 225, 256);
    distg_mfma<<<960, 512, 0, stream>>>(Y3h, Y3l, W3h, W3l, pnb, wnb3, dist, 12288, 625, 256, 24, pblk);
    sfm3s_kernel<<<4096/4, 256, 0, stream>>>(dist, pblk, 960, 7680000.0, Y4h, Y4l, pnb);

    // ---- layer 4: 640 blocks (bn 64, bo 10), bn8 = 8 ----
    if (!roomy) splitnorm_kernel<<<1280/4, 256, 0, stream>>>(w4, W4h, W4l, wnb4, 1225, 625, 640);
    distg_mfma<<<640, 512, 0, stream>>>(Y4h, Y4l, W4h, W4l, pnb, wnb4, dist, 4096, 1225, 640, 8, pblk);

    // ---- FC (scale re-derived in-block) ----
    fc_kernel<<<4096, 256, 0, stream>>>(dist, pblk, 640, 5017600.0, fc_w, fc_b, out);
}